// Round 16
// baseline (414.620 us; speedup 1.0000x reference)
//
#include <hip/hip_runtime.h>
#include <math.h>

#define NN 10000
#define EE 160000
#define KK 128
#define GG 16
#define NE 10
#define SQ3F 1.7320508075688772f
#define INV_SQ3 0.57735026918962576f
#define INV_AVG 0.0625f
#define RMAXI 0.2f

__device__ __forceinline__ void atomAddF(float* p, float v) { unsafeAtomicAdd(p, v); }

__device__ __forceinline__ float waveRed(float v) {
#pragma unroll
    for (int m = 32; m >= 1; m >>= 1) v += __shfl_xor(v, m);
    return v;
}

// ---------------- edge geometry + compaction + degree histogram ----------------
__global__ __launch_bounds__(256) void kg_geom(const float* __restrict__ pos, const float* __restrict__ shifts,
                            const int* __restrict__ ei,
                            float* __restrict__ ef, float* __restrict__ defdr,
                            float* __restrict__ Y1, float* __restrict__ rr,
                            int2* __restrict__ cei, int* __restrict__ nact,
                            int* __restrict__ deg_r, int* __restrict__ deg_s) {
    __shared__ int lcnt, lbase;
    if (threadIdx.x == 0) lcnt = 0;
    __syncthreads();
    const int e = blockIdx.x * 256 + threadIdx.x;
    const int sn = ei[e];
    const int rv = ei[EE + e];
    const float vx = pos[rv*3+0] - pos[sn*3+0] + shifts[e*3+0];
    const float vy = pos[rv*3+1] - pos[sn*3+1] + shifts[e*3+1];
    const float vz = pos[rv*3+2] - pos[sn*3+2] + shifts[e*3+2];
    const float r = sqrtf(vx*vx + vy*vy + vz*vz + 1e-12f);
    const float x = r * RMAXI;
    const int active = (x < 1.0f) ? 1 : 0;
    int pos_l = 0;
    if (active) pos_l = atomicAdd(&lcnt, 1);
    __syncthreads();
    if (threadIdx.x == 0 && lcnt > 0) lbase = atomicAdd(nact, lcnt);
    __syncthreads();
    if (!active) return;
    const int idx = lbase + pos_l;
    cei[idx] = make_int2(sn, rv);
    atomicAdd(&deg_s[sn], 1);
    atomicAdd(&deg_r[rv], 1);
    const float ir = 1.0f / r;
    rr[idx] = r;
    Y1[idx*3+0] = SQ3F*vx*ir;
    Y1[idx*3+1] = SQ3F*vy*ir;
    Y1[idx*3+2] = SQ3F*vz*ir;
    const float x2 = x*x, x4 = x2*x2, x5 = x4*x, x6 = x5*x, x7 = x6*x;
    const float fc  = 1.0f - 21.0f*x5 + 35.0f*x6 - 15.0f*x7;
    const float dfc = (-105.0f*x4 + 210.0f*x5 - 105.0f*x6) * RMAXI;
    const float C = 0.63245553203367587f;
    float4 efa, efb4, da, db;
    float* efp = (float*)&efa;
    float* dp  = (float*)&da;
#pragma unroll
    for (int b = 0; b < 8; b++) {
        const float kb = (float)(b + 1) * 0.62831853071795865f;
        float sb, cb;
        sincosf(kb * r, &sb, &cb);
        const float bess  = C * sb * ir;
        const float dbess = C * ir * (kb * cb - sb * ir);
        if (b == 4) { efp = (float*)&efb4; dp = (float*)&db; }
        efp[b & 3] = bess * fc;
        dp[b & 3]  = dbess * fc + bess * dfc;
    }
    ((float4*)ef)[idx*2]    = efa;
    ((float4*)ef)[idx*2+1]  = efb4;
    ((float4*)defdr)[idx*2]   = da;
    ((float4*)defdr)[idx*2+1] = db;
}

// ---------------- merged: zcount (blocks 0..39) + z-tables E1/T1/T2 (blocks 40..49) ----------------
__global__ __launch_bounds__(256) void kc_tab(const int* __restrict__ z, int* __restrict__ zcnt,
                        const float* __restrict__ We, const float* __restrict__ Wup1,
                        const float* __restrict__ Wsk1, const float* __restrict__ Wup2s,
                        float* __restrict__ E1, float* __restrict__ T1, float* __restrict__ T2) {
    __shared__ int h[NE];
    __shared__ float t1row[KK];
    const int t = threadIdx.x;
    if ((int)blockIdx.x < 40) {
        if (t < NE) h[t] = 0;
        __syncthreads();
        const int n = blockIdx.x * 256 + t;
        if (n < NN) atomicAdd(&h[z[n]], 1);
        __syncthreads();
        if (t < NE && h[t] > 0) atomicAdd(&zcnt[t], h[t]);
    } else {
        const int zz = blockIdx.x - 40;
        if (t < KK) {
            float a = 0.f, bv = 0.f;
            for (int c = 0; c < KK; c++) {
                const float w = We[zz*KK + c];
                a  += w * Wup1[c*KK + t];
                bv += w * Wsk1[(size_t)(zz*KK + c)*KK + t];
            }
            E1[zz*KK + t] = a;
            T1[zz*KK + t] = bv;
            t1row[t] = bv;
        }
        __syncthreads();
        if (t < KK) {
            float s = 0.f;
            for (int c = 0; c < KK; c++) s += t1row[c] * Wup2s[c*KK + t];
            T2[zz*KK + t] = s;
        }
    }
}

// ---------------- scans ----------------
__global__ __launch_bounds__(1024) void kg_scan(const int* __restrict__ deg_r, const int* __restrict__ deg_s,
                                               const int* __restrict__ zcnt,
                                               int* __restrict__ row_r, int* __restrict__ row_s,
                                               int* __restrict__ zrow) {
    __shared__ int part[1024];
    const int t = threadIdx.x;
    if (t == 0) {
        int s = 0;
        for (int i = 0; i < NE; i++) { zrow[i] = s; s += zcnt[i]; }
        zrow[NE] = s;
    }
    for (int a = 0; a < 2; a++) {
        const int* deg = a ? deg_s : deg_r;
        int* row = a ? row_s : row_r;
        const int base = t * 10;
        int loc[10];
        int s = 0;
#pragma unroll
        for (int k = 0; k < 10; k++) {
            loc[k] = s;
            if (base + k < NN) s += deg[base + k];
        }
        part[t] = s;
        __syncthreads();
        for (int off = 1; off < 1024; off <<= 1) {
            const int v = (t >= off) ? part[t - off] : 0;
            __syncthreads();
            part[t] += v;
            __syncthreads();
        }
        const int bex = (t > 0) ? part[t - 1] : 0;
#pragma unroll
        for (int k = 0; k < 10; k++)
            if (base + k < NN) row[base + k] = bex + loc[k];
        if (t == 1023) row[NN] = part[1023];
        __syncthreads();
    }
}

__global__ void kg_fill(const int2* __restrict__ cei, const int* __restrict__ nact,
                       const int* __restrict__ row_r, const int* __restrict__ row_s,
                       int* __restrict__ cur_r, int* __restrict__ cur_s,
                       int2* __restrict__ list_r, int2* __restrict__ list_s) {
    const int i = blockIdx.x * blockDim.x + threadIdx.x;
    if (i >= *nact) return;
    const int2 p = cei[i];
    const int pr = atomicAdd(&cur_r[p.y], 1);
    list_r[row_r[p.y] + pr] = make_int2(i, p.x);
    const int ps = atomicAdd(&cur_s[p.x], 1);
    list_s[row_s[p.x] + ps] = make_int2(i, p.y);
}

// ---------------- merged: zfill (blocks 0..39) + zinit3 (blocks 40..) ----------------
__global__ __launch_bounds__(256) void kz_init(const int* __restrict__ z, int* __restrict__ zcur,
                        const int* __restrict__ zrow, int* __restrict__ zlist,
                        const float* __restrict__ E1, const float* __restrict__ T1,
                        const float* __restrict__ T2,
                        float* __restrict__ su1, float* __restrict__ s1, float* __restrict__ s1u2) {
    const int t = threadIdx.x;
    if ((int)blockIdx.x < 40) {
        __shared__ int cnt[NE];
        __shared__ int base[NE];
        if (t < NE) cnt[t] = 0;
        __syncthreads();
        const int n = blockIdx.x * 256 + t;
        int pos = -1, zz = 0;
        if (n < NN) { zz = z[n]; pos = atomicAdd(&cnt[zz], 1); }
        __syncthreads();
        if (t < NE && cnt[t] > 0) base[t] = atomicAdd(&zcur[t], cnt[t]);
        __syncthreads();
        if (n < NN) zlist[zrow[zz] + base[zz] + pos] = n;
    } else {
        const int i = (blockIdx.x - 40) * 256 + t;
        if (i >= NN * KK) return;
        const int base = z[i >> 7] * KK + (i & 127);
        su1[i]  = E1[base];
        s1[i]   = T1[base];
        s1u2[i] = T2[base];
    }
}

// ============ dense core v3: tile 64 rows x 64 cols, 32KB LDS, thread = 4x4 ============
template <int TRANS>
__device__ __forceinline__ void d_stage(const float* __restrict__ W, int h, float* WL) {
    const int t = threadIdx.x;
    for (int i = t; i < KK * 64; i += 256) {
        int k, c;
        float v;
        if (!TRANS) { k = i >> 6; c = i & 63; v = W[k * KK + (h * 64 + c)]; }
        else        { c = i >> 7; k = i & 127; v = W[(h * 64 + c) * KK + k]; }
        WL[k * 64 + ((((c >> 2) + k) & 15) << 2) + (c & 3)] = v;
    }
}

template <int ACCUM, int GATHER>
__device__ __forceinline__ void d_compute(const float* __restrict__ in, float* __restrict__ out,
                                          int rows, float alpha, int bid_row, int h,
                                          const int* __restrict__ rowlist, const float* WL) {
    const int t = threadIdx.x;
    const int g0 = t & 15;
    const int cg = g0 << 2;
    const int i0 = bid_row * 64 + ((t >> 4) << 2);
    int rowv[4];
    const float* Ap[4];
#pragma unroll
    for (int j = 0; j < 4; j++) {
        int idx = i0 + j;
        if (idx > rows - 1) idx = rows - 1;
        rowv[j] = GATHER ? rowlist[idx] : idx;
        Ap[j] = in + (size_t)rowv[j] * KK;
    }
    float acc[4][4];
#pragma unroll
    for (int j = 0; j < 4; j++) { acc[j][0] = 0.f; acc[j][1] = 0.f; acc[j][2] = 0.f; acc[j][3] = 0.f; }
#pragma unroll 2
    for (int k = 0; k < KK; k += 4) {
        const float4 w0 = *(const float4*)&WL[(k+0)*64 + (((g0 + k + 0) & 15) << 2)];
        const float4 w1 = *(const float4*)&WL[(k+1)*64 + (((g0 + k + 1) & 15) << 2)];
        const float4 w2 = *(const float4*)&WL[(k+2)*64 + (((g0 + k + 2) & 15) << 2)];
        const float4 w3 = *(const float4*)&WL[(k+3)*64 + (((g0 + k + 3) & 15) << 2)];
#pragma unroll
        for (int j = 0; j < 4; j++) {
            const float4 a = *(const float4*)(Ap[j] + k);
            acc[j][0] += a.x*w0.x + a.y*w1.x + a.z*w2.x + a.w*w3.x;
            acc[j][1] += a.x*w0.y + a.y*w1.y + a.z*w2.y + a.w*w3.y;
            acc[j][2] += a.x*w0.z + a.y*w1.z + a.z*w2.z + a.w*w3.z;
            acc[j][3] += a.x*w0.w + a.y*w1.w + a.z*w2.w + a.w*w3.w;
        }
    }
    const int co = h * 64 + cg;
#pragma unroll
    for (int j = 0; j < 4; j++) {
        if (i0 + j < rows) {
            float4* o = (float4*)(out + (size_t)rowv[j] * KK + co);
            float4 v = make_float4(acc[j][0]*alpha, acc[j][1]*alpha, acc[j][2]*alpha, acc[j][3]*alpha);
            if (ACCUM) {
                const float4 old = *o;
                v.x += old.x; v.y += old.y; v.z += old.z; v.w += old.w;
            }
            *o = v;
        }
    }
}

// ---- single dense op ----
template <int TRANS, int ACCUM>
__global__ __launch_bounds__(256) void kd_one(const float* __restrict__ in, const float* __restrict__ W,
                                              float* __restrict__ out, int rows, float alpha) {
    __shared__ float WL[KK * 64];
    const int h = blockIdx.x & 1;
    d_stage<TRANS>(W, h, WL);
    __syncthreads();
    d_compute<ACCUM, 0>(in, out, rows, alpha, blockIdx.x >> 1, h, nullptr, WL);
}

// ---- two dense ops, one dispatch ----
template <int TA, int AA, int TB, int AB>
__global__ __launch_bounds__(256) void kd_two(
        const float* __restrict__ inA, const float* __restrict__ WA, float* __restrict__ outA,
        int rowsA, float alphaA,
        const float* __restrict__ inB, const float* __restrict__ WB, float* __restrict__ outB,
        int rowsB, float alphaB, int blocksA) {
    __shared__ float WL[KK * 64];
    if ((int)blockIdx.x < blocksA) {
        const int h = blockIdx.x & 1;
        d_stage<TA>(WA, h, WL);
        __syncthreads();
        d_compute<AA, 0>(inA, outA, rowsA, alphaA, blockIdx.x >> 1, h, nullptr, WL);
    } else {
        const int b = blockIdx.x - blocksA;
        const int h = b & 1;
        d_stage<TB>(WB, h, WL);
        __syncthreads();
        d_compute<AB, 0>(inB, outB, rowsB, alphaB, b >> 1, h, nullptr, WL);
    }
}

// ---- three dense ops, one dispatch ----
template <int TA, int AA, int TB, int AB, int TC, int AC>
__global__ __launch_bounds__(256) void kd_three(
        const float* __restrict__ inA, const float* __restrict__ WA, float* __restrict__ outA,
        int rowsA, float alphaA,
        const float* __restrict__ inB, const float* __restrict__ WB, float* __restrict__ outB,
        int rowsB, float alphaB,
        const float* __restrict__ inC, const float* __restrict__ WC, float* __restrict__ outC,
        int rowsC, float alphaC, int blocksA, int blocksAB) {
    __shared__ float WL[KK * 64];
    if ((int)blockIdx.x < blocksA) {
        const int h = blockIdx.x & 1;
        d_stage<TA>(WA, h, WL);
        __syncthreads();
        d_compute<AA, 0>(inA, outA, rowsA, alphaA, blockIdx.x >> 1, h, nullptr, WL);
    } else if ((int)blockIdx.x < blocksAB) {
        const int b = blockIdx.x - blocksA;
        const int h = b & 1;
        d_stage<TB>(WB, h, WL);
        __syncthreads();
        d_compute<AB, 0>(inB, outB, rowsB, alphaB, b >> 1, h, nullptr, WL);
    } else {
        const int b = blockIdx.x - blocksAB;
        const int h = b & 1;
        d_stage<TC>(WC, h, WL);
        __syncthreads();
        d_compute<AC, 0>(inC, outC, rowsC, alphaC, b >> 1, h, nullptr, WL);
    }
}

// ---- standalone per-z skip ----
template <int TRANS, int ACCUM>
__global__ __launch_bounds__(256) void kd_skip(
        const float* __restrict__ inS, const float* __restrict__ Wall, float* __restrict__ outS,
        const int* __restrict__ zrow, const int* __restrict__ zlist) {
    __shared__ float WL[KK * 64];
    const int sbid = blockIdx.x;
    const int zz = sbid % NE;
    const int q = sbid / NE;
    const int h = q & 1;
    const int ch0 = q >> 1;
    const int beg = zrow[zz];
    const int cnt = zrow[zz + 1] - beg;
    if (ch0 * 64 >= cnt) return;
    d_stage<TRANS>(Wall + (size_t)zz * (KK * KK), h, WL);
    __syncthreads();
    for (int ch = ch0; ch * 64 < cnt; ch += 16)
        d_compute<ACCUM, 1>(inS, outS, cnt, 1.f, ch, h, zlist + beg, WL);
}

// ---- dense op + per-z skip buckets, one dispatch ----
template <int TA, int AA, int TS, int AS>
__global__ __launch_bounds__(256) void kd_mix(
        const float* __restrict__ inA, const float* __restrict__ WA, float* __restrict__ outA,
        int rowsA, float alphaA,
        const float* __restrict__ inS, const float* __restrict__ Wall, float* __restrict__ outS,
        const int* __restrict__ zrow, const int* __restrict__ zlist, int blocksA) {
    __shared__ float WL[KK * 64];
    if ((int)blockIdx.x < blocksA) {
        const int h = blockIdx.x & 1;
        d_stage<TA>(WA, h, WL);
        __syncthreads();
        d_compute<AA, 0>(inA, outA, rowsA, alphaA, blockIdx.x >> 1, h, nullptr, WL);
    } else {
        const int sbid = blockIdx.x - blocksA;
        const int zz = sbid % NE;
        const int q = sbid / NE;
        const int h = q & 1;
        const int ch0 = q >> 1;
        const int beg = zrow[zz];
        const int cnt = zrow[zz + 1] - beg;
        if (ch0 * 64 >= cnt) return;
        d_stage<TS>(Wall + (size_t)zz * (KK * KK), h, WL);
        __syncthreads();
        for (int ch = ch0; ch * 64 < cnt; ch += 16)
            d_compute<AS, 1>(inS, outS, cnt, 1.f, ch, h, zlist + beg, WL);
    }
}

// ---------------- edge pass 1 (rcv-centric gather) ----------------
__global__ __launch_bounds__(256) void kg_edge1(const float* __restrict__ ef, const float* __restrict__ Y1,
                                                 const float* __restrict__ R1, const float* __restrict__ su1,
                                                 const int* __restrict__ row_r, const int2* __restrict__ list_r,
                                                 float* __restrict__ A0, float* __restrict__ A1) {
    __shared__ float RL[2048];
    for (int i = threadIdx.x; i < 2048; i += 256) RL[i] = R1[i];
    __syncthreads();
    const int lane = threadIdx.x & 63;
    const int n = blockIdx.x * 4 + (threadIdx.x >> 6);
    if (n >= NN) return;
    const int c0 = lane;
    const int c1 = lane + 64;
    float a00 = 0.f, a01 = 0.f;
    float ax0 = 0.f, ax1 = 0.f, ay0 = 0.f, ay1 = 0.f, az0 = 0.f, az1 = 0.f;
    const int beg = row_r[n];
    const int end = row_r[n + 1];
    for (int i = beg; i < end; i++) {
        const int2 p = list_r[i];
        const int e = p.x;
        const int sn = p.y;
        const float4 efa = ((const float4*)ef)[e*2];
        const float4 efb4 = ((const float4*)ef)[e*2+1];
        const float y0 = Y1[e*3+0], y1 = Y1[e*3+1], y2 = Y1[e*3+2];
        float wa0 = 0.f, wa1 = 0.f, wb0 = 0.f, wb1 = 0.f;
        const float* eb = (const float*)&efa;
#pragma unroll
        for (int b = 0; b < 8; b++) {
            if (b == 4) eb = (const float*)&efb4;
            const float v = eb[b & 3];
            wa0 += v * RL[b*256 + c0];
            wb0 += v * RL[b*256 + 128 + c0];
            wa1 += v * RL[b*256 + c1];
            wb1 += v * RL[b*256 + 128 + c1];
        }
        const float sj0 = su1[sn*KK + c0];
        const float sj1 = su1[sn*KK + c1];
        a00 += wa0 * sj0;
        a01 += wa1 * sj1;
        const float mb0 = wb0 * sj0;
        const float mb1 = wb1 * sj1;
        ax0 += mb0*y0; ax1 += mb1*y0;
        ay0 += mb0*y1; ay1 += mb1*y1;
        az0 += mb0*y2; az1 += mb1*y2;
    }
    A0[(size_t)n*KK + c0] = a00;
    A0[(size_t)n*KK + c1] = a01;
    float* A1r = A1 + (size_t)n * 384;
    A1r[c0] = ax0;        A1r[c1] = ax1;
    A1r[128 + c0] = ay0;  A1r[128 + c1] = ay1;
    A1r[256 + c0] = az0;  A1r[256 + c1] = az1;
}

// ---------------- edge pass 2 (rcv-centric gather) ----------------
__global__ __launch_bounds__(256) void kg_edge2(const float* __restrict__ ef, const float* __restrict__ Y1,
                                                 const float* __restrict__ R2, const float* __restrict__ s1u2,
                                                 const float* __restrict__ vup,
                                                 const int* __restrict__ row_r, const int2* __restrict__ list_r,
                                                 float* __restrict__ A2) {
    __shared__ float RL[2048];
    for (int i = threadIdx.x; i < 2048; i += 256) RL[i] = R2[(i >> 8) * 512 + (i & 255)];
    __syncthreads();
    const int lane = threadIdx.x & 63;
    const int n = blockIdx.x * 4 + (threadIdx.x >> 6);
    if (n >= NN) return;
    const int c0 = lane;
    const int c1 = lane + 64;
    float a0 = 0.f, a1 = 0.f;
    const int beg = row_r[n];
    const int end = row_r[n + 1];
    for (int i = beg; i < end; i++) {
        const int2 p = list_r[i];
        const int e = p.x;
        const int sn = p.y;
        const float4 efa = ((const float4*)ef)[e*2];
        const float4 efb4 = ((const float4*)ef)[e*2+1];
        const float y0 = Y1[e*3+0], y1 = Y1[e*3+1], y2 = Y1[e*3+2];
        float w00_0 = 0.f, w00_1 = 0.f, w110_0 = 0.f, w110_1 = 0.f;
        const float* eb = (const float*)&efa;
#pragma unroll
        for (int b = 0; b < 8; b++) {
            if (b == 4) eb = (const float*)&efb4;
            const float v = eb[b & 3];
            w00_0  += v * RL[b*256 + c0];
            w110_0 += v * RL[b*256 + 128 + c0];
            w00_1  += v * RL[b*256 + c1];
            w110_1 += v * RL[b*256 + 128 + c1];
        }
        const float sj0 = s1u2[sn*KK + c0];
        const float sj1 = s1u2[sn*KK + c1];
        const float* vu = vup + (size_t)sn * 384;
        const float tt0 = (vu[c0]*y0 + vu[128 + c0]*y1 + vu[256 + c0]*y2) * INV_SQ3;
        const float tt1 = (vu[c1]*y0 + vu[128 + c1]*y1 + vu[256 + c1]*y2) * INV_SQ3;
        a0 += w00_0 * sj0 + w110_0 * tt0;
        a1 += w00_1 * sj1 + w110_1 * tt1;
    }
    A2[(size_t)n*KK + c0] = a0;
    A2[(size_t)n*KK + c1] = a1;
}

// ---------------- MLP energy head + e1 + backward seed (grid-stride, staged W reused) ----------------
__global__ __launch_bounds__(128) void kg_mlp(const float* __restrict__ s2, const float* __restrict__ W_mlp,
                                             const float* __restrict__ w_out, const float* __restrict__ w_r1,
                                             const float* __restrict__ s1,
                                             float* __restrict__ g_s2, float* __restrict__ g_s1,
                                             float* __restrict__ e1n, float* __restrict__ e2n) {
    __shared__ float WmL[KK * 17];
    __shared__ float s2L[KK];
    __shared__ float part[128];
    __shared__ float ghL[16];
    __shared__ float eL[16];
    __shared__ float pw[2];
    const int t = threadIdx.x;
    for (int i = t; i < KK * 16; i += 128) WmL[(i >> 4) * 17 + (i & 15)] = W_mlp[i];
    const float wr = w_r1[t];
    for (int n = blockIdx.x; n < NN; n += gridDim.x) {
        __syncthreads();                 // protect s2L/part/eL/ghL/pw reuse
        s2L[t] = s2[(size_t)n * KK + t];
        float p = s1[(size_t)n * KK + t] * wr;
        p = waveRed(p);
        if ((t & 63) == 0) pw[t >> 6] = p;
        __syncthreads();
        {
            const int j = t & 15;
            const int seg = t >> 4;
            float pr = 0.f;
#pragma unroll
            for (int c = 0; c < 16; c++) pr += s2L[seg*16 + c] * WmL[(seg*16 + c) * 17 + j];
            part[t] = pr;
        }
        __syncthreads();
        if (t < 16) {
            float hh = 0.f;
#pragma unroll
            for (int s = 0; s < 8; s++) hh += part[s*16 + t];
            const float sg = 1.f / (1.f + expf(-hh));
            eL[t]  = hh * sg * w_out[t];
            ghL[t] = w_out[t] * sg * (1.f + hh * (1.f - sg));
        }
        __syncthreads();
        if (t == 0) {
            float e = 0.f;
#pragma unroll
            for (int j = 0; j < 16; j++) e += eL[j];
            e2n[n] = e;
            e1n[n] = pw[0] + pw[1];
        }
        float g = 0.f;
#pragma unroll
        for (int j = 0; j < 16; j++) g += ghL[j] * WmL[t * 17 + j];
        g_s2[(size_t)n * KK + t] = g;
        g_s1[(size_t)n * KK + t] = wr;
    }
}

// ---------------- energy reduction ----------------
__global__ __launch_bounds__(256) void kg_energy(const int* __restrict__ z, const int* __restrict__ batch,
                                                const float* __restrict__ ae,
                                                const float* __restrict__ e1n, const float* __restrict__ e2n,
                                                float* __restrict__ out) {
    __shared__ float bins[GG * 4];
    for (int i = threadIdx.x; i < GG * 4; i += 256) bins[i] = 0.f;
    __syncthreads();
    const int idx = blockIdx.x * 256 + threadIdx.x;
    const int stride = gridDim.x * 256;
    for (int n = idx; n < NN; n += stride) {
        const int b = batch[n];
        const float v0 = ae[z[n]];
        const float v1 = e1n[n];
        const float v2 = e2n[n];
        atomicAdd(&bins[b*4+0], v0 + v1 + v2);
        atomicAdd(&bins[b*4+1], v0);
        atomicAdd(&bins[b*4+2], v1);
        atomicAdd(&bins[b*4+3], v2);
    }
    __syncthreads();
    for (int i = threadIdx.x; i < GG * 4; i += 256) {
        const float v = bins[i];
        if (v != 0.f) {
            const int b = i >> 2;
            const int k = i & 3;
            float* dst = (k == 0) ? &out[b] : &out[GG + b*3 + (k - 1)];
            atomAddF(dst, v);
        }
    }
}

// ---------------- backward layer2, per-edge outputs ----------------
__global__ __launch_bounds__(256) void kg_bwdA_e(const float* __restrict__ ef8, const float* __restrict__ Y1,
                                                const int2* __restrict__ cei, const int* __restrict__ nact,
                                                const float* __restrict__ R2,
                                                const float* __restrict__ gA2, const float* __restrict__ s1u2,
                                                const float* __restrict__ vup, const int2* __restrict__ list_s,
                                                float* __restrict__ gefA, float* __restrict__ gyA) {
    const int i = blockIdx.x * 256 + threadIdx.x;
    if (i >= *nact) return;
    const int2 p = list_s[i];
    const int e = p.x;
    const int rv = p.y;
    const int sn = cei[e].x;
    const float y0 = Y1[e*3+0], y1 = Y1[e*3+1], y2 = Y1[e*3+2];
    const float4 efa = ((const float4*)ef8)[e*2];
    const float4 efb = ((const float4*)ef8)[e*2+1];
    const float efv[8] = {efa.x, efa.y, efa.z, efa.w, efb.x, efb.y, efb.z, efb.w};
    float acc[8] = {0.f,0.f,0.f,0.f,0.f,0.f,0.f,0.f};
    float g0 = 0.f, g1 = 0.f, g2 = 0.f;
    const float4* gaR = (const float4*)(gA2 + (size_t)rv * KK);
    const float4* sjR = (const float4*)(s1u2 + (size_t)sn * KK);
    const float4* vxR = (const float4*)(vup + (size_t)sn * 384);
    const float4* vyR = vxR + 32;
    const float4* vzR = vxR + 64;
    for (int cc = 0; cc < 32; cc++) {
        const float4 ga = gaR[cc];
        const float4 sj = sjR[cc];
        const float4 vx = vxR[cc];
        const float4 vy = vyR[cc];
        const float4 vz = vzR[cc];
#pragma unroll
        for (int k = 0; k < 4; k++) {
            const float gaE = ((const float*)&ga)[k];
            const float sjE = ((const float*)&sj)[k];
            const float vxE = ((const float*)&vx)[k];
            const float vyE = ((const float*)&vy)[k];
            const float vzE = ((const float*)&vz)[k];
            const float tt = (vxE*y0 + vyE*y1 + vzE*y2) * INV_SQ3;
            const float gw00 = gaE * sjE;
            const float gw110 = gaE * tt;
            float w110 = 0.f;
            const int c = cc*4 + k;
#pragma unroll
            for (int b = 0; b < 8; b++) {
                const float r2a = R2[b*512 + c];
                const float r2b = R2[b*512 + 128 + c];
                acc[b] += gw00 * r2a + gw110 * r2b;
                w110 += efv[b] * r2b;
            }
            const float gt = gaE * w110;
            g0 += gt * vxE;
            g1 += gt * vyE;
            g2 += gt * vzE;
        }
    }
    ((float4*)gefA)[e*2]   = make_float4(acc[0], acc[1], acc[2], acc[3]);
    ((float4*)gefA)[e*2+1] = make_float4(acc[4], acc[5], acc[6], acc[7]);
    gyA[e*3+0] = g0 * INV_SQ3;
    gyA[e*3+1] = g1 * INV_SQ3;
    gyA[e*3+2] = g2 * INV_SQ3;
}

// ---------------- backward layer2, node sums ----------------
__global__ __launch_bounds__(256) void kg_bwdA_n(const float* __restrict__ ef, const float* __restrict__ Y1,
                                                const float* __restrict__ R2, const float* __restrict__ gA2,
                                                const int* __restrict__ row_s, const int2* __restrict__ list_s,
                                                float* __restrict__ Gsj2, float* __restrict__ Gvj) {
    __shared__ float RL[2048];
    for (int i = threadIdx.x; i < 2048; i += 256) RL[i] = R2[(i >> 8) * 512 + (i & 255)];
    __syncthreads();
    const int lane = threadIdx.x & 63;
    const int sn = blockIdx.x * 4 + (threadIdx.x >> 6);
    if (sn >= NN) return;
    const int c0 = lane;
    const int c1 = lane + 64;
    float gs0 = 0.f, gs1 = 0.f;
    float gv00 = 0.f, gv01 = 0.f, gv10 = 0.f, gv11 = 0.f, gv20 = 0.f, gv21 = 0.f;
    const int beg = row_s[sn];
    const int end = row_s[sn + 1];
    for (int i = beg; i < end; i++) {
        const int2 p = list_s[i];
        const int e = p.x;
        const int rv = p.y;
        const float4 efa = ((const float4*)ef)[e*2];
        const float4 efb4 = ((const float4*)ef)[e*2+1];
        const float y0 = Y1[e*3+0], y1 = Y1[e*3+1], y2 = Y1[e*3+2];
        float w00_0 = 0.f, w00_1 = 0.f, w110_0 = 0.f, w110_1 = 0.f;
        const float* eb = (const float*)&efa;
#pragma unroll
        for (int b = 0; b < 8; b++) {
            if (b == 4) eb = (const float*)&efb4;
            const float v = eb[b & 3];
            w00_0  += v * RL[b*256 + c0];
            w110_0 += v * RL[b*256 + 128 + c0];
            w00_1  += v * RL[b*256 + c1];
            w110_1 += v * RL[b*256 + 128 + c1];
        }
        const float ga0 = gA2[(size_t)rv*KK + c0];
        const float ga1 = gA2[(size_t)rv*KK + c1];
        gs0 += ga0 * w00_0;
        gs1 += ga1 * w00_1;
        const float gts0 = ga0 * w110_0 * INV_SQ3;
        const float gts1 = ga1 * w110_1 * INV_SQ3;
        gv00 += gts0*y0; gv01 += gts1*y0;
        gv10 += gts0*y1; gv11 += gts1*y1;
        gv20 += gts0*y2; gv21 += gts1*y2;
    }
    Gsj2[(size_t)sn*KK + c0] = gs0;
    Gsj2[(size_t)sn*KK + c1] = gs1;
    float* Gv = Gvj + (size_t)sn * 384;
    Gv[c0] = gv00;        Gv[c1] = gv01;
    Gv[128 + c0] = gv10;  Gv[128 + c1] = gv11;
    Gv[256 + c0] = gv20;  Gv[256 + c1] = gv21;
}

// ---------------- backward layer1 per-edge + fused force ----------------
__global__ __launch_bounds__(256) void kg_bwdB_f(const float* __restrict__ ef8, const float* __restrict__ Y1,
                                                const int2* __restrict__ cei, const int* __restrict__ nact,
                                                const float* __restrict__ R1,
                                                const float* __restrict__ su1, const float* __restrict__ gA0,
                                                const float* __restrict__ gA1, const int2* __restrict__ list_r,
                                                const float* __restrict__ gefA, const float* __restrict__ gyA,
                                                const float* __restrict__ defdr, const float* __restrict__ rr,
                                                float* __restrict__ forces) {
    const int i = blockIdx.x * 256 + threadIdx.x;
    if (i >= *nact) return;
    const int2 p = list_r[i];
    const int e = p.x;
    const int sn = p.y;
    const int rv = cei[e].y;
    const float y0 = Y1[e*3+0], y1 = Y1[e*3+1], y2 = Y1[e*3+2];
    const float4 efa = ((const float4*)ef8)[e*2];
    const float4 efb = ((const float4*)ef8)[e*2+1];
    const float efv[8] = {efa.x, efa.y, efa.z, efa.w, efb.x, efb.y, efb.z, efb.w};
    float acc[8] = {0.f,0.f,0.f,0.f,0.f,0.f,0.f,0.f};
    float gg0 = 0.f, gg1 = 0.f, gg2 = 0.f;
    const float4* gmR = (const float4*)(gA0 + (size_t)rv * KK);
    const float4* sjR = (const float4*)(su1 + (size_t)sn * KK);
    const float4* gxR = (const float4*)(gA1 + (size_t)rv * 384);
    const float4* gyR = gxR + 32;
    const float4* gzR = gxR + 64;
    for (int cc = 0; cc < 32; cc++) {
        const float4 gm = gmR[cc];
        const float4 sj = sjR[cc];
        const float4 gx = gxR[cc];
        const float4 gy = gyR[cc];
        const float4 gz = gzR[cc];
#pragma unroll
        for (int k = 0; k < 4; k++) {
            const float gmE = ((const float*)&gm)[k];
            const float sjE = ((const float*)&sj)[k];
            const float g1E = ((const float*)&gx)[k];
            const float g2E = ((const float*)&gy)[k];
            const float g3E = ((const float*)&gz)[k];
            const float q = g1E*y0 + g2E*y1 + g3E*y2;
            const float gwa = gmE * sjE;
            const float gwb = q * sjE;
            float w = 0.f;
            const int c = cc*4 + k;
#pragma unroll
            for (int b = 0; b < 8; b++) {
                const float r1a = R1[b*256 + c];
                const float r1b = R1[b*256 + 128 + c];
                acc[b] += gwa * r1a + gwb * r1b;
                w += efv[b] * r1b;
            }
            const float ws = w * sjE;
            gg0 += g1E * ws;
            gg1 += g2E * ws;
            gg2 += g3E * ws;
        }
    }
    float gr = 0.f;
#pragma unroll
    for (int b = 0; b < 8; b++) gr += (gefA[e*8+b] + acc[b]) * defdr[e*8+b];
    const float g0 = gyA[e*3+0] + gg0;
    const float g1 = gyA[e*3+1] + gg1;
    const float g2 = gyA[e*3+2] + gg2;
    const float ir = 1.f / rr[e];
    const float dot = g0*y0 + g1*y1 + g2*y2;
    const float a = gr * INV_SQ3;
    const float b2 = SQ3F * ir;
    const float c = b2 * dot * (1.f / 3.f);
    const float gv0 = a*y0 + b2*g0 - c*y0;
    const float gv1 = a*y1 + b2*g1 - c*y1;
    const float gv2 = a*y2 + b2*g2 - c*y2;
    atomAddF(&forces[rv*3+0], -gv0);
    atomAddF(&forces[rv*3+1], -gv1);
    atomAddF(&forces[rv*3+2], -gv2);
    atomAddF(&forces[sn*3+0],  gv0);
    atomAddF(&forces[sn*3+1],  gv1);
    atomAddF(&forces[sn*3+2],  gv2);
}

extern "C" void kernel_launch(void* const* d_in, const int* in_sizes, int n_in,
                              void* d_out, int out_size, void* d_ws, size_t ws_size,
                              hipStream_t stream) {
    const float* positions  = (const float*)d_in[0];
    const float* shifts     = (const float*)d_in[1];
    const int*   edge_index = (const int*)d_in[2];
    const int*   node_z     = (const int*)d_in[3];
    const int*   batch      = (const int*)d_in[4];
    const float* atomic_e   = (const float*)d_in[5];
    const float* W_embed    = (const float*)d_in[6];
    const float* R1         = (const float*)d_in[7];
    const float* W_up1      = (const float*)d_in[8];
    const float* W_mix_s1   = (const float*)d_in[9];
    const float* W_mix_v1   = (const float*)d_in[10];
    const float* W_sk_s1    = (const float*)d_in[11];
    const float* w_r1       = (const float*)d_in[12];
    const float* R2         = (const float*)d_in[13];
    const float* W_up2s     = (const float*)d_in[14];
    const float* W_up2v     = (const float*)d_in[15];
    const float* W_mix_s2   = (const float*)d_in[16];
    const float* W_sk_s2    = (const float*)d_in[17];
    const float* W_mlp      = (const float*)d_in[18];
    const float* w_out      = (const float*)d_in[19];

    float* out = (float*)d_out;
    float* ws = (float*)d_ws;
    size_t off = 0;
    float* ef    = ws + off; off += (size_t)EE * 8;
    float* defdr = ws + off; off += (size_t)EE * 8;
    float* Y1    = ws + off; off += (size_t)EE * 3;
    float* rr    = ws + off; off += (size_t)EE;
    float* gefA  = ws + off; off += (size_t)EE * 8;
    float* gyA   = ws + off; off += (size_t)EE * 3;
    float* su1   = ws + off; off += (size_t)NN * KK;
    float* s1    = ws + off; off += (size_t)NN * KK;
    float* s1u2  = ws + off; off += (size_t)NN * KK;
    float* s2    = ws + off; off += (size_t)NN * KK;
    float* g_s2  = ws + off; off += (size_t)NN * KK;
    float* g_s1  = ws + off; off += (size_t)NN * KK;
    float* vup   = ws + off; off += (size_t)NN * KK * 3;
    float* A0    = ws + off; off += (size_t)NN * KK;
    float* A2    = ws + off; off += (size_t)NN * KK;
    float* Gsj2  = ws + off; off += (size_t)NN * KK;
    float* A1    = ws + off; off += (size_t)NN * KK * 3;
    float* Gvj   = ws + off; off += (size_t)NN * KK * 3;
    float* E1    = ws + off; off += 10 * KK;
    float* T1    = ws + off; off += 10 * KK;
    float* T2    = ws + off; off += 10 * KK;
    float* Wc    = ws + off; off += KK * KK;
    float* Wc2   = ws + off; off += KK * KK;
    float* e1n   = ws + off; off += NN;
    float* e2n   = ws + off; off += NN;
    int* ip = (int*)(ws + off);
    size_t ioff = 0;
    int* deg_r = ip + ioff; ioff += NN;
    int* deg_s = ip + ioff; ioff += NN;
    int* cur_r = ip + ioff; ioff += NN;
    int* cur_s = ip + ioff; ioff += NN;
    int* zcnt  = ip + ioff; ioff += 16;
    int* zcur  = ip + ioff; ioff += 16;
    int* nact  = ip + ioff; ioff += 16;
    int* row_r = ip + ioff; ioff += NN + 2;
    int* row_s = ip + ioff; ioff += NN + 2;
    int* zrow  = ip + ioff; ioff += 16;
    int* zlist = ip + ioff; ioff += NN;
    int2* cei    = (int2*)(ip + ioff); ioff += (size_t)EE * 2;
    int2* list_r = (int2*)(ip + ioff); ioff += (size_t)EE * 2;
    int2* list_s = (int2*)(ip + ioff); ioff += (size_t)EE * 2;

    hipMemsetAsync(out, 0, (size_t)out_size * sizeof(float), stream);
    hipMemsetAsync(deg_r, 0, ((size_t)4 * NN + 48) * sizeof(int), stream);

    const int EG = (EE + 255) / 256;
    const int BNB  = ((NN + 63) / 64) * 2;          // 314
    const int BN3B = ((NN * 3 + 63) / 64) * 2;      // 938
    const int BS   = NE * 32;                       // 320
    kg_geom<<<EG, 256, 0, stream>>>(positions, shifts, edge_index, ef, defdr, Y1, rr, cei, nact, deg_r, deg_s);
    kc_tab<<<50, 256, 0, stream>>>(node_z, zcnt, W_embed, W_up1, W_sk_s1, W_up2s, E1, T1, T2);
    kg_scan<<<1, 1024, 0, stream>>>(deg_r, deg_s, zcnt, row_r, row_s, zrow);
    kg_fill<<<EG, 256, 0, stream>>>(cei, nact, row_r, row_s, cur_r, cur_s, list_r, list_s);
    kz_init<<<40 + (NN * KK + 255) / 256, 256, 0, stream>>>(node_z, zcur, zrow, zlist, E1, T1, T2, su1, s1, s1u2);
    kd_two<0, 0, 0, 0><<<8, 256, 0, stream>>>(W_mix_v1, W_up2v, Wc, KK, 1.f,
                                              W_mix_s1, W_up2s, Wc2, KK, 1.f, 4);
    kg_edge1<<<(NN + 3) / 4, 256, 0, stream>>>(ef, Y1, R1, su1, row_r, list_r, A0, A1);
    kd_three<0, 1, 0, 1, 0, 0><<<BNB + BNB + BN3B, 256, 0, stream>>>(
        A0, W_mix_s1, s1, NN, INV_AVG,
        A0, Wc2, s1u2, NN, INV_AVG,
        A1, Wc, vup, NN * 3, INV_AVG, BNB, BNB + BNB);
    kd_skip<0, 0><<<BS, 256, 0, stream>>>(s1, W_sk_s2, s2, zrow, zlist);
    kg_edge2<<<(NN + 3) / 4, 256, 0, stream>>>(ef, Y1, R2, s1u2, vup, row_r, list_r, A2);
    kd_one<0, 1><<<BNB, 256, 0, stream>>>(A2, W_mix_s2, s2, NN, INV_AVG);
    kg_mlp<<<640, 128, 0, stream>>>(s2, W_mlp, w_out, w_r1, s1, g_s2, g_s1, e1n, e2n);
    kg_energy<<<32, 256, 0, stream>>>(node_z, batch, atomic_e, e1n, e2n, out);
    kd_mix<1, 0, 1, 1><<<BNB + BS, 256, 0, stream>>>(g_s2, W_mix_s2, A2, NN, INV_AVG,
                                                     g_s2, W_sk_s2, g_s1, zrow, zlist, BNB);
    kg_bwdA_e<<<EG, 256, 0, stream>>>(ef, Y1, cei, nact, R2, A2, s1u2, vup, list_s, gefA, gyA);
    kg_bwdA_n<<<(NN + 3) / 4, 256, 0, stream>>>(ef, Y1, R2, A2, row_s, list_s, Gsj2, Gvj);
    kd_two<1, 0, 1, 1><<<BN3B + BNB, 256, 0, stream>>>(Gvj, Wc, A1, NN * 3, INV_AVG,
                                                       Gsj2, W_up2s, g_s1, NN, 1.f, BN3B);
    kd_one<1, 0><<<BNB, 256, 0, stream>>>(g_s1, W_mix_s1, A0, NN, INV_AVG);
    kg_bwdB_f<<<EG, 256, 0, stream>>>(ef, Y1, cei, nact, R1, su1, A0, A1, list_r,
                                      gefA, gyA, defdr, rr, out + GG + GG * 3);
}

// Round 17
// 393.018 us; speedup vs baseline: 1.0550x; 1.0550x over previous
//
#include <hip/hip_runtime.h>
#include <math.h>

#define NN 10000
#define EE 160000
#define KK 128
#define GG 16
#define NE 10
#define SQ3F 1.7320508075688772f
#define INV_SQ3 0.57735026918962576f
#define INV_AVG 0.0625f
#define RMAXI 0.2f

__device__ __forceinline__ void atomAddF(float* p, float v) { unsafeAtomicAdd(p, v); }

__device__ __forceinline__ float waveRed(float v) {
#pragma unroll
    for (int m = 32; m >= 1; m >>= 1) v += __shfl_xor(v, m);
    return v;
}

// ---------------- edge geometry + compaction + degree histogram ----------------
__global__ __launch_bounds__(256) void qa_geom(const float* __restrict__ pos, const float* __restrict__ shifts,
                            const int* __restrict__ ei,
                            float* __restrict__ ef, float* __restrict__ defdr,
                            float* __restrict__ Y1, float* __restrict__ rr,
                            int2* __restrict__ cei, int* __restrict__ nact,
                            int* __restrict__ deg_r, int* __restrict__ deg_s) {
    __shared__ int lcnt, lbase;
    if (threadIdx.x == 0) lcnt = 0;
    __syncthreads();
    const int e = blockIdx.x * 256 + threadIdx.x;
    const int sn = ei[e];
    const int rv = ei[EE + e];
    const float vx = pos[rv*3+0] - pos[sn*3+0] + shifts[e*3+0];
    const float vy = pos[rv*3+1] - pos[sn*3+1] + shifts[e*3+1];
    const float vz = pos[rv*3+2] - pos[sn*3+2] + shifts[e*3+2];
    const float r = sqrtf(vx*vx + vy*vy + vz*vz + 1e-12f);
    const float x = r * RMAXI;
    const int active = (x < 1.0f) ? 1 : 0;
    int pos_l = 0;
    if (active) pos_l = atomicAdd(&lcnt, 1);
    __syncthreads();
    if (threadIdx.x == 0 && lcnt > 0) lbase = atomicAdd(nact, lcnt);
    __syncthreads();
    if (!active) return;
    const int idx = lbase + pos_l;
    cei[idx] = make_int2(sn, rv);
    atomicAdd(&deg_s[sn], 1);
    atomicAdd(&deg_r[rv], 1);
    const float ir = 1.0f / r;
    rr[idx] = r;
    Y1[idx*3+0] = SQ3F*vx*ir;
    Y1[idx*3+1] = SQ3F*vy*ir;
    Y1[idx*3+2] = SQ3F*vz*ir;
    const float x2 = x*x, x4 = x2*x2, x5 = x4*x, x6 = x5*x, x7 = x6*x;
    const float fc  = 1.0f - 21.0f*x5 + 35.0f*x6 - 15.0f*x7;
    const float dfc = (-105.0f*x4 + 210.0f*x5 - 105.0f*x6) * RMAXI;
    const float C = 0.63245553203367587f;
    float4 efa, efb4, da, db;
    float* efp = (float*)&efa;
    float* dp  = (float*)&da;
#pragma unroll
    for (int b = 0; b < 8; b++) {
        const float kb = (float)(b + 1) * 0.62831853071795865f;
        float sb, cb;
        sincosf(kb * r, &sb, &cb);
        const float bess  = C * sb * ir;
        const float dbess = C * ir * (kb * cb - sb * ir);
        if (b == 4) { efp = (float*)&efb4; dp = (float*)&db; }
        efp[b & 3] = bess * fc;
        dp[b & 3]  = dbess * fc + bess * dfc;
    }
    ((float4*)ef)[idx*2]    = efa;
    ((float4*)ef)[idx*2+1]  = efb4;
    ((float4*)defdr)[idx*2]   = da;
    ((float4*)defdr)[idx*2+1] = db;
}

// ---------------- merged: zcount (blocks 0..39) + z-tables E1/T1 (blocks 40..49) ----------------
__global__ __launch_bounds__(256) void qp_tab(const int* __restrict__ z, int* __restrict__ zcnt,
                        const float* __restrict__ We, const float* __restrict__ Wup1,
                        const float* __restrict__ Wsk1,
                        float* __restrict__ E1, float* __restrict__ T1) {
    __shared__ int h[NE];
    const int t = threadIdx.x;
    if ((int)blockIdx.x < 40) {
        if (t < NE) h[t] = 0;
        __syncthreads();
        const int n = blockIdx.x * 256 + t;
        if (n < NN) atomicAdd(&h[z[n]], 1);
        __syncthreads();
        if (t < NE && h[t] > 0) atomicAdd(&zcnt[t], h[t]);
    } else {
        const int zz = blockIdx.x - 40;
        if (t < KK) {
            float a = 0.f, bv = 0.f;
            for (int c = 0; c < KK; c++) {
                const float w = We[zz*KK + c];
                a  += w * Wup1[c*KK + t];
                bv += w * Wsk1[(size_t)(zz*KK + c)*KK + t];
            }
            E1[zz*KK + t] = a;
            T1[zz*KK + t] = bv;
        }
    }
}

// ---------------- scans ----------------
__global__ __launch_bounds__(1024) void qa_scan(const int* __restrict__ deg_r, const int* __restrict__ deg_s,
                                               const int* __restrict__ zcnt,
                                               int* __restrict__ row_r, int* __restrict__ row_s,
                                               int* __restrict__ zrow) {
    __shared__ int part[1024];
    const int t = threadIdx.x;
    if (t == 0) {
        int s = 0;
        for (int i = 0; i < NE; i++) { zrow[i] = s; s += zcnt[i]; }
        zrow[NE] = s;
    }
    for (int a = 0; a < 2; a++) {
        const int* deg = a ? deg_s : deg_r;
        int* row = a ? row_s : row_r;
        const int base = t * 10;
        int loc[10];
        int s = 0;
#pragma unroll
        for (int k = 0; k < 10; k++) {
            loc[k] = s;
            if (base + k < NN) s += deg[base + k];
        }
        part[t] = s;
        __syncthreads();
        for (int off = 1; off < 1024; off <<= 1) {
            const int v = (t >= off) ? part[t - off] : 0;
            __syncthreads();
            part[t] += v;
            __syncthreads();
        }
        const int bex = (t > 0) ? part[t - 1] : 0;
#pragma unroll
        for (int k = 0; k < 10; k++)
            if (base + k < NN) row[base + k] = bex + loc[k];
        if (t == 1023) row[NN] = part[1023];
        __syncthreads();
    }
}

__global__ void qa_fill(const int2* __restrict__ cei, const int* __restrict__ nact,
                       const int* __restrict__ row_r, const int* __restrict__ row_s,
                       int* __restrict__ cur_r, int* __restrict__ cur_s,
                       int2* __restrict__ list_r, int2* __restrict__ list_s) {
    const int i = blockIdx.x * blockDim.x + threadIdx.x;
    if (i >= *nact) return;
    const int2 p = cei[i];
    const int pr = atomicAdd(&cur_r[p.y], 1);
    list_r[row_r[p.y] + pr] = make_int2(i, p.x);
    const int ps = atomicAdd(&cur_s[p.x], 1);
    list_s[row_s[p.x] + ps] = make_int2(i, p.y);
}

// ---------------- merged: zfill (blocks 0..39) + zinit su1/s1 (blocks 40..) ----------------
__global__ __launch_bounds__(256) void qp_zinit(const int* __restrict__ z, int* __restrict__ zcur,
                        const int* __restrict__ zrow, int* __restrict__ zlist,
                        const float* __restrict__ E1, const float* __restrict__ T1,
                        float* __restrict__ su1, float* __restrict__ s1) {
    const int t = threadIdx.x;
    if ((int)blockIdx.x < 40) {
        __shared__ int cnt[NE];
        __shared__ int base[NE];
        if (t < NE) cnt[t] = 0;
        __syncthreads();
        const int n = blockIdx.x * 256 + t;
        int pos = -1, zz = 0;
        if (n < NN) { zz = z[n]; pos = atomicAdd(&cnt[zz], 1); }
        __syncthreads();
        if (t < NE && cnt[t] > 0) base[t] = atomicAdd(&zcur[t], cnt[t]);
        __syncthreads();
        if (n < NN) zlist[zrow[zz] + base[zz] + pos] = n;
    } else {
        const int i = (blockIdx.x - 40) * 256 + t;
        if (i >= NN * KK) return;
        const int base = z[i >> 7] * KK + (i & 127);
        su1[i] = E1[base];
        s1[i]  = T1[base];
    }
}

// ============ dense core v3: tile 64 rows x 64 cols, 32KB LDS, thread = 4x4 ============
template <int TRANS>
__device__ __forceinline__ void q_stage(const float* __restrict__ W, int h, float* WL) {
    const int t = threadIdx.x;
    for (int i = t; i < KK * 64; i += 256) {
        int k, c;
        float v;
        if (!TRANS) { k = i >> 6; c = i & 63; v = W[k * KK + (h * 64 + c)]; }
        else        { c = i >> 7; k = i & 127; v = W[(h * 64 + c) * KK + k]; }
        WL[k * 64 + ((((c >> 2) + k) & 15) << 2) + (c & 3)] = v;
    }
}

template <int ACCUM, int GATHER>
__device__ __forceinline__ void q_compute(const float* __restrict__ in, float* __restrict__ out,
                                          int rows, float alpha, int bid_row, int h,
                                          const int* __restrict__ rowlist, const float* WL) {
    const int t = threadIdx.x;
    const int g0 = t & 15;
    const int cg = g0 << 2;
    const int i0 = bid_row * 64 + ((t >> 4) << 2);
    int rowv[4];
    const float* Ap[4];
#pragma unroll
    for (int j = 0; j < 4; j++) {
        int idx = i0 + j;
        if (idx > rows - 1) idx = rows - 1;
        rowv[j] = GATHER ? rowlist[idx] : idx;
        Ap[j] = in + (size_t)rowv[j] * KK;
    }
    float acc[4][4];
#pragma unroll
    for (int j = 0; j < 4; j++) { acc[j][0] = 0.f; acc[j][1] = 0.f; acc[j][2] = 0.f; acc[j][3] = 0.f; }
#pragma unroll 2
    for (int k = 0; k < KK; k += 4) {
        const float4 w0 = *(const float4*)&WL[(k+0)*64 + (((g0 + k + 0) & 15) << 2)];
        const float4 w1 = *(const float4*)&WL[(k+1)*64 + (((g0 + k + 1) & 15) << 2)];
        const float4 w2 = *(const float4*)&WL[(k+2)*64 + (((g0 + k + 2) & 15) << 2)];
        const float4 w3 = *(const float4*)&WL[(k+3)*64 + (((g0 + k + 3) & 15) << 2)];
#pragma unroll
        for (int j = 0; j < 4; j++) {
            const float4 a = *(const float4*)(Ap[j] + k);
            acc[j][0] += a.x*w0.x + a.y*w1.x + a.z*w2.x + a.w*w3.x;
            acc[j][1] += a.x*w0.y + a.y*w1.y + a.z*w2.y + a.w*w3.y;
            acc[j][2] += a.x*w0.z + a.y*w1.z + a.z*w2.z + a.w*w3.z;
            acc[j][3] += a.x*w0.w + a.y*w1.w + a.z*w2.w + a.w*w3.w;
        }
    }
    const int co = h * 64 + cg;
#pragma unroll
    for (int j = 0; j < 4; j++) {
        if (i0 + j < rows) {
            float4* o = (float4*)(out + (size_t)rowv[j] * KK + co);
            float4 v = make_float4(acc[j][0]*alpha, acc[j][1]*alpha, acc[j][2]*alpha, acc[j][3]*alpha);
            if (ACCUM) {
                const float4 old = *o;
                v.x += old.x; v.y += old.y; v.z += old.z; v.w += old.w;
            }
            *o = v;
        }
    }
}

// ---- single dense op ----
template <int TRANS, int ACCUM>
__global__ __launch_bounds__(256) void qd_one(const float* __restrict__ in, const float* __restrict__ W,
                                              float* __restrict__ out, int rows, float alpha) {
    __shared__ float WL[KK * 64];
    const int h = blockIdx.x & 1;
    q_stage<TRANS>(W, h, WL);
    __syncthreads();
    q_compute<ACCUM, 0>(in, out, rows, alpha, blockIdx.x >> 1, h, nullptr, WL);
}

// ---- two dense ops, one dispatch ----
template <int TA, int AA, int TB, int AB>
__global__ __launch_bounds__(256) void qd_two(
        const float* __restrict__ inA, const float* __restrict__ WA, float* __restrict__ outA,
        int rowsA, float alphaA,
        const float* __restrict__ inB, const float* __restrict__ WB, float* __restrict__ outB,
        int rowsB, float alphaB, int blocksA) {
    __shared__ float WL[KK * 64];
    if ((int)blockIdx.x < blocksA) {
        const int h = blockIdx.x & 1;
        q_stage<TA>(WA, h, WL);
        __syncthreads();
        q_compute<AA, 0>(inA, outA, rowsA, alphaA, blockIdx.x >> 1, h, nullptr, WL);
    } else {
        const int b = blockIdx.x - blocksA;
        const int h = b & 1;
        q_stage<TB>(WB, h, WL);
        __syncthreads();
        q_compute<AB, 0>(inB, outB, rowsB, alphaB, b >> 1, h, nullptr, WL);
    }
}

// ---- dense op + per-z skip buckets, one dispatch ----
template <int TA, int AA, int TS, int AS>
__global__ __launch_bounds__(256) void qd_mix(
        const float* __restrict__ inA, const float* __restrict__ WA, float* __restrict__ outA,
        int rowsA, float alphaA,
        const float* __restrict__ inS, const float* __restrict__ Wall, float* __restrict__ outS,
        const int* __restrict__ zrow, const int* __restrict__ zlist, int blocksA) {
    __shared__ float WL[KK * 64];
    if ((int)blockIdx.x < blocksA) {
        const int h = blockIdx.x & 1;
        q_stage<TA>(WA, h, WL);
        __syncthreads();
        q_compute<AA, 0>(inA, outA, rowsA, alphaA, blockIdx.x >> 1, h, nullptr, WL);
    } else {
        const int sbid = blockIdx.x - blocksA;
        const int zz = sbid % NE;
        const int q = sbid / NE;
        const int h = q & 1;
        const int ch0 = q >> 1;
        const int beg = zrow[zz];
        const int cnt = zrow[zz + 1] - beg;
        if (ch0 * 64 >= cnt) return;
        q_stage<TS>(Wall + (size_t)zz * (KK * KK), h, WL);
        __syncthreads();
        for (int ch = ch0; ch * 64 < cnt; ch += 16)
            q_compute<AS, 1>(inS, outS, cnt, 1.f, ch, h, zlist + beg, WL);
    }
}

// ---------------- edge pass 1 (rcv-centric gather) ----------------
__global__ __launch_bounds__(256) void qe_edge1(const float* __restrict__ ef, const float* __restrict__ Y1,
                                                 const float* __restrict__ R1, const float* __restrict__ su1,
                                                 const int* __restrict__ row_r, const int2* __restrict__ list_r,
                                                 float* __restrict__ A0, float* __restrict__ A1) {
    __shared__ float RL[2048];
    for (int i = threadIdx.x; i < 2048; i += 256) RL[i] = R1[i];
    __syncthreads();
    const int lane = threadIdx.x & 63;
    const int n = blockIdx.x * 4 + (threadIdx.x >> 6);
    if (n >= NN) return;
    const int c0 = lane;
    const int c1 = lane + 64;
    float a00 = 0.f, a01 = 0.f;
    float ax0 = 0.f, ax1 = 0.f, ay0 = 0.f, ay1 = 0.f, az0 = 0.f, az1 = 0.f;
    const int beg = row_r[n];
    const int end = row_r[n + 1];
    for (int i = beg; i < end; i++) {
        const int2 p = list_r[i];
        const int e = p.x;
        const int sn = p.y;
        const float4 efa = ((const float4*)ef)[e*2];
        const float4 efb4 = ((const float4*)ef)[e*2+1];
        const float y0 = Y1[e*3+0], y1 = Y1[e*3+1], y2 = Y1[e*3+2];
        float wa0 = 0.f, wa1 = 0.f, wb0 = 0.f, wb1 = 0.f;
        const float* eb = (const float*)&efa;
#pragma unroll
        for (int b = 0; b < 8; b++) {
            if (b == 4) eb = (const float*)&efb4;
            const float v = eb[b & 3];
            wa0 += v * RL[b*256 + c0];
            wb0 += v * RL[b*256 + 128 + c0];
            wa1 += v * RL[b*256 + c1];
            wb1 += v * RL[b*256 + 128 + c1];
        }
        const float sj0 = su1[sn*KK + c0];
        const float sj1 = su1[sn*KK + c1];
        a00 += wa0 * sj0;
        a01 += wa1 * sj1;
        const float mb0 = wb0 * sj0;
        const float mb1 = wb1 * sj1;
        ax0 += mb0*y0; ax1 += mb1*y0;
        ay0 += mb0*y1; ay1 += mb1*y1;
        az0 += mb0*y2; az1 += mb1*y2;
    }
    A0[(size_t)n*KK + c0] = a00;
    A0[(size_t)n*KK + c1] = a01;
    float* A1r = A1 + (size_t)n * 384;
    A1r[c0] = ax0;        A1r[c1] = ax1;
    A1r[128 + c0] = ay0;  A1r[128 + c1] = ay1;
    A1r[256 + c0] = az0;  A1r[256 + c1] = az1;
}

// ---------------- edge pass 2 (rcv-centric gather) ----------------
__global__ __launch_bounds__(256) void qe_edge2(const float* __restrict__ ef, const float* __restrict__ Y1,
                                                 const float* __restrict__ R2, const float* __restrict__ s1u2,
                                                 const float* __restrict__ vup,
                                                 const int* __restrict__ row_r, const int2* __restrict__ list_r,
                                                 float* __restrict__ A2) {
    __shared__ float RL[2048];
    for (int i = threadIdx.x; i < 2048; i += 256) RL[i] = R2[(i >> 8) * 512 + (i & 255)];
    __syncthreads();
    const int lane = threadIdx.x & 63;
    const int n = blockIdx.x * 4 + (threadIdx.x >> 6);
    if (n >= NN) return;
    const int c0 = lane;
    const int c1 = lane + 64;
    float a0 = 0.f, a1 = 0.f;
    const int beg = row_r[n];
    const int end = row_r[n + 1];
    for (int i = beg; i < end; i++) {
        const int2 p = list_r[i];
        const int e = p.x;
        const int sn = p.y;
        const float4 efa = ((const float4*)ef)[e*2];
        const float4 efb4 = ((const float4*)ef)[e*2+1];
        const float y0 = Y1[e*3+0], y1 = Y1[e*3+1], y2 = Y1[e*3+2];
        float w00_0 = 0.f, w00_1 = 0.f, w110_0 = 0.f, w110_1 = 0.f;
        const float* eb = (const float*)&efa;
#pragma unroll
        for (int b = 0; b < 8; b++) {
            if (b == 4) eb = (const float*)&efb4;
            const float v = eb[b & 3];
            w00_0  += v * RL[b*256 + c0];
            w110_0 += v * RL[b*256 + 128 + c0];
            w00_1  += v * RL[b*256 + c1];
            w110_1 += v * RL[b*256 + 128 + c1];
        }
        const float sj0 = s1u2[sn*KK + c0];
        const float sj1 = s1u2[sn*KK + c1];
        const float* vu = vup + (size_t)sn * 384;
        const float tt0 = (vu[c0]*y0 + vu[128 + c0]*y1 + vu[256 + c0]*y2) * INV_SQ3;
        const float tt1 = (vu[c1]*y0 + vu[128 + c1]*y1 + vu[256 + c1]*y2) * INV_SQ3;
        a0 += w00_0 * sj0 + w110_0 * tt0;
        a1 += w00_1 * sj1 + w110_1 * tt1;
    }
    A2[(size_t)n*KK + c0] = a0;
    A2[(size_t)n*KK + c1] = a1;
}

// ---------------- MLP energy head + e1 + backward seed ----------------
__global__ __launch_bounds__(128) void qm_mlp(const float* __restrict__ s2, const float* __restrict__ W_mlp,
                                             const float* __restrict__ w_out, const float* __restrict__ w_r1,
                                             const float* __restrict__ s1,
                                             float* __restrict__ g_s2, float* __restrict__ g_s1,
                                             float* __restrict__ e1n, float* __restrict__ e2n) {
    __shared__ float WmL[KK * 17];
    __shared__ float s2L[KK];
    __shared__ float part[128];
    __shared__ float ghL[16];
    __shared__ float eL[16];
    __shared__ float pw[2];
    const int n = blockIdx.x;
    const int t = threadIdx.x;
    for (int i = t; i < KK * 16; i += 128) WmL[(i >> 4) * 17 + (i & 15)] = W_mlp[i];
    s2L[t] = s2[(size_t)n * KK + t];
    const float wr = w_r1[t];
    float p = s1[(size_t)n * KK + t] * wr;
    p = waveRed(p);
    if ((t & 63) == 0) pw[t >> 6] = p;
    __syncthreads();
    {
        const int j = t & 15;
        const int seg = t >> 4;
        float pr = 0.f;
#pragma unroll
        for (int c = 0; c < 16; c++) pr += s2L[seg*16 + c] * WmL[(seg*16 + c) * 17 + j];
        part[t] = pr;
    }
    __syncthreads();
    if (t < 16) {
        float hh = 0.f;
#pragma unroll
        for (int s = 0; s < 8; s++) hh += part[s*16 + t];
        const float sg = 1.f / (1.f + expf(-hh));
        eL[t]  = hh * sg * w_out[t];
        ghL[t] = w_out[t] * sg * (1.f + hh * (1.f - sg));
    }
    __syncthreads();
    if (t == 0) {
        float e = 0.f;
#pragma unroll
        for (int j = 0; j < 16; j++) e += eL[j];
        e2n[n] = e;
        e1n[n] = pw[0] + pw[1];
    }
    float g = 0.f;
#pragma unroll
    for (int j = 0; j < 16; j++) g += ghL[j] * WmL[t * 17 + j];
    g_s2[(size_t)n * KK + t] = g;
    g_s1[(size_t)n * KK + t] = wr;
}

// ---------------- energy reduction ----------------
__global__ __launch_bounds__(256) void qm_energy(const int* __restrict__ z, const int* __restrict__ batch,
                                                const float* __restrict__ ae,
                                                const float* __restrict__ e1n, const float* __restrict__ e2n,
                                                float* __restrict__ out) {
    __shared__ float bins[GG * 4];
    for (int i = threadIdx.x; i < GG * 4; i += 256) bins[i] = 0.f;
    __syncthreads();
    const int idx = blockIdx.x * 256 + threadIdx.x;
    const int stride = gridDim.x * 256;
    for (int n = idx; n < NN; n += stride) {
        const int b = batch[n];
        const float v0 = ae[z[n]];
        const float v1 = e1n[n];
        const float v2 = e2n[n];
        atomicAdd(&bins[b*4+0], v0 + v1 + v2);
        atomicAdd(&bins[b*4+1], v0);
        atomicAdd(&bins[b*4+2], v1);
        atomicAdd(&bins[b*4+3], v2);
    }
    __syncthreads();
    for (int i = threadIdx.x; i < GG * 4; i += 256) {
        const float v = bins[i];
        if (v != 0.f) {
            const int b = i >> 2;
            const int k = i & 3;
            float* dst = (k == 0) ? &out[b] : &out[GG + b*3 + (k - 1)];
            atomAddF(dst, v);
        }
    }
}

// ---------------- backward layer2, per-edge outputs ----------------
__global__ __launch_bounds__(256) void qb_bwdA_e(const float* __restrict__ ef8, const float* __restrict__ Y1,
                                                const int2* __restrict__ cei, const int* __restrict__ nact,
                                                const float* __restrict__ R2,
                                                const float* __restrict__ gA2, const float* __restrict__ s1u2,
                                                const float* __restrict__ vup, const int2* __restrict__ list_s,
                                                float* __restrict__ gefA, float* __restrict__ gyA) {
    const int i = blockIdx.x * 256 + threadIdx.x;
    if (i >= *nact) return;
    const int2 p = list_s[i];
    const int e = p.x;
    const int rv = p.y;
    const int sn = cei[e].x;
    const float y0 = Y1[e*3+0], y1 = Y1[e*3+1], y2 = Y1[e*3+2];
    const float4 efa = ((const float4*)ef8)[e*2];
    const float4 efb = ((const float4*)ef8)[e*2+1];
    const float efv[8] = {efa.x, efa.y, efa.z, efa.w, efb.x, efb.y, efb.z, efb.w};
    float acc[8] = {0.f,0.f,0.f,0.f,0.f,0.f,0.f,0.f};
    float g0 = 0.f, g1 = 0.f, g2 = 0.f;
    const float4* gaR = (const float4*)(gA2 + (size_t)rv * KK);
    const float4* sjR = (const float4*)(s1u2 + (size_t)sn * KK);
    const float4* vxR = (const float4*)(vup + (size_t)sn * 384);
    const float4* vyR = vxR + 32;
    const float4* vzR = vxR + 64;
    for (int cc = 0; cc < 32; cc++) {
        const float4 ga = gaR[cc];
        const float4 sj = sjR[cc];
        const float4 vx = vxR[cc];
        const float4 vy = vyR[cc];
        const float4 vz = vzR[cc];
#pragma unroll
        for (int k = 0; k < 4; k++) {
            const float gaE = ((const float*)&ga)[k];
            const float sjE = ((const float*)&sj)[k];
            const float vxE = ((const float*)&vx)[k];
            const float vyE = ((const float*)&vy)[k];
            const float vzE = ((const float*)&vz)[k];
            const float tt = (vxE*y0 + vyE*y1 + vzE*y2) * INV_SQ3;
            const float gw00 = gaE * sjE;
            const float gw110 = gaE * tt;
            float w110 = 0.f;
            const int c = cc*4 + k;
#pragma unroll
            for (int b = 0; b < 8; b++) {
                const float r2a = R2[b*512 + c];
                const float r2b = R2[b*512 + 128 + c];
                acc[b] += gw00 * r2a + gw110 * r2b;
                w110 += efv[b] * r2b;
            }
            const float gt = gaE * w110;
            g0 += gt * vxE;
            g1 += gt * vyE;
            g2 += gt * vzE;
        }
    }
    ((float4*)gefA)[e*2]   = make_float4(acc[0], acc[1], acc[2], acc[3]);
    ((float4*)gefA)[e*2+1] = make_float4(acc[4], acc[5], acc[6], acc[7]);
    gyA[e*3+0] = g0 * INV_SQ3;
    gyA[e*3+1] = g1 * INV_SQ3;
    gyA[e*3+2] = g2 * INV_SQ3;
}

// ---------------- backward layer2, node sums ----------------
__global__ __launch_bounds__(256) void qb_bwdA_n(const float* __restrict__ ef, const float* __restrict__ Y1,
                                                const float* __restrict__ R2, const float* __restrict__ gA2,
                                                const int* __restrict__ row_s, const int2* __restrict__ list_s,
                                                float* __restrict__ Gsj2, float* __restrict__ Gvj) {
    __shared__ float RL[2048];
    for (int i = threadIdx.x; i < 2048; i += 256) RL[i] = R2[(i >> 8) * 512 + (i & 255)];
    __syncthreads();
    const int lane = threadIdx.x & 63;
    const int sn = blockIdx.x * 4 + (threadIdx.x >> 6);
    if (sn >= NN) return;
    const int c0 = lane;
    const int c1 = lane + 64;
    float gs0 = 0.f, gs1 = 0.f;
    float gv00 = 0.f, gv01 = 0.f, gv10 = 0.f, gv11 = 0.f, gv20 = 0.f, gv21 = 0.f;
    const int beg = row_s[sn];
    const int end = row_s[sn + 1];
    for (int i = beg; i < end; i++) {
        const int2 p = list_s[i];
        const int e = p.x;
        const int rv = p.y;
        const float4 efa = ((const float4*)ef)[e*2];
        const float4 efb4 = ((const float4*)ef)[e*2+1];
        const float y0 = Y1[e*3+0], y1 = Y1[e*3+1], y2 = Y1[e*3+2];
        float w00_0 = 0.f, w00_1 = 0.f, w110_0 = 0.f, w110_1 = 0.f;
        const float* eb = (const float*)&efa;
#pragma unroll
        for (int b = 0; b < 8; b++) {
            if (b == 4) eb = (const float*)&efb4;
            const float v = eb[b & 3];
            w00_0  += v * RL[b*256 + c0];
            w110_0 += v * RL[b*256 + 128 + c0];
            w00_1  += v * RL[b*256 + c1];
            w110_1 += v * RL[b*256 + 128 + c1];
        }
        const float ga0 = gA2[(size_t)rv*KK + c0];
        const float ga1 = gA2[(size_t)rv*KK + c1];
        gs0 += ga0 * w00_0;
        gs1 += ga1 * w00_1;
        const float gts0 = ga0 * w110_0 * INV_SQ3;
        const float gts1 = ga1 * w110_1 * INV_SQ3;
        gv00 += gts0*y0; gv01 += gts1*y0;
        gv10 += gts0*y1; gv11 += gts1*y1;
        gv20 += gts0*y2; gv21 += gts1*y2;
    }
    Gsj2[(size_t)sn*KK + c0] = gs0;
    Gsj2[(size_t)sn*KK + c1] = gs1;
    float* Gv = Gvj + (size_t)sn * 384;
    Gv[c0] = gv00;        Gv[c1] = gv01;
    Gv[128 + c0] = gv10;  Gv[128 + c1] = gv11;
    Gv[256 + c0] = gv20;  Gv[256 + c1] = gv21;
}

// ---------------- backward layer1 per-edge + fused force ----------------
__global__ __launch_bounds__(256) void qb_bwdB_f(const float* __restrict__ ef8, const float* __restrict__ Y1,
                                                const int2* __restrict__ cei, const int* __restrict__ nact,
                                                const float* __restrict__ R1,
                                                const float* __restrict__ su1, const float* __restrict__ gA0,
                                                const float* __restrict__ gA1, const int2* __restrict__ list_r,
                                                const float* __restrict__ gefA, const float* __restrict__ gyA,
                                                const float* __restrict__ defdr, const float* __restrict__ rr,
                                                float* __restrict__ forces) {
    const int i = blockIdx.x * 256 + threadIdx.x;
    if (i >= *nact) return;
    const int2 p = list_r[i];
    const int e = p.x;
    const int sn = p.y;
    const int rv = cei[e].y;
    const float y0 = Y1[e*3+0], y1 = Y1[e*3+1], y2 = Y1[e*3+2];
    const float4 efa = ((const float4*)ef8)[e*2];
    const float4 efb = ((const float4*)ef8)[e*2+1];
    const float efv[8] = {efa.x, efa.y, efa.z, efa.w, efb.x, efb.y, efb.z, efb.w};
    float acc[8] = {0.f,0.f,0.f,0.f,0.f,0.f,0.f,0.f};
    float gg0 = 0.f, gg1 = 0.f, gg2 = 0.f;
    const float4* gmR = (const float4*)(gA0 + (size_t)rv * KK);
    const float4* sjR = (const float4*)(su1 + (size_t)sn * KK);
    const float4* gxR = (const float4*)(gA1 + (size_t)rv * 384);
    const float4* gyR = gxR + 32;
    const float4* gzR = gxR + 64;
    for (int cc = 0; cc < 32; cc++) {
        const float4 gm = gmR[cc];
        const float4 sj = sjR[cc];
        const float4 gx = gxR[cc];
        const float4 gy = gyR[cc];
        const float4 gz = gzR[cc];
#pragma unroll
        for (int k = 0; k < 4; k++) {
            const float gmE = ((const float*)&gm)[k];
            const float sjE = ((const float*)&sj)[k];
            const float g1E = ((const float*)&gx)[k];
            const float g2E = ((const float*)&gy)[k];
            const float g3E = ((const float*)&gz)[k];
            const float q = g1E*y0 + g2E*y1 + g3E*y2;
            const float gwa = gmE * sjE;
            const float gwb = q * sjE;
            float w = 0.f;
            const int c = cc*4 + k;
#pragma unroll
            for (int b = 0; b < 8; b++) {
                const float r1a = R1[b*256 + c];
                const float r1b = R1[b*256 + 128 + c];
                acc[b] += gwa * r1a + gwb * r1b;
                w += efv[b] * r1b;
            }
            const float ws = w * sjE;
            gg0 += g1E * ws;
            gg1 += g2E * ws;
            gg2 += g3E * ws;
        }
    }
    float gr = 0.f;
#pragma unroll
    for (int b = 0; b < 8; b++) gr += (gefA[e*8+b] + acc[b]) * defdr[e*8+b];
    const float g0 = gyA[e*3+0] + gg0;
    const float g1 = gyA[e*3+1] + gg1;
    const float g2 = gyA[e*3+2] + gg2;
    const float ir = 1.f / rr[e];
    const float dot = g0*y0 + g1*y1 + g2*y2;
    const float a = gr * INV_SQ3;
    const float b2 = SQ3F * ir;
    const float c = b2 * dot * (1.f / 3.f);
    const float gv0 = a*y0 + b2*g0 - c*y0;
    const float gv1 = a*y1 + b2*g1 - c*y1;
    const float gv2 = a*y2 + b2*g2 - c*y2;
    atomAddF(&forces[rv*3+0], -gv0);
    atomAddF(&forces[rv*3+1], -gv1);
    atomAddF(&forces[rv*3+2], -gv2);
    atomAddF(&forces[sn*3+0],  gv0);
    atomAddF(&forces[sn*3+1],  gv1);
    atomAddF(&forces[sn*3+2],  gv2);
}

extern "C" void kernel_launch(void* const* d_in, const int* in_sizes, int n_in,
                              void* d_out, int out_size, void* d_ws, size_t ws_size,
                              hipStream_t stream) {
    const float* positions  = (const float*)d_in[0];
    const float* shifts     = (const float*)d_in[1];
    const int*   edge_index = (const int*)d_in[2];
    const int*   node_z     = (const int*)d_in[3];
    const int*   batch      = (const int*)d_in[4];
    const float* atomic_e   = (const float*)d_in[5];
    const float* W_embed    = (const float*)d_in[6];
    const float* R1         = (const float*)d_in[7];
    const float* W_up1      = (const float*)d_in[8];
    const float* W_mix_s1   = (const float*)d_in[9];
    const float* W_mix_v1   = (const float*)d_in[10];
    const float* W_sk_s1    = (const float*)d_in[11];
    const float* w_r1       = (const float*)d_in[12];
    const float* R2         = (const float*)d_in[13];
    const float* W_up2s     = (const float*)d_in[14];
    const float* W_up2v     = (const float*)d_in[15];
    const float* W_mix_s2   = (const float*)d_in[16];
    const float* W_sk_s2    = (const float*)d_in[17];
    const float* W_mlp      = (const float*)d_in[18];
    const float* w_out      = (const float*)d_in[19];

    float* out = (float*)d_out;
    float* ws = (float*)d_ws;
    size_t off = 0;
    float* ef    = ws + off; off += (size_t)EE * 8;
    float* defdr = ws + off; off += (size_t)EE * 8;
    float* Y1    = ws + off; off += (size_t)EE * 3;
    float* rr    = ws + off; off += (size_t)EE;
    float* gefA  = ws + off; off += (size_t)EE * 8;
    float* gyA   = ws + off; off += (size_t)EE * 3;
    float* su1   = ws + off; off += (size_t)NN * KK;
    float* s1    = ws + off; off += (size_t)NN * KK;
    float* s1u2  = ws + off; off += (size_t)NN * KK;
    float* s2    = ws + off; off += (size_t)NN * KK;
    float* g_s2  = ws + off; off += (size_t)NN * KK;
    float* g_s1  = ws + off; off += (size_t)NN * KK;
    float* vup   = ws + off; off += (size_t)NN * KK * 3;
    float* A0    = ws + off; off += (size_t)NN * KK;
    float* A2    = ws + off; off += (size_t)NN * KK;
    float* Gsj2  = ws + off; off += (size_t)NN * KK;
    float* A1    = ws + off; off += (size_t)NN * KK * 3;
    float* Gvj   = ws + off; off += (size_t)NN * KK * 3;
    float* E1    = ws + off; off += 10 * KK;
    float* T1    = ws + off; off += 10 * KK;
    float* Wc    = ws + off; off += KK * KK;
    float* e1n   = ws + off; off += NN;
    float* e2n   = ws + off; off += NN;
    int* ip = (int*)(ws + off);
    size_t ioff = 0;
    int* deg_r = ip + ioff; ioff += NN;
    int* deg_s = ip + ioff; ioff += NN;
    int* cur_r = ip + ioff; ioff += NN;
    int* cur_s = ip + ioff; ioff += NN;
    int* zcnt  = ip + ioff; ioff += 16;
    int* zcur  = ip + ioff; ioff += 16;
    int* nact  = ip + ioff; ioff += 16;
    int* row_r = ip + ioff; ioff += NN + 2;
    int* row_s = ip + ioff; ioff += NN + 2;
    int* zrow  = ip + ioff; ioff += 16;
    int* zlist = ip + ioff; ioff += NN;
    int2* cei    = (int2*)(ip + ioff); ioff += (size_t)EE * 2;
    int2* list_r = (int2*)(ip + ioff); ioff += (size_t)EE * 2;
    int2* list_s = (int2*)(ip + ioff); ioff += (size_t)EE * 2;

    hipMemsetAsync(out, 0, (size_t)out_size * sizeof(float), stream);
    hipMemsetAsync(deg_r, 0, ((size_t)4 * NN + 48) * sizeof(int), stream);

    const int EG = (EE + 255) / 256;
    const int BNB  = ((NN + 63) / 64) * 2;          // 314
    const int BN3B = ((NN * 3 + 63) / 64) * 2;      // 938
    const int BS   = NE * 32;                       // 320
    qa_geom<<<EG, 256, 0, stream>>>(positions, shifts, edge_index, ef, defdr, Y1, rr, cei, nact, deg_r, deg_s);
    qp_tab<<<50, 256, 0, stream>>>(node_z, zcnt, W_embed, W_up1, W_sk_s1, E1, T1);
    qa_scan<<<1, 1024, 0, stream>>>(deg_r, deg_s, zcnt, row_r, row_s, zrow);
    qa_fill<<<EG, 256, 0, stream>>>(cei, nact, row_r, row_s, cur_r, cur_s, list_r, list_s);
    qp_zinit<<<40 + (NN * KK + 255) / 256, 256, 0, stream>>>(node_z, zcur, zrow, zlist, E1, T1, su1, s1);
    qd_one<0, 0><<<4, 256, 0, stream>>>(W_mix_v1, W_up2v, Wc, KK, 1.f);
    qe_edge1<<<(NN + 3) / 4, 256, 0, stream>>>(ef, Y1, R1, su1, row_r, list_r, A0, A1);
    qd_two<0, 1, 0, 0><<<BNB + BN3B, 256, 0, stream>>>(A0, W_mix_s1, s1, NN, INV_AVG,
                                                       A1, Wc, vup, NN * 3, INV_AVG, BNB);
    qd_mix<0, 0, 0, 0><<<BNB + BS, 256, 0, stream>>>(s1, W_up2s, s1u2, NN, 1.f,
                                                     s1, W_sk_s2, s2, zrow, zlist, BNB);
    qe_edge2<<<(NN + 3) / 4, 256, 0, stream>>>(ef, Y1, R2, s1u2, vup, row_r, list_r, A2);
    qd_one<0, 1><<<BNB, 256, 0, stream>>>(A2, W_mix_s2, s2, NN, INV_AVG);
    qm_mlp<<<NN, 128, 0, stream>>>(s2, W_mlp, w_out, w_r1, s1, g_s2, g_s1, e1n, e2n);
    qm_energy<<<32, 256, 0, stream>>>(node_z, batch, atomic_e, e1n, e2n, out);
    qd_mix<1, 0, 1, 1><<<BNB + BS, 256, 0, stream>>>(g_s2, W_mix_s2, A2, NN, INV_AVG,
                                                     g_s2, W_sk_s2, g_s1, zrow, zlist, BNB);
    qb_bwdA_e<<<EG, 256, 0, stream>>>(ef, Y1, cei, nact, R2, A2, s1u2, vup, list_s, gefA, gyA);
    qb_bwdA_n<<<(NN + 3) / 4, 256, 0, stream>>>(ef, Y1, R2, A2, row_s, list_s, Gsj2, Gvj);
    qd_two<1, 0, 1, 1><<<BN3B + BNB, 256, 0, stream>>>(Gvj, Wc, A1, NN * 3, INV_AVG,
                                                       Gsj2, W_up2s, g_s1, NN, 1.f, BN3B);
    qd_one<1, 0><<<BNB, 256, 0, stream>>>(g_s1, W_mix_s1, A0, NN, INV_AVG);
    qb_bwdB_f<<<EG, 256, 0, stream>>>(ef, Y1, cei, nact, R1, su1, A0, A1, list_r,
                                      gefA, gyA, defdr, rr, out + GG + GG * 3);
}

// Round 18
// 368.617 us; speedup vs baseline: 1.1248x; 1.0662x over previous
//
#include <hip/hip_runtime.h>
#include <math.h>

#define NN 10000
#define EE 160000
#define KK 128
#define GG 16
#define NE 10
#define SQ3F 1.7320508075688772f
#define INV_SQ3 0.57735026918962576f
#define INV_AVG 0.0625f
#define RMAXI 0.2f

__device__ __forceinline__ void atomAddF(float* p, float v) { unsafeAtomicAdd(p, v); }

__device__ __forceinline__ float waveRed(float v) {
#pragma unroll
    for (int m = 32; m >= 1; m >>= 1) v += __shfl_xor(v, m);
    return v;
}

// ============ dense core: tile 64 rows x 64 cols, 32KB LDS, thread = 4x4 ============
template <int TRANS>
__device__ __forceinline__ void r_stage(const float* __restrict__ W, int h, float* WL) {
    const int t = threadIdx.x;
    for (int i = t; i < KK * 64; i += 256) {
        int k, c;
        float v;
        if (!TRANS) { k = i >> 6; c = i & 63; v = W[k * KK + (h * 64 + c)]; }
        else        { c = i >> 7; k = i & 127; v = W[(h * 64 + c) * KK + k]; }
        WL[k * 64 + ((((c >> 2) + k) & 15) << 2) + (c & 3)] = v;
    }
}

template <int ACCUM, int GATHER>
__device__ __forceinline__ void r_compute(const float* __restrict__ in, float* __restrict__ out,
                                          int rows, float alpha, int bid_row, int h,
                                          const int* __restrict__ rowlist, const float* WL) {
    const int t = threadIdx.x;
    const int g0 = t & 15;
    const int cg = g0 << 2;
    const int i0 = bid_row * 64 + ((t >> 4) << 2);
    int rowv[4];
    const float* Ap[4];
#pragma unroll
    for (int j = 0; j < 4; j++) {
        int idx = i0 + j;
        if (idx > rows - 1) idx = rows - 1;
        rowv[j] = GATHER ? rowlist[idx] : idx;
        Ap[j] = in + (size_t)rowv[j] * KK;
    }
    float acc[4][4];
#pragma unroll
    for (int j = 0; j < 4; j++) { acc[j][0] = 0.f; acc[j][1] = 0.f; acc[j][2] = 0.f; acc[j][3] = 0.f; }
#pragma unroll 2
    for (int k = 0; k < KK; k += 4) {
        const float4 w0 = *(const float4*)&WL[(k+0)*64 + (((g0 + k + 0) & 15) << 2)];
        const float4 w1 = *(const float4*)&WL[(k+1)*64 + (((g0 + k + 1) & 15) << 2)];
        const float4 w2 = *(const float4*)&WL[(k+2)*64 + (((g0 + k + 2) & 15) << 2)];
        const float4 w3 = *(const float4*)&WL[(k+3)*64 + (((g0 + k + 3) & 15) << 2)];
#pragma unroll
        for (int j = 0; j < 4; j++) {
            const float4 a = *(const float4*)(Ap[j] + k);
            acc[j][0] += a.x*w0.x + a.y*w1.x + a.z*w2.x + a.w*w3.x;
            acc[j][1] += a.x*w0.y + a.y*w1.y + a.z*w2.y + a.w*w3.y;
            acc[j][2] += a.x*w0.z + a.y*w1.z + a.z*w2.z + a.w*w3.z;
            acc[j][3] += a.x*w0.w + a.y*w1.w + a.z*w2.w + a.w*w3.w;
        }
    }
    const int co = h * 64 + cg;
#pragma unroll
    for (int j = 0; j < 4; j++) {
        if (i0 + j < rows) {
            float4* o = (float4*)(out + (size_t)rowv[j] * KK + co);
            float4 v = make_float4(acc[j][0]*alpha, acc[j][1]*alpha, acc[j][2]*alpha, acc[j][3]*alpha);
            if (ACCUM) {
                const float4 old = *o;
                v.x += old.x; v.y += old.y; v.z += old.z; v.w += old.w;
            }
            *o = v;
        }
    }
}

// ---------------- edge geometry + compaction + degree histogram ----------------
__global__ __launch_bounds__(256) void rx_geom(const float* __restrict__ pos, const float* __restrict__ shifts,
                            const int* __restrict__ ei,
                            float* __restrict__ ef, float* __restrict__ defdr,
                            float* __restrict__ Y1, float* __restrict__ rr,
                            int2* __restrict__ cei, int* __restrict__ nact,
                            int* __restrict__ deg_r, int* __restrict__ deg_s) {
    __shared__ int lcnt, lbase;
    if (threadIdx.x == 0) lcnt = 0;
    __syncthreads();
    const int e = blockIdx.x * 256 + threadIdx.x;
    const int sn = ei[e];
    const int rv = ei[EE + e];
    const float vx = pos[rv*3+0] - pos[sn*3+0] + shifts[e*3+0];
    const float vy = pos[rv*3+1] - pos[sn*3+1] + shifts[e*3+1];
    const float vz = pos[rv*3+2] - pos[sn*3+2] + shifts[e*3+2];
    const float r = sqrtf(vx*vx + vy*vy + vz*vz + 1e-12f);
    const float x = r * RMAXI;
    const int active = (x < 1.0f) ? 1 : 0;
    int pos_l = 0;
    if (active) pos_l = atomicAdd(&lcnt, 1);
    __syncthreads();
    if (threadIdx.x == 0 && lcnt > 0) lbase = atomicAdd(nact, lcnt);
    __syncthreads();
    if (!active) return;
    const int idx = lbase + pos_l;
    cei[idx] = make_int2(sn, rv);
    atomicAdd(&deg_s[sn], 1);
    atomicAdd(&deg_r[rv], 1);
    const float ir = 1.0f / r;
    rr[idx] = r;
    Y1[idx*3+0] = SQ3F*vx*ir;
    Y1[idx*3+1] = SQ3F*vy*ir;
    Y1[idx*3+2] = SQ3F*vz*ir;
    const float x2 = x*x, x4 = x2*x2, x5 = x4*x, x6 = x5*x, x7 = x6*x;
    const float fc  = 1.0f - 21.0f*x5 + 35.0f*x6 - 15.0f*x7;
    const float dfc = (-105.0f*x4 + 210.0f*x5 - 105.0f*x6) * RMAXI;
    const float C = 0.63245553203367587f;
    float4 efa, efb4, da, db;
    float* efp = (float*)&efa;
    float* dp  = (float*)&da;
#pragma unroll
    for (int b = 0; b < 8; b++) {
        const float kb = (float)(b + 1) * 0.62831853071795865f;
        float sb, cb;
        sincosf(kb * r, &sb, &cb);
        const float bess  = C * sb * ir;
        const float dbess = C * ir * (kb * cb - sb * ir);
        if (b == 4) { efp = (float*)&efb4; dp = (float*)&db; }
        efp[b & 3] = bess * fc;
        dp[b & 3]  = dbess * fc + bess * dfc;
    }
    ((float4*)ef)[idx*2]    = efa;
    ((float4*)ef)[idx*2+1]  = efb4;
    ((float4*)defdr)[idx*2]   = da;
    ((float4*)defdr)[idx*2+1] = db;
}

// ---------------- merged: zcount (0..39) + z-tables (40..49) + Wc dense (50..53) ----------------
__global__ __launch_bounds__(256) void rx_tab(const int* __restrict__ z, int* __restrict__ zcnt,
                        const float* __restrict__ We, const float* __restrict__ Wup1,
                        const float* __restrict__ Wsk1,
                        float* __restrict__ E1, float* __restrict__ T1,
                        const float* __restrict__ Wmv1, const float* __restrict__ Wu2v,
                        float* __restrict__ Wc) {
    __shared__ float WL[KK * 64];
    const int t = threadIdx.x;
    if ((int)blockIdx.x < 40) {
        int* h = (int*)WL;
        if (t < NE) h[t] = 0;
        __syncthreads();
        const int n = blockIdx.x * 256 + t;
        if (n < NN) atomicAdd(&h[z[n]], 1);
        __syncthreads();
        if (t < NE && h[t] > 0) atomicAdd(&zcnt[t], h[t]);
    } else if ((int)blockIdx.x < 50) {
        const int zz = blockIdx.x - 40;
        if (t < KK) {
            float a = 0.f, bv = 0.f;
            for (int c = 0; c < KK; c++) {
                const float w = We[zz*KK + c];
                a  += w * Wup1[c*KK + t];
                bv += w * Wsk1[(size_t)(zz*KK + c)*KK + t];
            }
            E1[zz*KK + t] = a;
            T1[zz*KK + t] = bv;
        }
    } else {
        const int b = blockIdx.x - 50;       // 0..3
        const int h = b & 1;
        r_stage<0>(Wu2v, h, WL);             // Wc = Wmv1 @ Wu2v
        __syncthreads();
        r_compute<0, 0>(Wmv1, Wc, KK, 1.f, b >> 1, h, nullptr, WL);
    }
}

// ---------------- scans ----------------
__global__ __launch_bounds__(1024) void rx_scan(const int* __restrict__ deg_r, const int* __restrict__ deg_s,
                                               const int* __restrict__ zcnt,
                                               int* __restrict__ row_r, int* __restrict__ row_s,
                                               int* __restrict__ zrow) {
    __shared__ int part[1024];
    const int t = threadIdx.x;
    if (t == 0) {
        int s = 0;
        for (int i = 0; i < NE; i++) { zrow[i] = s; s += zcnt[i]; }
        zrow[NE] = s;
    }
    for (int a = 0; a < 2; a++) {
        const int* deg = a ? deg_s : deg_r;
        int* row = a ? row_s : row_r;
        const int base = t * 10;
        int loc[10];
        int s = 0;
#pragma unroll
        for (int k = 0; k < 10; k++) {
            loc[k] = s;
            if (base + k < NN) s += deg[base + k];
        }
        part[t] = s;
        __syncthreads();
        for (int off = 1; off < 1024; off <<= 1) {
            const int v = (t >= off) ? part[t - off] : 0;
            __syncthreads();
            part[t] += v;
            __syncthreads();
        }
        const int bex = (t > 0) ? part[t - 1] : 0;
#pragma unroll
        for (int k = 0; k < 10; k++)
            if (base + k < NN) row[base + k] = bex + loc[k];
        if (t == 1023) row[NN] = part[1023];
        __syncthreads();
    }
}

// ---------------- merged: CSR fill (0..624) + zfill (625..664) + zinit (665..5664) ----------------
__global__ __launch_bounds__(256) void rx_fill3(const int2* __restrict__ cei, const int* __restrict__ nact,
                       const int* __restrict__ row_r, const int* __restrict__ row_s,
                       int* __restrict__ cur_r, int* __restrict__ cur_s,
                       int2* __restrict__ list_r, int2* __restrict__ list_s,
                       const int* __restrict__ z, int* __restrict__ zcur,
                       const int* __restrict__ zrow, int* __restrict__ zlist,
                       const float* __restrict__ E1, const float* __restrict__ T1,
                       float* __restrict__ su1, float* __restrict__ s1) {
    const int t = threadIdx.x;
    if ((int)blockIdx.x < 625) {
        const int i = blockIdx.x * 256 + t;
        if (i >= *nact) return;
        const int2 p = cei[i];
        const int pr = atomicAdd(&cur_r[p.y], 1);
        list_r[row_r[p.y] + pr] = make_int2(i, p.x);
        const int ps = atomicAdd(&cur_s[p.x], 1);
        list_s[row_s[p.x] + ps] = make_int2(i, p.y);
    } else if ((int)blockIdx.x < 665) {
        __shared__ int cnt[NE];
        __shared__ int base[NE];
        if (t < NE) cnt[t] = 0;
        __syncthreads();
        const int n = (blockIdx.x - 625) * 256 + t;
        int pos = -1, zz = 0;
        if (n < NN) { zz = z[n]; pos = atomicAdd(&cnt[zz], 1); }
        __syncthreads();
        if (t < NE && cnt[t] > 0) base[t] = atomicAdd(&zcur[t], cnt[t]);
        __syncthreads();
        if (n < NN) zlist[zrow[zz] + base[zz] + pos] = n;
    } else {
        const int i = (blockIdx.x - 665) * 256 + t;
        if (i >= NN * KK) return;
        const int base = z[i >> 7] * KK + (i & 127);
        su1[i] = E1[base];
        s1[i]  = T1[base];
    }
}

// ---- single dense op ----
template <int TRANS, int ACCUM>
__global__ __launch_bounds__(256) void rx_one(const float* __restrict__ in, const float* __restrict__ W,
                                              float* __restrict__ out, int rows, float alpha) {
    __shared__ float WL[KK * 64];
    const int h = blockIdx.x & 1;
    r_stage<TRANS>(W, h, WL);
    __syncthreads();
    r_compute<ACCUM, 0>(in, out, rows, alpha, blockIdx.x >> 1, h, nullptr, WL);
}

// ---- two dense ops, one dispatch ----
template <int TA, int AA, int TB, int AB>
__global__ __launch_bounds__(256) void rx_two(
        const float* __restrict__ inA, const float* __restrict__ WA, float* __restrict__ outA,
        int rowsA, float alphaA,
        const float* __restrict__ inB, const float* __restrict__ WB, float* __restrict__ outB,
        int rowsB, float alphaB, int blocksA) {
    __shared__ float WL[KK * 64];
    if ((int)blockIdx.x < blocksA) {
        const int h = blockIdx.x & 1;
        r_stage<TA>(WA, h, WL);
        __syncthreads();
        r_compute<AA, 0>(inA, outA, rowsA, alphaA, blockIdx.x >> 1, h, nullptr, WL);
    } else {
        const int b = blockIdx.x - blocksA;
        const int h = b & 1;
        r_stage<TB>(WB, h, WL);
        __syncthreads();
        r_compute<AB, 0>(inB, outB, rowsB, alphaB, b >> 1, h, nullptr, WL);
    }
}

// ---- dense op + per-z skip buckets, one dispatch ----
template <int TA, int AA, int TS, int AS>
__global__ __launch_bounds__(256) void rx_mix(
        const float* __restrict__ inA, const float* __restrict__ WA, float* __restrict__ outA,
        int rowsA, float alphaA,
        const float* __restrict__ inS, const float* __restrict__ Wall, float* __restrict__ outS,
        const int* __restrict__ zrow, const int* __restrict__ zlist, int blocksA) {
    __shared__ float WL[KK * 64];
    if ((int)blockIdx.x < blocksA) {
        const int h = blockIdx.x & 1;
        r_stage<TA>(WA, h, WL);
        __syncthreads();
        r_compute<AA, 0>(inA, outA, rowsA, alphaA, blockIdx.x >> 1, h, nullptr, WL);
    } else {
        const int sbid = blockIdx.x - blocksA;
        const int zz = sbid % NE;
        const int q = sbid / NE;
        const int h = q & 1;
        const int ch0 = q >> 1;
        const int beg = zrow[zz];
        const int cnt = zrow[zz + 1] - beg;
        if (ch0 * 64 >= cnt) return;
        r_stage<TS>(Wall + (size_t)zz * (KK * KK), h, WL);
        __syncthreads();
        for (int ch = ch0; ch * 64 < cnt; ch += 16)
            r_compute<AS, 1>(inS, outS, cnt, 1.f, ch, h, zlist + beg, WL);
    }
}

// ---- backward bundle: dense g_A2 (0..BNB-1) + skip bwd accum (BNB..BNB+BS-1) + energy (last 32) ----
__global__ __launch_bounds__(256) void rx_bwdmix(
        const float* __restrict__ g_s2, const float* __restrict__ Wms2, float* __restrict__ gA2,
        const float* __restrict__ Wsk2, float* __restrict__ g_s1,
        const int* __restrict__ zrow, const int* __restrict__ zlist,
        const int* __restrict__ z, const int* __restrict__ batch, const float* __restrict__ ae,
        const float* __restrict__ e1n, const float* __restrict__ e2n, float* __restrict__ out,
        int blocksA, int blocksAB) {
    __shared__ float WL[KK * 64];
    const int t = threadIdx.x;
    if ((int)blockIdx.x < blocksA) {
        const int h = blockIdx.x & 1;
        r_stage<1>(Wms2, h, WL);
        __syncthreads();
        r_compute<0, 0>(g_s2, gA2, NN, INV_AVG, blockIdx.x >> 1, h, nullptr, WL);
    } else if ((int)blockIdx.x < blocksAB) {
        const int sbid = blockIdx.x - blocksA;
        const int zz = sbid % NE;
        const int q = sbid / NE;
        const int h = q & 1;
        const int ch0 = q >> 1;
        const int beg = zrow[zz];
        const int cnt = zrow[zz + 1] - beg;
        if (ch0 * 64 >= cnt) return;
        r_stage<1>(Wsk2 + (size_t)zz * (KK * KK), h, WL);
        __syncthreads();
        for (int ch = ch0; ch * 64 < cnt; ch += 16)
            r_compute<1, 1>(g_s2, g_s1, cnt, 1.f, ch, h, zlist + beg, WL);
    } else {
        float* bins = WL;
        for (int i = t; i < GG * 4; i += 256) bins[i] = 0.f;
        __syncthreads();
        const int idx = (blockIdx.x - blocksAB) * 256 + t;
        const int stride = 32 * 256;
        for (int n = idx; n < NN; n += stride) {
            const int b = batch[n];
            const float v0 = ae[z[n]];
            const float v1 = e1n[n];
            const float v2 = e2n[n];
            atomicAdd(&bins[b*4+0], v0 + v1 + v2);
            atomicAdd(&bins[b*4+1], v0);
            atomicAdd(&bins[b*4+2], v1);
            atomicAdd(&bins[b*4+3], v2);
        }
        __syncthreads();
        for (int i = t; i < GG * 4; i += 256) {
            const float v = bins[i];
            if (v != 0.f) {
                const int b = i >> 2;
                const int k = i & 3;
                float* dst = (k == 0) ? &out[b] : &out[GG + b*3 + (k - 1)];
                atomAddF(dst, v);
            }
        }
    }
}

// ---------------- edge pass 1 (rcv-centric gather) ----------------
__global__ __launch_bounds__(256) void rx_edge1(const float* __restrict__ ef, const float* __restrict__ Y1,
                                                 const float* __restrict__ R1, const float* __restrict__ su1,
                                                 const int* __restrict__ row_r, const int2* __restrict__ list_r,
                                                 float* __restrict__ A0, float* __restrict__ A1) {
    __shared__ float RL[2048];
    for (int i = threadIdx.x; i < 2048; i += 256) RL[i] = R1[i];
    __syncthreads();
    const int lane = threadIdx.x & 63;
    const int n = blockIdx.x * 4 + (threadIdx.x >> 6);
    if (n >= NN) return;
    const int c0 = lane;
    const int c1 = lane + 64;
    float a00 = 0.f, a01 = 0.f;
    float ax0 = 0.f, ax1 = 0.f, ay0 = 0.f, ay1 = 0.f, az0 = 0.f, az1 = 0.f;
    const int beg = row_r[n];
    const int end = row_r[n + 1];
    for (int i = beg; i < end; i++) {
        const int2 p = list_r[i];
        const int e = p.x;
        const int sn = p.y;
        const float4 efa = ((const float4*)ef)[e*2];
        const float4 efb4 = ((const float4*)ef)[e*2+1];
        const float y0 = Y1[e*3+0], y1 = Y1[e*3+1], y2 = Y1[e*3+2];
        float wa0 = 0.f, wa1 = 0.f, wb0 = 0.f, wb1 = 0.f;
        const float* eb = (const float*)&efa;
#pragma unroll
        for (int b = 0; b < 8; b++) {
            if (b == 4) eb = (const float*)&efb4;
            const float v = eb[b & 3];
            wa0 += v * RL[b*256 + c0];
            wb0 += v * RL[b*256 + 128 + c0];
            wa1 += v * RL[b*256 + c1];
            wb1 += v * RL[b*256 + 128 + c1];
        }
        const float sj0 = su1[sn*KK + c0];
        const float sj1 = su1[sn*KK + c1];
        a00 += wa0 * sj0;
        a01 += wa1 * sj1;
        const float mb0 = wb0 * sj0;
        const float mb1 = wb1 * sj1;
        ax0 += mb0*y0; ax1 += mb1*y0;
        ay0 += mb0*y1; ay1 += mb1*y1;
        az0 += mb0*y2; az1 += mb1*y2;
    }
    A0[(size_t)n*KK + c0] = a00;
    A0[(size_t)n*KK + c1] = a01;
    float* A1r = A1 + (size_t)n * 384;
    A1r[c0] = ax0;        A1r[c1] = ax1;
    A1r[128 + c0] = ay0;  A1r[128 + c1] = ay1;
    A1r[256 + c0] = az0;  A1r[256 + c1] = az1;
}

// ---------------- edge pass 2 (rcv-centric gather) ----------------
__global__ __launch_bounds__(256) void rx_edge2(const float* __restrict__ ef, const float* __restrict__ Y1,
                                                 const float* __restrict__ R2, const float* __restrict__ s1u2,
                                                 const float* __restrict__ vup,
                                                 const int* __restrict__ row_r, const int2* __restrict__ list_r,
                                                 float* __restrict__ A2) {
    __shared__ float RL[2048];
    for (int i = threadIdx.x; i < 2048; i += 256) RL[i] = R2[(i >> 8) * 512 + (i & 255)];
    __syncthreads();
    const int lane = threadIdx.x & 63;
    const int n = blockIdx.x * 4 + (threadIdx.x >> 6);
    if (n >= NN) return;
    const int c0 = lane;
    const int c1 = lane + 64;
    float a0 = 0.f, a1 = 0.f;
    const int beg = row_r[n];
    const int end = row_r[n + 1];
    for (int i = beg; i < end; i++) {
        const int2 p = list_r[i];
        const int e = p.x;
        const int sn = p.y;
        const float4 efa = ((const float4*)ef)[e*2];
        const float4 efb4 = ((const float4*)ef)[e*2+1];
        const float y0 = Y1[e*3+0], y1 = Y1[e*3+1], y2 = Y1[e*3+2];
        float w00_0 = 0.f, w00_1 = 0.f, w110_0 = 0.f, w110_1 = 0.f;
        const float* eb = (const float*)&efa;
#pragma unroll
        for (int b = 0; b < 8; b++) {
            if (b == 4) eb = (const float*)&efb4;
            const float v = eb[b & 3];
            w00_0  += v * RL[b*256 + c0];
            w110_0 += v * RL[b*256 + 128 + c0];
            w00_1  += v * RL[b*256 + c1];
            w110_1 += v * RL[b*256 + 128 + c1];
        }
        const float sj0 = s1u2[sn*KK + c0];
        const float sj1 = s1u2[sn*KK + c1];
        const float* vu = vup + (size_t)sn * 384;
        const float tt0 = (vu[c0]*y0 + vu[128 + c0]*y1 + vu[256 + c0]*y2) * INV_SQ3;
        const float tt1 = (vu[c1]*y0 + vu[128 + c1]*y1 + vu[256 + c1]*y2) * INV_SQ3;
        a0 += w00_0 * sj0 + w110_0 * tt0;
        a1 += w00_1 * sj1 + w110_1 * tt1;
    }
    A2[(size_t)n*KK + c0] = a0;
    A2[(size_t)n*KK + c1] = a1;
}

// ---------------- MLP energy head + e1 + backward seed ----------------
__global__ __launch_bounds__(128) void rx_mlp(const float* __restrict__ s2, const float* __restrict__ W_mlp,
                                             const float* __restrict__ w_out, const float* __restrict__ w_r1,
                                             const float* __restrict__ s1,
                                             float* __restrict__ g_s2, float* __restrict__ g_s1,
                                             float* __restrict__ e1n, float* __restrict__ e2n) {
    __shared__ float WmL[KK * 17];
    __shared__ float s2L[KK];
    __shared__ float part[128];
    __shared__ float ghL[16];
    __shared__ float eL[16];
    __shared__ float pw[2];
    const int n = blockIdx.x;
    const int t = threadIdx.x;
    for (int i = t; i < KK * 16; i += 128) WmL[(i >> 4) * 17 + (i & 15)] = W_mlp[i];
    s2L[t] = s2[(size_t)n * KK + t];
    const float wr = w_r1[t];
    float p = s1[(size_t)n * KK + t] * wr;
    p = waveRed(p);
    if ((t & 63) == 0) pw[t >> 6] = p;
    __syncthreads();
    {
        const int j = t & 15;
        const int seg = t >> 4;
        float pr = 0.f;
#pragma unroll
        for (int c = 0; c < 16; c++) pr += s2L[seg*16 + c] * WmL[(seg*16 + c) * 17 + j];
        part[t] = pr;
    }
    __syncthreads();
    if (t < 16) {
        float hh = 0.f;
#pragma unroll
        for (int s = 0; s < 8; s++) hh += part[s*16 + t];
        const float sg = 1.f / (1.f + expf(-hh));
        eL[t]  = hh * sg * w_out[t];
        ghL[t] = w_out[t] * sg * (1.f + hh * (1.f - sg));
    }
    __syncthreads();
    if (t == 0) {
        float e = 0.f;
#pragma unroll
        for (int j = 0; j < 16; j++) e += eL[j];
        e2n[n] = e;
        e1n[n] = pw[0] + pw[1];
    }
    float g = 0.f;
#pragma unroll
    for (int j = 0; j < 16; j++) g += ghL[j] * WmL[t * 17 + j];
    g_s2[(size_t)n * KK + t] = g;
    g_s1[(size_t)n * KK + t] = wr;
}

// ---------------- merged backward layer2: per-edge (blocks 0..624) + node sums (625..3124) ----------------
__global__ __launch_bounds__(256) void rx_bwdA(const float* __restrict__ ef8, const float* __restrict__ Y1,
                                                const int2* __restrict__ cei, const int* __restrict__ nact,
                                                const float* __restrict__ R2,
                                                const float* __restrict__ gA2, const float* __restrict__ s1u2,
                                                const float* __restrict__ vup,
                                                const int2* __restrict__ list_s, const int* __restrict__ row_s,
                                                float* __restrict__ gefA, float* __restrict__ gyA,
                                                float* __restrict__ Gsj2, float* __restrict__ Gvj) {
    __shared__ float RL[2048];
    const int t = threadIdx.x;
    if ((int)blockIdx.x < 625) {
        const int i = blockIdx.x * 256 + t;
        if (i >= *nact) return;
        const int2 p = list_s[i];
        const int e = p.x;
        const int rv = p.y;
        const int sn = cei[e].x;
        const float y0 = Y1[e*3+0], y1 = Y1[e*3+1], y2 = Y1[e*3+2];
        const float4 efa = ((const float4*)ef8)[e*2];
        const float4 efb = ((const float4*)ef8)[e*2+1];
        const float efv[8] = {efa.x, efa.y, efa.z, efa.w, efb.x, efb.y, efb.z, efb.w};
        float acc[8] = {0.f,0.f,0.f,0.f,0.f,0.f,0.f,0.f};
        float g0 = 0.f, g1 = 0.f, g2 = 0.f;
        const float4* gaR = (const float4*)(gA2 + (size_t)rv * KK);
        const float4* sjR = (const float4*)(s1u2 + (size_t)sn * KK);
        const float4* vxR = (const float4*)(vup + (size_t)sn * 384);
        const float4* vyR = vxR + 32;
        const float4* vzR = vxR + 64;
        for (int cc = 0; cc < 32; cc++) {
            const float4 ga = gaR[cc];
            const float4 sj = sjR[cc];
            const float4 vx = vxR[cc];
            const float4 vy = vyR[cc];
            const float4 vz = vzR[cc];
#pragma unroll
            for (int k = 0; k < 4; k++) {
                const float gaE = ((const float*)&ga)[k];
                const float sjE = ((const float*)&sj)[k];
                const float vxE = ((const float*)&vx)[k];
                const float vyE = ((const float*)&vy)[k];
                const float vzE = ((const float*)&vz)[k];
                const float tt = (vxE*y0 + vyE*y1 + vzE*y2) * INV_SQ3;
                const float gw00 = gaE * sjE;
                const float gw110 = gaE * tt;
                float w110 = 0.f;
                const int c = cc*4 + k;
#pragma unroll
                for (int b = 0; b < 8; b++) {
                    const float r2a = R2[b*512 + c];
                    const float r2b = R2[b*512 + 128 + c];
                    acc[b] += gw00 * r2a + gw110 * r2b;
                    w110 += efv[b] * r2b;
                }
                const float gt = gaE * w110;
                g0 += gt * vxE;
                g1 += gt * vyE;
                g2 += gt * vzE;
            }
        }
        ((float4*)gefA)[e*2]   = make_float4(acc[0], acc[1], acc[2], acc[3]);
        ((float4*)gefA)[e*2+1] = make_float4(acc[4], acc[5], acc[6], acc[7]);
        gyA[e*3+0] = g0 * INV_SQ3;
        gyA[e*3+1] = g1 * INV_SQ3;
        gyA[e*3+2] = g2 * INV_SQ3;
    } else {
        for (int i = t; i < 2048; i += 256) RL[i] = R2[(i >> 8) * 512 + (i & 255)];
        __syncthreads();
        const int lane = t & 63;
        const int sn = (blockIdx.x - 625) * 4 + (t >> 6);
        if (sn >= NN) return;
        const int c0 = lane;
        const int c1 = lane + 64;
        float gs0 = 0.f, gs1 = 0.f;
        float gv00 = 0.f, gv01 = 0.f, gv10 = 0.f, gv11 = 0.f, gv20 = 0.f, gv21 = 0.f;
        const int beg = row_s[sn];
        const int end = row_s[sn + 1];
        for (int i = beg; i < end; i++) {
            const int2 p = list_s[i];
            const int e = p.x;
            const int rv = p.y;
            const float4 efa = ((const float4*)ef8)[e*2];
            const float4 efb4 = ((const float4*)ef8)[e*2+1];
            const float y0 = Y1[e*3+0], y1 = Y1[e*3+1], y2 = Y1[e*3+2];
            float w00_0 = 0.f, w00_1 = 0.f, w110_0 = 0.f, w110_1 = 0.f;
            const float* eb = (const float*)&efa;
#pragma unroll
            for (int b = 0; b < 8; b++) {
                if (b == 4) eb = (const float*)&efb4;
                const float v = eb[b & 3];
                w00_0  += v * RL[b*256 + c0];
                w110_0 += v * RL[b*256 + 128 + c0];
                w00_1  += v * RL[b*256 + c1];
                w110_1 += v * RL[b*256 + 128 + c1];
            }
            const float ga0 = gA2[(size_t)rv*KK + c0];
            const float ga1 = gA2[(size_t)rv*KK + c1];
            gs0 += ga0 * w00_0;
            gs1 += ga1 * w00_1;
            const float gts0 = ga0 * w110_0 * INV_SQ3;
            const float gts1 = ga1 * w110_1 * INV_SQ3;
            gv00 += gts0*y0; gv01 += gts1*y0;
            gv10 += gts0*y1; gv11 += gts1*y1;
            gv20 += gts0*y2; gv21 += gts1*y2;
        }
        Gsj2[(size_t)sn*KK + c0] = gs0;
        Gsj2[(size_t)sn*KK + c1] = gs1;
        float* Gv = Gvj + (size_t)sn * 384;
        Gv[c0] = gv00;        Gv[c1] = gv01;
        Gv[128 + c0] = gv10;  Gv[128 + c1] = gv11;
        Gv[256 + c0] = gv20;  Gv[256 + c1] = gv21;
    }
}

// ---------------- backward layer1 per-edge + fused force ----------------
__global__ __launch_bounds__(256) void rx_bwdB(const float* __restrict__ ef8, const float* __restrict__ Y1,
                                                const int2* __restrict__ cei, const int* __restrict__ nact,
                                                const float* __restrict__ R1,
                                                const float* __restrict__ su1, const float* __restrict__ gA0,
                                                const float* __restrict__ gA1, const int2* __restrict__ list_r,
                                                const float* __restrict__ gefA, const float* __restrict__ gyA,
                                                const float* __restrict__ defdr, const float* __restrict__ rr,
                                                float* __restrict__ forces) {
    const int i = blockIdx.x * 256 + threadIdx.x;
    if (i >= *nact) return;
    const int2 p = list_r[i];
    const int e = p.x;
    const int sn = p.y;
    const int rv = cei[e].y;
    const float y0 = Y1[e*3+0], y1 = Y1[e*3+1], y2 = Y1[e*3+2];
    const float4 efa = ((const float4*)ef8)[e*2];
    const float4 efb = ((const float4*)ef8)[e*2+1];
    const float efv[8] = {efa.x, efa.y, efa.z, efa.w, efb.x, efb.y, efb.z, efb.w};
    float acc[8] = {0.f,0.f,0.f,0.f,0.f,0.f,0.f,0.f};
    float gg0 = 0.f, gg1 = 0.f, gg2 = 0.f;
    const float4* gmR = (const float4*)(gA0 + (size_t)rv * KK);
    const float4* sjR = (const float4*)(su1 + (size_t)sn * KK);
    const float4* gxR = (const float4*)(gA1 + (size_t)rv * 384);
    const float4* gyR = gxR + 32;
    const float4* gzR = gxR + 64;
    for (int cc = 0; cc < 32; cc++) {
        const float4 gm = gmR[cc];
        const float4 sj = sjR[cc];
        const float4 gx = gxR[cc];
        const float4 gy = gyR[cc];
        const float4 gz = gzR[cc];
#pragma unroll
        for (int k = 0; k < 4; k++) {
            const float gmE = ((const float*)&gm)[k];
            const float sjE = ((const float*)&sj)[k];
            const float g1E = ((const float*)&gx)[k];
            const float g2E = ((const float*)&gy)[k];
            const float g3E = ((const float*)&gz)[k];
            const float q = g1E*y0 + g2E*y1 + g3E*y2;
            const float gwa = gmE * sjE;
            const float gwb = q * sjE;
            float w = 0.f;
            const int c = cc*4 + k;
#pragma unroll
            for (int b = 0; b < 8; b++) {
                const float r1a = R1[b*256 + c];
                const float r1b = R1[b*256 + 128 + c];
                acc[b] += gwa * r1a + gwb * r1b;
                w += efv[b] * r1b;
            }
            const float ws = w * sjE;
            gg0 += g1E * ws;
            gg1 += g2E * ws;
            gg2 += g3E * ws;
        }
    }
    float gr = 0.f;
#pragma unroll
    for (int b = 0; b < 8; b++) gr += (gefA[e*8+b] + acc[b]) * defdr[e*8+b];
    const float g0 = gyA[e*3+0] + gg0;
    const float g1 = gyA[e*3+1] + gg1;
    const float g2 = gyA[e*3+2] + gg2;
    const float ir = 1.f / rr[e];
    const float dot = g0*y0 + g1*y1 + g2*y2;
    const float a = gr * INV_SQ3;
    const float b2 = SQ3F * ir;
    const float c = b2 * dot * (1.f / 3.f);
    const float gv0 = a*y0 + b2*g0 - c*y0;
    const float gv1 = a*y1 + b2*g1 - c*y1;
    const float gv2 = a*y2 + b2*g2 - c*y2;
    atomAddF(&forces[rv*3+0], -gv0);
    atomAddF(&forces[rv*3+1], -gv1);
    atomAddF(&forces[rv*3+2], -gv2);
    atomAddF(&forces[sn*3+0],  gv0);
    atomAddF(&forces[sn*3+1],  gv1);
    atomAddF(&forces[sn*3+2],  gv2);
}

extern "C" void kernel_launch(void* const* d_in, const int* in_sizes, int n_in,
                              void* d_out, int out_size, void* d_ws, size_t ws_size,
                              hipStream_t stream) {
    const float* positions  = (const float*)d_in[0];
    const float* shifts     = (const float*)d_in[1];
    const int*   edge_index = (const int*)d_in[2];
    const int*   node_z     = (const int*)d_in[3];
    const int*   batch      = (const int*)d_in[4];
    const float* atomic_e   = (const float*)d_in[5];
    const float* W_embed    = (const float*)d_in[6];
    const float* R1         = (const float*)d_in[7];
    const float* W_up1      = (const float*)d_in[8];
    const float* W_mix_s1   = (const float*)d_in[9];
    const float* W_mix_v1   = (const float*)d_in[10];
    const float* W_sk_s1    = (const float*)d_in[11];
    const float* w_r1       = (const float*)d_in[12];
    const float* R2         = (const float*)d_in[13];
    const float* W_up2s     = (const float*)d_in[14];
    const float* W_up2v     = (const float*)d_in[15];
    const float* W_mix_s2   = (const float*)d_in[16];
    const float* W_sk_s2    = (const float*)d_in[17];
    const float* W_mlp      = (const float*)d_in[18];
    const float* w_out      = (const float*)d_in[19];

    float* out = (float*)d_out;
    float* ws = (float*)d_ws;
    size_t off = 0;
    float* ef    = ws + off; off += (size_t)EE * 8;
    float* defdr = ws + off; off += (size_t)EE * 8;
    float* Y1    = ws + off; off += (size_t)EE * 3;
    float* rr    = ws + off; off += (size_t)EE;
    float* gefA  = ws + off; off += (size_t)EE * 8;
    float* gyA   = ws + off; off += (size_t)EE * 3;
    float* su1   = ws + off; off += (size_t)NN * KK;
    float* s1    = ws + off; off += (size_t)NN * KK;
    float* s1u2  = ws + off; off += (size_t)NN * KK;
    float* s2    = ws + off; off += (size_t)NN * KK;
    float* g_s2  = ws + off; off += (size_t)NN * KK;
    float* g_s1  = ws + off; off += (size_t)NN * KK;
    float* vup   = ws + off; off += (size_t)NN * KK * 3;
    float* A0    = ws + off; off += (size_t)NN * KK;
    float* A2    = ws + off; off += (size_t)NN * KK;
    float* Gsj2  = ws + off; off += (size_t)NN * KK;
    float* A1    = ws + off; off += (size_t)NN * KK * 3;
    float* Gvj   = ws + off; off += (size_t)NN * KK * 3;
    float* E1    = ws + off; off += 10 * KK;
    float* T1    = ws + off; off += 10 * KK;
    float* Wc    = ws + off; off += KK * KK;
    float* e1n   = ws + off; off += NN;
    float* e2n   = ws + off; off += NN;
    int* ip = (int*)(ws + off);
    size_t ioff = 0;
    int* deg_r = ip + ioff; ioff += NN;
    int* deg_s = ip + ioff; ioff += NN;
    int* cur_r = ip + ioff; ioff += NN;
    int* cur_s = ip + ioff; ioff += NN;
    int* zcnt  = ip + ioff; ioff += 16;
    int* zcur  = ip + ioff; ioff += 16;
    int* nact  = ip + ioff; ioff += 16;
    int* row_r = ip + ioff; ioff += NN + 2;
    int* row_s = ip + ioff; ioff += NN + 2;
    int* zrow  = ip + ioff; ioff += 16;
    int* zlist = ip + ioff; ioff += NN;
    int2* cei    = (int2*)(ip + ioff); ioff += (size_t)EE * 2;
    int2* list_r = (int2*)(ip + ioff); ioff += (size_t)EE * 2;
    int2* list_s = (int2*)(ip + ioff); ioff += (size_t)EE * 2;

    hipMemsetAsync(out, 0, (size_t)out_size * sizeof(float), stream);
    hipMemsetAsync(deg_r, 0, ((size_t)4 * NN + 48) * sizeof(int), stream);

    const int EG = (EE + 255) / 256;                // 625
    const int BNB  = ((NN + 63) / 64) * 2;          // 314
    const int BN3B = ((NN * 3 + 63) / 64) * 2;      // 938
    const int BS   = NE * 32;                       // 320
    rx_geom<<<EG, 256, 0, stream>>>(positions, shifts, edge_index, ef, defdr, Y1, rr, cei, nact, deg_r, deg_s);
    rx_tab<<<54, 256, 0, stream>>>(node_z, zcnt, W_embed, W_up1, W_sk_s1, E1, T1,
                                   W_mix_v1, W_up2v, Wc);
    rx_scan<<<1, 1024, 0, stream>>>(deg_r, deg_s, zcnt, row_r, row_s, zrow);
    rx_fill3<<<665 + (NN * KK) / 256, 256, 0, stream>>>(cei, nact, row_r, row_s, cur_r, cur_s,
                                                        list_r, list_s, node_z, zcur, zrow, zlist,
                                                        E1, T1, su1, s1);
    rx_edge1<<<(NN + 3) / 4, 256, 0, stream>>>(ef, Y1, R1, su1, row_r, list_r, A0, A1);
    rx_two<0, 1, 0, 0><<<BNB + BN3B, 256, 0, stream>>>(A0, W_mix_s1, s1, NN, INV_AVG,
                                                       A1, Wc, vup, NN * 3, INV_AVG, BNB);
    rx_mix<0, 0, 0, 0><<<BNB + BS, 256, 0, stream>>>(s1, W_up2s, s1u2, NN, 1.f,
                                                     s1, W_sk_s2, s2, zrow, zlist, BNB);
    rx_edge2<<<(NN + 3) / 4, 256, 0, stream>>>(ef, Y1, R2, s1u2, vup, row_r, list_r, A2);
    rx_one<0, 1><<<BNB, 256, 0, stream>>>(A2, W_mix_s2, s2, NN, INV_AVG);
    rx_mlp<<<NN, 128, 0, stream>>>(s2, W_mlp, w_out, w_r1, s1, g_s2, g_s1, e1n, e2n);
    rx_bwdmix<<<BNB + BS + 32, 256, 0, stream>>>(g_s2, W_mix_s2, A2, W_sk_s2, g_s1,
                                                 zrow, zlist, node_z, batch, atomic_e,
                                                 e1n, e2n, out, BNB, BNB + BS);
    rx_bwdA<<<625 + (NN + 3) / 4, 256, 0, stream>>>(ef, Y1, cei, nact, R2, A2, s1u2, vup,
                                                    list_s, row_s, gefA, gyA, Gsj2, Gvj);
    rx_two<1, 0, 1, 1><<<BN3B + BNB, 256, 0, stream>>>(Gvj, Wc, A1, NN * 3, INV_AVG,
                                                       Gsj2, W_up2s, g_s1, NN, 1.f, BN3B);
    rx_one<1, 0><<<BNB, 256, 0, stream>>>(g_s1, W_mix_s1, A0, NN, INV_AVG);
    rx_bwdB<<<EG, 256, 0, stream>>>(ef, Y1, cei, nact, R1, su1, A0, A1, list_r,
                                    gefA, gyA, defdr, rr, out + GG + GG * 3);
}

// Round 19
// 359.637 us; speedup vs baseline: 1.1529x; 1.0250x over previous
//
#include <hip/hip_runtime.h>
#include <math.h>

#define NN 10000
#define EE 160000
#define KK 128
#define GG 16
#define NE 10
#define SQ3F 1.7320508075688772f
#define INV_SQ3 0.57735026918962576f
#define INV_AVG 0.0625f
#define RMAXI 0.2f

__device__ __forceinline__ void atomAddF(float* p, float v) { unsafeAtomicAdd(p, v); }

__device__ __forceinline__ float waveRed(float v) {
#pragma unroll
    for (int m = 32; m >= 1; m >>= 1) v += __shfl_xor(v, m);
    return v;
}

// ============ dense core: tile 64 rows x 64 cols, 32KB LDS, thread = 4x4 ============
template <int TRANS>
__device__ __forceinline__ void s_stage(const float* __restrict__ W, int h, float* WL) {
    const int t = threadIdx.x;
    for (int i = t; i < KK * 64; i += 256) {
        int k, c;
        float v;
        if (!TRANS) { k = i >> 6; c = i & 63; v = W[k * KK + (h * 64 + c)]; }
        else        { c = i >> 7; k = i & 127; v = W[(h * 64 + c) * KK + k]; }
        WL[k * 64 + ((((c >> 2) + k) & 15) << 2) + (c & 3)] = v;
    }
}

template <int ACCUM, int GATHER>
__device__ __forceinline__ void s_compute(const float* __restrict__ in, float* __restrict__ out,
                                          int rows, float alpha, int bid_row, int h,
                                          const int* __restrict__ rowlist, const float* WL) {
    const int t = threadIdx.x;
    const int g0 = t & 15;
    const int cg = g0 << 2;
    const int i0 = bid_row * 64 + ((t >> 4) << 2);
    int rowv[4];
    const float* Ap[4];
#pragma unroll
    for (int j = 0; j < 4; j++) {
        int idx = i0 + j;
        if (idx > rows - 1) idx = rows - 1;
        rowv[j] = GATHER ? rowlist[idx] : idx;
        Ap[j] = in + (size_t)rowv[j] * KK;
    }
    float acc[4][4];
#pragma unroll
    for (int j = 0; j < 4; j++) { acc[j][0] = 0.f; acc[j][1] = 0.f; acc[j][2] = 0.f; acc[j][3] = 0.f; }
#pragma unroll 2
    for (int k = 0; k < KK; k += 4) {
        const float4 w0 = *(const float4*)&WL[(k+0)*64 + (((g0 + k + 0) & 15) << 2)];
        const float4 w1 = *(const float4*)&WL[(k+1)*64 + (((g0 + k + 1) & 15) << 2)];
        const float4 w2 = *(const float4*)&WL[(k+2)*64 + (((g0 + k + 2) & 15) << 2)];
        const float4 w3 = *(const float4*)&WL[(k+3)*64 + (((g0 + k + 3) & 15) << 2)];
#pragma unroll
        for (int j = 0; j < 4; j++) {
            const float4 a = *(const float4*)(Ap[j] + k);
            acc[j][0] += a.x*w0.x + a.y*w1.x + a.z*w2.x + a.w*w3.x;
            acc[j][1] += a.x*w0.y + a.y*w1.y + a.z*w2.y + a.w*w3.y;
            acc[j][2] += a.x*w0.z + a.y*w1.z + a.z*w2.z + a.w*w3.z;
            acc[j][3] += a.x*w0.w + a.y*w1.w + a.z*w2.w + a.w*w3.w;
        }
    }
    const int co = h * 64 + cg;
#pragma unroll
    for (int j = 0; j < 4; j++) {
        if (i0 + j < rows) {
            float4* o = (float4*)(out + (size_t)rowv[j] * KK + co);
            float4 v = make_float4(acc[j][0]*alpha, acc[j][1]*alpha, acc[j][2]*alpha, acc[j][3]*alpha);
            if (ACCUM) {
                const float4 old = *o;
                v.x += old.x; v.y += old.y; v.z += old.z; v.w += old.w;
            }
            *o = v;
        }
    }
}

// ---------------- zero-init: out (blocks 0..zb-1) + int counters (rest) ----------------
__global__ __launch_bounds__(256) void sz_zero(float* __restrict__ out, int out_size,
                                               int* __restrict__ ints, int icount, int zb) {
    const int t = threadIdx.x;
    if ((int)blockIdx.x < zb) {
        const int i = blockIdx.x * 256 + t;
        if (i < out_size) out[i] = 0.f;
    } else {
        const int i = (blockIdx.x - zb) * 256 + t;
        if (i < icount) ints[i] = 0;
    }
}

// ---------------- merged: geometry+compaction (0..624) + zcount (625..664) + tables (665..674) + Wc (675..678) ----------------
__global__ __launch_bounds__(256) void sz_geomtab(const float* __restrict__ pos, const float* __restrict__ shifts,
                            const int* __restrict__ ei,
                            float* __restrict__ ef, float* __restrict__ defdr,
                            float* __restrict__ Y1, float* __restrict__ rr,
                            int2* __restrict__ cei, int* __restrict__ nact,
                            int* __restrict__ deg_r, int* __restrict__ deg_s,
                            const int* __restrict__ z, int* __restrict__ zcnt,
                            const float* __restrict__ We, const float* __restrict__ Wup1,
                            const float* __restrict__ Wsk1,
                            float* __restrict__ E1, float* __restrict__ T1,
                            const float* __restrict__ Wmv1, const float* __restrict__ Wu2v,
                            float* __restrict__ Wc) {
    __shared__ float WL[KK * 64];
    const int t = threadIdx.x;
    if ((int)blockIdx.x < 625) {
        int* lcnt = (int*)WL;
        int* lbase = ((int*)WL) + 1;
        if (t == 0) *lcnt = 0;
        __syncthreads();
        const int e = blockIdx.x * 256 + t;
        const int sn = ei[e];
        const int rv = ei[EE + e];
        const float vx = pos[rv*3+0] - pos[sn*3+0] + shifts[e*3+0];
        const float vy = pos[rv*3+1] - pos[sn*3+1] + shifts[e*3+1];
        const float vz = pos[rv*3+2] - pos[sn*3+2] + shifts[e*3+2];
        const float r = sqrtf(vx*vx + vy*vy + vz*vz + 1e-12f);
        const float x = r * RMAXI;
        const int active = (x < 1.0f) ? 1 : 0;
        int pos_l = 0;
        if (active) pos_l = atomicAdd(lcnt, 1);
        __syncthreads();
        if (t == 0 && *lcnt > 0) *lbase = atomicAdd(nact, *lcnt);
        __syncthreads();
        if (!active) return;
        const int idx = *lbase + pos_l;
        cei[idx] = make_int2(sn, rv);
        atomicAdd(&deg_s[sn], 1);
        atomicAdd(&deg_r[rv], 1);
        const float ir = 1.0f / r;
        rr[idx] = r;
        Y1[idx*3+0] = SQ3F*vx*ir;
        Y1[idx*3+1] = SQ3F*vy*ir;
        Y1[idx*3+2] = SQ3F*vz*ir;
        const float x2 = x*x, x4 = x2*x2, x5 = x4*x, x6 = x5*x, x7 = x6*x;
        const float fc  = 1.0f - 21.0f*x5 + 35.0f*x6 - 15.0f*x7;
        const float dfc = (-105.0f*x4 + 210.0f*x5 - 105.0f*x6) * RMAXI;
        const float C = 0.63245553203367587f;
        float4 efa, efb4, da, db;
        float* efp = (float*)&efa;
        float* dp  = (float*)&da;
#pragma unroll
        for (int b = 0; b < 8; b++) {
            const float kb = (float)(b + 1) * 0.62831853071795865f;
            float sb, cb;
            sincosf(kb * r, &sb, &cb);
            const float bess  = C * sb * ir;
            const float dbess = C * ir * (kb * cb - sb * ir);
            if (b == 4) { efp = (float*)&efb4; dp = (float*)&db; }
            efp[b & 3] = bess * fc;
            dp[b & 3]  = dbess * fc + bess * dfc;
        }
        ((float4*)ef)[idx*2]    = efa;
        ((float4*)ef)[idx*2+1]  = efb4;
        ((float4*)defdr)[idx*2]   = da;
        ((float4*)defdr)[idx*2+1] = db;
    } else if ((int)blockIdx.x < 665) {
        int* h = (int*)WL;
        if (t < NE) h[t] = 0;
        __syncthreads();
        const int n = (blockIdx.x - 625) * 256 + t;
        if (n < NN) atomicAdd(&h[z[n]], 1);
        __syncthreads();
        if (t < NE && h[t] > 0) atomicAdd(&zcnt[t], h[t]);
    } else if ((int)blockIdx.x < 675) {
        const int zz = blockIdx.x - 665;
        if (t < KK) {
            float a = 0.f, bv = 0.f;
            for (int c = 0; c < KK; c++) {
                const float w = We[zz*KK + c];
                a  += w * Wup1[c*KK + t];
                bv += w * Wsk1[(size_t)(zz*KK + c)*KK + t];
            }
            E1[zz*KK + t] = a;
            T1[zz*KK + t] = bv;
        }
    } else {
        const int b = blockIdx.x - 675;      // 0..3
        const int h = b & 1;
        s_stage<0>(Wu2v, h, WL);             // Wc = Wmv1 @ Wu2v
        __syncthreads();
        s_compute<0, 0>(Wmv1, Wc, KK, 1.f, b >> 1, h, nullptr, WL);
    }
}

// ---------------- scans ----------------
__global__ __launch_bounds__(1024) void sz_scan(const int* __restrict__ deg_r, const int* __restrict__ deg_s,
                                               const int* __restrict__ zcnt,
                                               int* __restrict__ row_r, int* __restrict__ row_s,
                                               int* __restrict__ zrow) {
    __shared__ int part[1024];
    const int t = threadIdx.x;
    if (t == 0) {
        int s = 0;
        for (int i = 0; i < NE; i++) { zrow[i] = s; s += zcnt[i]; }
        zrow[NE] = s;
    }
    for (int a = 0; a < 2; a++) {
        const int* deg = a ? deg_s : deg_r;
        int* row = a ? row_s : row_r;
        const int base = t * 10;
        int loc[10];
        int s = 0;
#pragma unroll
        for (int k = 0; k < 10; k++) {
            loc[k] = s;
            if (base + k < NN) s += deg[base + k];
        }
        part[t] = s;
        __syncthreads();
        for (int off = 1; off < 1024; off <<= 1) {
            const int v = (t >= off) ? part[t - off] : 0;
            __syncthreads();
            part[t] += v;
            __syncthreads();
        }
        const int bex = (t > 0) ? part[t - 1] : 0;
#pragma unroll
        for (int k = 0; k < 10; k++)
            if (base + k < NN) row[base + k] = bex + loc[k];
        if (t == 1023) row[NN] = part[1023];
        __syncthreads();
    }
}

// ---------------- merged: CSR fill (0..624) + zfill (625..664) + zinit (665..5664) ----------------
__global__ __launch_bounds__(256) void sz_fill3(const int2* __restrict__ cei, const int* __restrict__ nact,
                       const int* __restrict__ row_r, const int* __restrict__ row_s,
                       int* __restrict__ cur_r, int* __restrict__ cur_s,
                       int2* __restrict__ list_r, int2* __restrict__ list_s,
                       const int* __restrict__ z, int* __restrict__ zcur,
                       const int* __restrict__ zrow, int* __restrict__ zlist,
                       const float* __restrict__ E1, const float* __restrict__ T1,
                       float* __restrict__ su1, float* __restrict__ s1) {
    const int t = threadIdx.x;
    if ((int)blockIdx.x < 625) {
        const int i = blockIdx.x * 256 + t;
        if (i >= *nact) return;
        const int2 p = cei[i];
        const int pr = atomicAdd(&cur_r[p.y], 1);
        list_r[row_r[p.y] + pr] = make_int2(i, p.x);
        const int ps = atomicAdd(&cur_s[p.x], 1);
        list_s[row_s[p.x] + ps] = make_int2(i, p.y);
    } else if ((int)blockIdx.x < 665) {
        __shared__ int cnt[NE];
        __shared__ int base[NE];
        if (t < NE) cnt[t] = 0;
        __syncthreads();
        const int n = (blockIdx.x - 625) * 256 + t;
        int pos = -1, zz = 0;
        if (n < NN) { zz = z[n]; pos = atomicAdd(&cnt[zz], 1); }
        __syncthreads();
        if (t < NE && cnt[t] > 0) base[t] = atomicAdd(&zcur[t], cnt[t]);
        __syncthreads();
        if (n < NN) zlist[zrow[zz] + base[zz] + pos] = n;
    } else {
        const int i = (blockIdx.x - 665) * 256 + t;
        if (i >= NN * KK) return;
        const int base = z[i >> 7] * KK + (i & 127);
        su1[i] = E1[base];
        s1[i]  = T1[base];
    }
}

// ---- single dense op ----
template <int TRANS, int ACCUM>
__global__ __launch_bounds__(256) void sz_one(const float* __restrict__ in, const float* __restrict__ W,
                                              float* __restrict__ out, int rows, float alpha) {
    __shared__ float WL[KK * 64];
    const int h = blockIdx.x & 1;
    s_stage<TRANS>(W, h, WL);
    __syncthreads();
    s_compute<ACCUM, 0>(in, out, rows, alpha, blockIdx.x >> 1, h, nullptr, WL);
}

// ---- two dense ops, one dispatch ----
template <int TA, int AA, int TB, int AB>
__global__ __launch_bounds__(256) void sz_two(
        const float* __restrict__ inA, const float* __restrict__ WA, float* __restrict__ outA,
        int rowsA, float alphaA,
        const float* __restrict__ inB, const float* __restrict__ WB, float* __restrict__ outB,
        int rowsB, float alphaB, int blocksA) {
    __shared__ float WL[KK * 64];
    if ((int)blockIdx.x < blocksA) {
        const int h = blockIdx.x & 1;
        s_stage<TA>(WA, h, WL);
        __syncthreads();
        s_compute<AA, 0>(inA, outA, rowsA, alphaA, blockIdx.x >> 1, h, nullptr, WL);
    } else {
        const int b = blockIdx.x - blocksA;
        const int h = b & 1;
        s_stage<TB>(WB, h, WL);
        __syncthreads();
        s_compute<AB, 0>(inB, outB, rowsB, alphaB, b >> 1, h, nullptr, WL);
    }
}

// ---- dense op + per-z skip buckets, one dispatch ----
template <int TA, int AA, int TS, int AS>
__global__ __launch_bounds__(256) void sz_mix(
        const float* __restrict__ inA, const float* __restrict__ WA, float* __restrict__ outA,
        int rowsA, float alphaA,
        const float* __restrict__ inS, const float* __restrict__ Wall, float* __restrict__ outS,
        const int* __restrict__ zrow, const int* __restrict__ zlist, int blocksA) {
    __shared__ float WL[KK * 64];
    if ((int)blockIdx.x < blocksA) {
        const int h = blockIdx.x & 1;
        s_stage<TA>(WA, h, WL);
        __syncthreads();
        s_compute<AA, 0>(inA, outA, rowsA, alphaA, blockIdx.x >> 1, h, nullptr, WL);
    } else {
        const int sbid = blockIdx.x - blocksA;
        const int zz = sbid % NE;
        const int q = sbid / NE;
        const int h = q & 1;
        const int ch0 = q >> 1;
        const int beg = zrow[zz];
        const int cnt = zrow[zz + 1] - beg;
        if (ch0 * 64 >= cnt) return;
        s_stage<TS>(Wall + (size_t)zz * (KK * KK), h, WL);
        __syncthreads();
        for (int ch = ch0; ch * 64 < cnt; ch += 16)
            s_compute<AS, 1>(inS, outS, cnt, 1.f, ch, h, zlist + beg, WL);
    }
}

// ---- backward bundle: dense g_A2 + skip bwd accum + energy (last 32) ----
__global__ __launch_bounds__(256) void sz_bwdmix(
        const float* __restrict__ g_s2, const float* __restrict__ Wms2, float* __restrict__ gA2,
        const float* __restrict__ Wsk2, float* __restrict__ g_s1,
        const int* __restrict__ zrow, const int* __restrict__ zlist,
        const int* __restrict__ z, const int* __restrict__ batch, const float* __restrict__ ae,
        const float* __restrict__ e1n, const float* __restrict__ e2n, float* __restrict__ out,
        int blocksA, int blocksAB) {
    __shared__ float WL[KK * 64];
    const int t = threadIdx.x;
    if ((int)blockIdx.x < blocksA) {
        const int h = blockIdx.x & 1;
        s_stage<1>(Wms2, h, WL);
        __syncthreads();
        s_compute<0, 0>(g_s2, gA2, NN, INV_AVG, blockIdx.x >> 1, h, nullptr, WL);
    } else if ((int)blockIdx.x < blocksAB) {
        const int sbid = blockIdx.x - blocksA;
        const int zz = sbid % NE;
        const int q = sbid / NE;
        const int h = q & 1;
        const int ch0 = q >> 1;
        const int beg = zrow[zz];
        const int cnt = zrow[zz + 1] - beg;
        if (ch0 * 64 >= cnt) return;
        s_stage<1>(Wsk2 + (size_t)zz * (KK * KK), h, WL);
        __syncthreads();
        for (int ch = ch0; ch * 64 < cnt; ch += 16)
            s_compute<1, 1>(g_s2, g_s1, cnt, 1.f, ch, h, zlist + beg, WL);
    } else {
        float* bins = WL;
        for (int i = t; i < GG * 4; i += 256) bins[i] = 0.f;
        __syncthreads();
        const int idx = (blockIdx.x - blocksAB) * 256 + t;
        const int stride = 32 * 256;
        for (int n = idx; n < NN; n += stride) {
            const int b = batch[n];
            const float v0 = ae[z[n]];
            const float v1 = e1n[n];
            const float v2 = e2n[n];
            atomicAdd(&bins[b*4+0], v0 + v1 + v2);
            atomicAdd(&bins[b*4+1], v0);
            atomicAdd(&bins[b*4+2], v1);
            atomicAdd(&bins[b*4+3], v2);
        }
        __syncthreads();
        for (int i = t; i < GG * 4; i += 256) {
            const float v = bins[i];
            if (v != 0.f) {
                const int b = i >> 2;
                const int k = i & 3;
                float* dst = (k == 0) ? &out[b] : &out[GG + b*3 + (k - 1)];
                atomAddF(dst, v);
            }
        }
    }
}

// ---------------- edge pass 1 (rcv-centric gather) ----------------
__global__ __launch_bounds__(256) void sz_edge1(const float* __restrict__ ef, const float* __restrict__ Y1,
                                                 const float* __restrict__ R1, const float* __restrict__ su1,
                                                 const int* __restrict__ row_r, const int2* __restrict__ list_r,
                                                 float* __restrict__ A0, float* __restrict__ A1) {
    __shared__ float RL[2048];
    for (int i = threadIdx.x; i < 2048; i += 256) RL[i] = R1[i];
    __syncthreads();
    const int lane = threadIdx.x & 63;
    const int n = blockIdx.x * 4 + (threadIdx.x >> 6);
    if (n >= NN) return;
    const int c0 = lane;
    const int c1 = lane + 64;
    float a00 = 0.f, a01 = 0.f;
    float ax0 = 0.f, ax1 = 0.f, ay0 = 0.f, ay1 = 0.f, az0 = 0.f, az1 = 0.f;
    const int beg = row_r[n];
    const int end = row_r[n + 1];
    for (int i = beg; i < end; i++) {
        const int2 p = list_r[i];
        const int e = p.x;
        const int sn = p.y;
        const float4 efa = ((const float4*)ef)[e*2];
        const float4 efb4 = ((const float4*)ef)[e*2+1];
        const float y0 = Y1[e*3+0], y1 = Y1[e*3+1], y2 = Y1[e*3+2];
        float wa0 = 0.f, wa1 = 0.f, wb0 = 0.f, wb1 = 0.f;
        const float* eb = (const float*)&efa;
#pragma unroll
        for (int b = 0; b < 8; b++) {
            if (b == 4) eb = (const float*)&efb4;
            const float v = eb[b & 3];
            wa0 += v * RL[b*256 + c0];
            wb0 += v * RL[b*256 + 128 + c0];
            wa1 += v * RL[b*256 + c1];
            wb1 += v * RL[b*256 + 128 + c1];
        }
        const float sj0 = su1[sn*KK + c0];
        const float sj1 = su1[sn*KK + c1];
        a00 += wa0 * sj0;
        a01 += wa1 * sj1;
        const float mb0 = wb0 * sj0;
        const float mb1 = wb1 * sj1;
        ax0 += mb0*y0; ax1 += mb1*y0;
        ay0 += mb0*y1; ay1 += mb1*y1;
        az0 += mb0*y2; az1 += mb1*y2;
    }
    A0[(size_t)n*KK + c0] = a00;
    A0[(size_t)n*KK + c1] = a01;
    float* A1r = A1 + (size_t)n * 384;
    A1r[c0] = ax0;        A1r[c1] = ax1;
    A1r[128 + c0] = ay0;  A1r[128 + c1] = ay1;
    A1r[256 + c0] = az0;  A1r[256 + c1] = az1;
}

// ---------------- edge pass 2 (rcv-centric gather) ----------------
__global__ __launch_bounds__(256) void sz_edge2(const float* __restrict__ ef, const float* __restrict__ Y1,
                                                 const float* __restrict__ R2, const float* __restrict__ s1u2,
                                                 const float* __restrict__ vup,
                                                 const int* __restrict__ row_r, const int2* __restrict__ list_r,
                                                 float* __restrict__ A2) {
    __shared__ float RL[2048];
    for (int i = threadIdx.x; i < 2048; i += 256) RL[i] = R2[(i >> 8) * 512 + (i & 255)];
    __syncthreads();
    const int lane = threadIdx.x & 63;
    const int n = blockIdx.x * 4 + (threadIdx.x >> 6);
    if (n >= NN) return;
    const int c0 = lane;
    const int c1 = lane + 64;
    float a0 = 0.f, a1 = 0.f;
    const int beg = row_r[n];
    const int end = row_r[n + 1];
    for (int i = beg; i < end; i++) {
        const int2 p = list_r[i];
        const int e = p.x;
        const int sn = p.y;
        const float4 efa = ((const float4*)ef)[e*2];
        const float4 efb4 = ((const float4*)ef)[e*2+1];
        const float y0 = Y1[e*3+0], y1 = Y1[e*3+1], y2 = Y1[e*3+2];
        float w00_0 = 0.f, w00_1 = 0.f, w110_0 = 0.f, w110_1 = 0.f;
        const float* eb = (const float*)&efa;
#pragma unroll
        for (int b = 0; b < 8; b++) {
            if (b == 4) eb = (const float*)&efb4;
            const float v = eb[b & 3];
            w00_0  += v * RL[b*256 + c0];
            w110_0 += v * RL[b*256 + 128 + c0];
            w00_1  += v * RL[b*256 + c1];
            w110_1 += v * RL[b*256 + 128 + c1];
        }
        const float sj0 = s1u2[sn*KK + c0];
        const float sj1 = s1u2[sn*KK + c1];
        const float* vu = vup + (size_t)sn * 384;
        const float tt0 = (vu[c0]*y0 + vu[128 + c0]*y1 + vu[256 + c0]*y2) * INV_SQ3;
        const float tt1 = (vu[c1]*y0 + vu[128 + c1]*y1 + vu[256 + c1]*y2) * INV_SQ3;
        a0 += w00_0 * sj0 + w110_0 * tt0;
        a1 += w00_1 * sj1 + w110_1 * tt1;
    }
    A2[(size_t)n*KK + c0] = a0;
    A2[(size_t)n*KK + c1] = a1;
}

// ---------------- MLP energy head + e1 + backward seed ----------------
__global__ __launch_bounds__(128) void sz_mlp(const float* __restrict__ s2, const float* __restrict__ W_mlp,
                                             const float* __restrict__ w_out, const float* __restrict__ w_r1,
                                             const float* __restrict__ s1,
                                             float* __restrict__ g_s2, float* __restrict__ g_s1,
                                             float* __restrict__ e1n, float* __restrict__ e2n) {
    __shared__ float WmL[KK * 17];
    __shared__ float s2L[KK];
    __shared__ float part[128];
    __shared__ float ghL[16];
    __shared__ float eL[16];
    __shared__ float pw[2];
    const int n = blockIdx.x;
    const int t = threadIdx.x;
    for (int i = t; i < KK * 16; i += 128) WmL[(i >> 4) * 17 + (i & 15)] = W_mlp[i];
    s2L[t] = s2[(size_t)n * KK + t];
    const float wr = w_r1[t];
    float p = s1[(size_t)n * KK + t] * wr;
    p = waveRed(p);
    if ((t & 63) == 0) pw[t >> 6] = p;
    __syncthreads();
    {
        const int j = t & 15;
        const int seg = t >> 4;
        float pr = 0.f;
#pragma unroll
        for (int c = 0; c < 16; c++) pr += s2L[seg*16 + c] * WmL[(seg*16 + c) * 17 + j];
        part[t] = pr;
    }
    __syncthreads();
    if (t < 16) {
        float hh = 0.f;
#pragma unroll
        for (int s = 0; s < 8; s++) hh += part[s*16 + t];
        const float sg = 1.f / (1.f + expf(-hh));
        eL[t]  = hh * sg * w_out[t];
        ghL[t] = w_out[t] * sg * (1.f + hh * (1.f - sg));
    }
    __syncthreads();
    if (t == 0) {
        float e = 0.f;
#pragma unroll
        for (int j = 0; j < 16; j++) e += eL[j];
        e2n[n] = e;
        e1n[n] = pw[0] + pw[1];
    }
    float g = 0.f;
#pragma unroll
    for (int j = 0; j < 16; j++) g += ghL[j] * WmL[t * 17 + j];
    g_s2[(size_t)n * KK + t] = g;
    g_s1[(size_t)n * KK + t] = wr;
}

// ---------------- merged backward layer2: per-edge (0..624) + node sums (625..3124) ----------------
__global__ __launch_bounds__(256) void sz_bwdA(const float* __restrict__ ef8, const float* __restrict__ Y1,
                                                const int2* __restrict__ cei, const int* __restrict__ nact,
                                                const float* __restrict__ R2,
                                                const float* __restrict__ gA2, const float* __restrict__ s1u2,
                                                const float* __restrict__ vup,
                                                const int2* __restrict__ list_s, const int* __restrict__ row_s,
                                                float* __restrict__ gefA, float* __restrict__ gyA,
                                                float* __restrict__ Gsj2, float* __restrict__ Gvj) {
    __shared__ float RL[2048];
    const int t = threadIdx.x;
    if ((int)blockIdx.x < 625) {
        const int i = blockIdx.x * 256 + t;
        if (i >= *nact) return;
        const int2 p = list_s[i];
        const int e = p.x;
        const int rv = p.y;
        const int sn = cei[e].x;
        const float y0 = Y1[e*3+0], y1 = Y1[e*3+1], y2 = Y1[e*3+2];
        const float4 efa = ((const float4*)ef8)[e*2];
        const float4 efb = ((const float4*)ef8)[e*2+1];
        const float efv[8] = {efa.x, efa.y, efa.z, efa.w, efb.x, efb.y, efb.z, efb.w};
        float acc[8] = {0.f,0.f,0.f,0.f,0.f,0.f,0.f,0.f};
        float g0 = 0.f, g1 = 0.f, g2 = 0.f;
        const float4* gaR = (const float4*)(gA2 + (size_t)rv * KK);
        const float4* sjR = (const float4*)(s1u2 + (size_t)sn * KK);
        const float4* vxR = (const float4*)(vup + (size_t)sn * 384);
        const float4* vyR = vxR + 32;
        const float4* vzR = vxR + 64;
        for (int cc = 0; cc < 32; cc++) {
            const float4 ga = gaR[cc];
            const float4 sj = sjR[cc];
            const float4 vx = vxR[cc];
            const float4 vy = vyR[cc];
            const float4 vz = vzR[cc];
#pragma unroll
            for (int k = 0; k < 4; k++) {
                const float gaE = ((const float*)&ga)[k];
                const float sjE = ((const float*)&sj)[k];
                const float vxE = ((const float*)&vx)[k];
                const float vyE = ((const float*)&vy)[k];
                const float vzE = ((const float*)&vz)[k];
                const float tt = (vxE*y0 + vyE*y1 + vzE*y2) * INV_SQ3;
                const float gw00 = gaE * sjE;
                const float gw110 = gaE * tt;
                float w110 = 0.f;
                const int c = cc*4 + k;
#pragma unroll
                for (int b = 0; b < 8; b++) {
                    const float r2a = R2[b*512 + c];
                    const float r2b = R2[b*512 + 128 + c];
                    acc[b] += gw00 * r2a + gw110 * r2b;
                    w110 += efv[b] * r2b;
                }
                const float gt = gaE * w110;
                g0 += gt * vxE;
                g1 += gt * vyE;
                g2 += gt * vzE;
            }
        }
        ((float4*)gefA)[e*2]   = make_float4(acc[0], acc[1], acc[2], acc[3]);
        ((float4*)gefA)[e*2+1] = make_float4(acc[4], acc[5], acc[6], acc[7]);
        gyA[e*3+0] = g0 * INV_SQ3;
        gyA[e*3+1] = g1 * INV_SQ3;
        gyA[e*3+2] = g2 * INV_SQ3;
    } else {
        for (int i = t; i < 2048; i += 256) RL[i] = R2[(i >> 8) * 512 + (i & 255)];
        __syncthreads();
        const int lane = t & 63;
        const int sn = (blockIdx.x - 625) * 4 + (t >> 6);
        if (sn >= NN) return;
        const int c0 = lane;
        const int c1 = lane + 64;
        float gs0 = 0.f, gs1 = 0.f;
        float gv00 = 0.f, gv01 = 0.f, gv10 = 0.f, gv11 = 0.f, gv20 = 0.f, gv21 = 0.f;
        const int beg = row_s[sn];
        const int end = row_s[sn + 1];
        for (int i = beg; i < end; i++) {
            const int2 p = list_s[i];
            const int e = p.x;
            const int rv = p.y;
            const float4 efa = ((const float4*)ef8)[e*2];
            const float4 efb4 = ((const float4*)ef8)[e*2+1];
            const float y0 = Y1[e*3+0], y1 = Y1[e*3+1], y2 = Y1[e*3+2];
            float w00_0 = 0.f, w00_1 = 0.f, w110_0 = 0.f, w110_1 = 0.f;
            const float* eb = (const float*)&efa;
#pragma unroll
            for (int b = 0; b < 8; b++) {
                if (b == 4) eb = (const float*)&efb4;
                const float v = eb[b & 3];
                w00_0  += v * RL[b*256 + c0];
                w110_0 += v * RL[b*256 + 128 + c0];
                w00_1  += v * RL[b*256 + c1];
                w110_1 += v * RL[b*256 + 128 + c1];
            }
            const float ga0 = gA2[(size_t)rv*KK + c0];
            const float ga1 = gA2[(size_t)rv*KK + c1];
            gs0 += ga0 * w00_0;
            gs1 += ga1 * w00_1;
            const float gts0 = ga0 * w110_0 * INV_SQ3;
            const float gts1 = ga1 * w110_1 * INV_SQ3;
            gv00 += gts0*y0; gv01 += gts1*y0;
            gv10 += gts0*y1; gv11 += gts1*y1;
            gv20 += gts0*y2; gv21 += gts1*y2;
        }
        Gsj2[(size_t)sn*KK + c0] = gs0;
        Gsj2[(size_t)sn*KK + c1] = gs1;
        float* Gv = Gvj + (size_t)sn * 384;
        Gv[c0] = gv00;        Gv[c1] = gv01;
        Gv[128 + c0] = gv10;  Gv[128 + c1] = gv11;
        Gv[256 + c0] = gv20;  Gv[256 + c1] = gv21;
    }
}

// ---------------- backward layer1 per-edge + fused force ----------------
__global__ __launch_bounds__(256) void sz_bwdB(const float* __restrict__ ef8, const float* __restrict__ Y1,
                                                const int2* __restrict__ cei, const int* __restrict__ nact,
                                                const float* __restrict__ R1,
                                                const float* __restrict__ su1, const float* __restrict__ gA0,
                                                const float* __restrict__ gA1, const int2* __restrict__ list_r,
                                                const float* __restrict__ gefA, const float* __restrict__ gyA,
                                                const float* __restrict__ defdr, const float* __restrict__ rr,
                                                float* __restrict__ forces) {
    const int i = blockIdx.x * 256 + threadIdx.x;
    if (i >= *nact) return;
    const int2 p = list_r[i];
    const int e = p.x;
    const int sn = p.y;
    const int rv = cei[e].y;
    const float y0 = Y1[e*3+0], y1 = Y1[e*3+1], y2 = Y1[e*3+2];
    const float4 efa = ((const float4*)ef8)[e*2];
    const float4 efb = ((const float4*)ef8)[e*2+1];
    const float efv[8] = {efa.x, efa.y, efa.z, efa.w, efb.x, efb.y, efb.z, efb.w};
    float acc[8] = {0.f,0.f,0.f,0.f,0.f,0.f,0.f,0.f};
    float gg0 = 0.f, gg1 = 0.f, gg2 = 0.f;
    const float4* gmR = (const float4*)(gA0 + (size_t)rv * KK);
    const float4* sjR = (const float4*)(su1 + (size_t)sn * KK);
    const float4* gxR = (const float4*)(gA1 + (size_t)rv * 384);
    const float4* gyR = gxR + 32;
    const float4* gzR = gxR + 64;
    for (int cc = 0; cc < 32; cc++) {
        const float4 gm = gmR[cc];
        const float4 sj = sjR[cc];
        const float4 gx = gxR[cc];
        const float4 gy = gyR[cc];
        const float4 gz = gzR[cc];
#pragma unroll
        for (int k = 0; k < 4; k++) {
            const float gmE = ((const float*)&gm)[k];
            const float sjE = ((const float*)&sj)[k];
            const float g1E = ((const float*)&gx)[k];
            const float g2E = ((const float*)&gy)[k];
            const float g3E = ((const float*)&gz)[k];
            const float q = g1E*y0 + g2E*y1 + g3E*y2;
            const float gwa = gmE * sjE;
            const float gwb = q * sjE;
            float w = 0.f;
            const int c = cc*4 + k;
#pragma unroll
            for (int b = 0; b < 8; b++) {
                const float r1a = R1[b*256 + c];
                const float r1b = R1[b*256 + 128 + c];
                acc[b] += gwa * r1a + gwb * r1b;
                w += efv[b] * r1b;
            }
            const float ws = w * sjE;
            gg0 += g1E * ws;
            gg1 += g2E * ws;
            gg2 += g3E * ws;
        }
    }
    float gr = 0.f;
#pragma unroll
    for (int b = 0; b < 8; b++) gr += (gefA[e*8+b] + acc[b]) * defdr[e*8+b];
    const float g0 = gyA[e*3+0] + gg0;
    const float g1 = gyA[e*3+1] + gg1;
    const float g2 = gyA[e*3+2] + gg2;
    const float ir = 1.f / rr[e];
    const float dot = g0*y0 + g1*y1 + g2*y2;
    const float a = gr * INV_SQ3;
    const float b2 = SQ3F * ir;
    const float c = b2 * dot * (1.f / 3.f);
    const float gv0 = a*y0 + b2*g0 - c*y0;
    const float gv1 = a*y1 + b2*g1 - c*y1;
    const float gv2 = a*y2 + b2*g2 - c*y2;
    atomAddF(&forces[rv*3+0], -gv0);
    atomAddF(&forces[rv*3+1], -gv1);
    atomAddF(&forces[rv*3+2], -gv2);
    atomAddF(&forces[sn*3+0],  gv0);
    atomAddF(&forces[sn*3+1],  gv1);
    atomAddF(&forces[sn*3+2],  gv2);
}

extern "C" void kernel_launch(void* const* d_in, const int* in_sizes, int n_in,
                              void* d_out, int out_size, void* d_ws, size_t ws_size,
                              hipStream_t stream) {
    const float* positions  = (const float*)d_in[0];
    const float* shifts     = (const float*)d_in[1];
    const int*   edge_index = (const int*)d_in[2];
    const int*   node_z     = (const int*)d_in[3];
    const int*   batch      = (const int*)d_in[4];
    const float* atomic_e   = (const float*)d_in[5];
    const float* W_embed    = (const float*)d_in[6];
    const float* R1         = (const float*)d_in[7];
    const float* W_up1      = (const float*)d_in[8];
    const float* W_mix_s1   = (const float*)d_in[9];
    const float* W_mix_v1   = (const float*)d_in[10];
    const float* W_sk_s1    = (const float*)d_in[11];
    const float* w_r1       = (const float*)d_in[12];
    const float* R2         = (const float*)d_in[13];
    const float* W_up2s     = (const float*)d_in[14];
    const float* W_up2v     = (const float*)d_in[15];
    const float* W_mix_s2   = (const float*)d_in[16];
    const float* W_sk_s2    = (const float*)d_in[17];
    const float* W_mlp      = (const float*)d_in[18];
    const float* w_out      = (const float*)d_in[19];

    float* out = (float*)d_out;
    float* ws = (float*)d_ws;
    size_t off = 0;
    float* ef    = ws + off; off += (size_t)EE * 8;
    float* defdr = ws + off; off += (size_t)EE * 8;
    float* Y1    = ws + off; off += (size_t)EE * 3;
    float* rr    = ws + off; off += (size_t)EE;
    float* gefA  = ws + off; off += (size_t)EE * 8;
    float* gyA   = ws + off; off += (size_t)EE * 3;
    float* su1   = ws + off; off += (size_t)NN * KK;
    float* s1    = ws + off; off += (size_t)NN * KK;
    float* s1u2  = ws + off; off += (size_t)NN * KK;
    float* s2    = ws + off; off += (size_t)NN * KK;
    float* g_s2  = ws + off; off += (size_t)NN * KK;
    float* g_s1  = ws + off; off += (size_t)NN * KK;
    float* vup   = ws + off; off += (size_t)NN * KK * 3;
    float* A0    = ws + off; off += (size_t)NN * KK;
    float* A2    = ws + off; off += (size_t)NN * KK;
    float* Gsj2  = ws + off; off += (size_t)NN * KK;
    float* A1    = ws + off; off += (size_t)NN * KK * 3;
    float* Gvj   = ws + off; off += (size_t)NN * KK * 3;
    float* E1    = ws + off; off += 10 * KK;
    float* T1    = ws + off; off += 10 * KK;
    float* Wc    = ws + off; off += KK * KK;
    float* e1n   = ws + off; off += NN;
    float* e2n   = ws + off; off += NN;
    int* ip = (int*)(ws + off);
    size_t ioff = 0;
    int* deg_r = ip + ioff; ioff += NN;
    int* deg_s = ip + ioff; ioff += NN;
    int* cur_r = ip + ioff; ioff += NN;
    int* cur_s = ip + ioff; ioff += NN;
    int* zcnt  = ip + ioff; ioff += 16;
    int* zcur  = ip + ioff; ioff += 16;
    int* nact  = ip + ioff; ioff += 16;
    int* row_r = ip + ioff; ioff += NN + 2;
    int* row_s = ip + ioff; ioff += NN + 2;
    int* zrow  = ip + ioff; ioff += 16;
    int* zlist = ip + ioff; ioff += NN;
    int2* cei    = (int2*)(ip + ioff); ioff += (size_t)EE * 2;
    int2* list_r = (int2*)(ip + ioff); ioff += (size_t)EE * 2;
    int2* list_s = (int2*)(ip + ioff); ioff += (size_t)EE * 2;

    const int EG = (EE + 255) / 256;                // 625
    const int BNB  = ((NN + 63) / 64) * 2;          // 314
    const int BN3B = ((NN * 3 + 63) / 64) * 2;      // 938
    const int BS   = NE * 32;                       // 320
    const int ZB   = (out_size + 255) / 256;
    const int ZI   = (4 * NN + 48 + 255) / 256;
    sz_zero<<<ZB + ZI, 256, 0, stream>>>(out, out_size, deg_r, 4 * NN + 48, ZB);
    sz_geomtab<<<679, 256, 0, stream>>>(positions, shifts, edge_index, ef, defdr, Y1, rr,
                                        cei, nact, deg_r, deg_s, node_z, zcnt,
                                        W_embed, W_up1, W_sk_s1, E1, T1, W_mix_v1, W_up2v, Wc);
    sz_scan<<<1, 1024, 0, stream>>>(deg_r, deg_s, zcnt, row_r, row_s, zrow);
    sz_fill3<<<665 + (NN * KK) / 256, 256, 0, stream>>>(cei, nact, row_r, row_s, cur_r, cur_s,
                                                        list_r, list_s, node_z, zcur, zrow, zlist,
                                                        E1, T1, su1, s1);
    sz_edge1<<<(NN + 3) / 4, 256, 0, stream>>>(ef, Y1, R1, su1, row_r, list_r, A0, A1);
    sz_two<0, 1, 0, 0><<<BNB + BN3B, 256, 0, stream>>>(A0, W_mix_s1, s1, NN, INV_AVG,
                                                       A1, Wc, vup, NN * 3, INV_AVG, BNB);
    sz_mix<0, 0, 0, 0><<<BNB + BS, 256, 0, stream>>>(s1, W_up2s, s1u2, NN, 1.f,
                                                     s1, W_sk_s2, s2, zrow, zlist, BNB);
    sz_edge2<<<(NN + 3) / 4, 256, 0, stream>>>(ef, Y1, R2, s1u2, vup, row_r, list_r, A2);
    sz_one<0, 1><<<BNB, 256, 0, stream>>>(A2, W_mix_s2, s2, NN, INV_AVG);
    sz_mlp<<<NN, 128, 0, stream>>>(s2, W_mlp, w_out, w_r1, s1, g_s2, g_s1, e1n, e2n);
    sz_bwdmix<<<BNB + BS + 32, 256, 0, stream>>>(g_s2, W_mix_s2, A2, W_sk_s2, g_s1,
                                                 zrow, zlist, node_z, batch, atomic_e,
                                                 e1n, e2n, out, BNB, BNB + BS);
    sz_bwdA<<<625 + (NN + 3) / 4, 256, 0, stream>>>(ef, Y1, cei, nact, R2, A2, s1u2, vup,
                                                    list_s, row_s, gefA, gyA, Gsj2, Gvj);
    sz_two<1, 0, 1, 1><<<BN3B + BNB, 256, 0, stream>>>(Gvj, Wc, A1, NN * 3, INV_AVG,
                                                       Gsj2, W_up2s, g_s1, NN, 1.f, BN3B);
    sz_one<1, 0><<<BNB, 256, 0, stream>>>(g_s1, W_mix_s1, A0, NN, INV_AVG);
    sz_bwdB<<<EG, 256, 0, stream>>>(ef, Y1, cei, nact, R1, su1, A0, A1, list_r,
                                    gefA, gyA, defdr, rr, out + GG + GG * 3);
}

// Round 20
// 355.347 us; speedup vs baseline: 1.1668x; 1.0121x over previous
//
#include <hip/hip_runtime.h>
#include <math.h>

#define NN 10000
#define EE 160000
#define KK 128
#define GG 16
#define NE 10
#define SQ3F 1.7320508075688772f
#define INV_SQ3 0.57735026918962576f
#define INV_AVG 0.0625f
#define RMAXI 0.2f

__device__ __forceinline__ void atomAddF(float* p, float v) { unsafeAtomicAdd(p, v); }

__device__ __forceinline__ float waveRed(float v) {
#pragma unroll
    for (int m = 32; m >= 1; m >>= 1) v += __shfl_xor(v, m);
    return v;
}

// ============ dense core: tile 64 rows x 64 cols, 32KB LDS, thread = 4x4 ============
template <int TRANS>
__device__ __forceinline__ void t_stage(const float* __restrict__ W, int h, float* WL) {
    const int t = threadIdx.x;
    for (int i = t; i < KK * 64; i += 256) {
        int k, c;
        float v;
        if (!TRANS) { k = i >> 6; c = i & 63; v = W[k * KK + (h * 64 + c)]; }
        else        { c = i >> 7; k = i & 127; v = W[(h * 64 + c) * KK + k]; }
        WL[k * 64 + ((((c >> 2) + k) & 15) << 2) + (c & 3)] = v;
    }
}

template <int ACCUM, int GATHER>
__device__ __forceinline__ void t_compute(const float* __restrict__ in, float* __restrict__ out,
                                          int rows, float alpha, int bid_row, int h,
                                          const int* __restrict__ rowlist, const float* WL) {
    const int t = threadIdx.x;
    const int g0 = t & 15;
    const int cg = g0 << 2;
    const int i0 = bid_row * 64 + ((t >> 4) << 2);
    int rowv[4];
    const float* Ap[4];
#pragma unroll
    for (int j = 0; j < 4; j++) {
        int idx = i0 + j;
        if (idx > rows - 1) idx = rows - 1;
        rowv[j] = GATHER ? rowlist[idx] : idx;
        Ap[j] = in + (size_t)rowv[j] * KK;
    }
    float acc[4][4];
#pragma unroll
    for (int j = 0; j < 4; j++) { acc[j][0] = 0.f; acc[j][1] = 0.f; acc[j][2] = 0.f; acc[j][3] = 0.f; }
#pragma unroll 2
    for (int k = 0; k < KK; k += 4) {
        const float4 w0 = *(const float4*)&WL[(k+0)*64 + (((g0 + k + 0) & 15) << 2)];
        const float4 w1 = *(const float4*)&WL[(k+1)*64 + (((g0 + k + 1) & 15) << 2)];
        const float4 w2 = *(const float4*)&WL[(k+2)*64 + (((g0 + k + 2) & 15) << 2)];
        const float4 w3 = *(const float4*)&WL[(k+3)*64 + (((g0 + k + 3) & 15) << 2)];
#pragma unroll
        for (int j = 0; j < 4; j++) {
            const float4 a = *(const float4*)(Ap[j] + k);
            acc[j][0] += a.x*w0.x + a.y*w1.x + a.z*w2.x + a.w*w3.x;
            acc[j][1] += a.x*w0.y + a.y*w1.y + a.z*w2.y + a.w*w3.y;
            acc[j][2] += a.x*w0.z + a.y*w1.z + a.z*w2.z + a.w*w3.z;
            acc[j][3] += a.x*w0.w + a.y*w1.w + a.z*w2.w + a.w*w3.w;
        }
    }
    const int co = h * 64 + cg;
#pragma unroll
    for (int j = 0; j < 4; j++) {
        if (i0 + j < rows) {
            float4* o = (float4*)(out + (size_t)rowv[j] * KK + co);
            float4 v = make_float4(acc[j][0]*alpha, acc[j][1]*alpha, acc[j][2]*alpha, acc[j][3]*alpha);
            if (ACCUM) {
                const float4 old = *o;
                v.x += old.x; v.y += old.y; v.z += old.z; v.w += old.w;
            }
            *o = v;
        }
    }
}

// ---------------- zero-init: out + int counters ----------------
__global__ __launch_bounds__(256) void tz_zero(float* __restrict__ out, int out_size,
                                               int* __restrict__ ints, int icount, int zb) {
    const int t = threadIdx.x;
    if ((int)blockIdx.x < zb) {
        const int i = blockIdx.x * 256 + t;
        if (i < out_size) out[i] = 0.f;
    } else {
        const int i = (blockIdx.x - zb) * 256 + t;
        if (i < icount) ints[i] = 0;
    }
}

// ---------------- merged: geom (0..624) + zcount (625..664) + tables (665..674) + Wc (675..678) + Wd (679..682) ----------------
__global__ __launch_bounds__(256) void tz_geomtab(const float* __restrict__ pos, const float* __restrict__ shifts,
                            const int* __restrict__ ei,
                            float* __restrict__ ef, float* __restrict__ defdr,
                            float* __restrict__ Y1, float* __restrict__ rr,
                            int2* __restrict__ cei, int* __restrict__ nact,
                            int* __restrict__ deg_r, int* __restrict__ deg_s,
                            const int* __restrict__ z, int* __restrict__ zcnt,
                            const float* __restrict__ We, const float* __restrict__ Wup1,
                            const float* __restrict__ Wsk1,
                            float* __restrict__ E1, float* __restrict__ T1,
                            const float* __restrict__ Wmv1, const float* __restrict__ Wu2v,
                            float* __restrict__ Wc,
                            const float* __restrict__ Wms1, const float* __restrict__ Wu2s,
                            float* __restrict__ Wd) {
    __shared__ float WL[KK * 64];
    const int t = threadIdx.x;
    if ((int)blockIdx.x < 625) {
        int* lcnt = (int*)WL;
        int* lbase = ((int*)WL) + 1;
        if (t == 0) *lcnt = 0;
        __syncthreads();
        const int e = blockIdx.x * 256 + t;
        const int sn = ei[e];
        const int rv = ei[EE + e];
        const float vx = pos[rv*3+0] - pos[sn*3+0] + shifts[e*3+0];
        const float vy = pos[rv*3+1] - pos[sn*3+1] + shifts[e*3+1];
        const float vz = pos[rv*3+2] - pos[sn*3+2] + shifts[e*3+2];
        const float r = sqrtf(vx*vx + vy*vy + vz*vz + 1e-12f);
        const float x = r * RMAXI;
        const int active = (x < 1.0f) ? 1 : 0;
        int pos_l = 0;
        if (active) pos_l = atomicAdd(lcnt, 1);
        __syncthreads();
        if (t == 0 && *lcnt > 0) *lbase = atomicAdd(nact, *lcnt);
        __syncthreads();
        if (!active) return;
        const int idx = *lbase + pos_l;
        cei[idx] = make_int2(sn, rv);
        atomicAdd(&deg_s[sn], 1);
        atomicAdd(&deg_r[rv], 1);
        const float ir = 1.0f / r;
        rr[idx] = r;
        Y1[idx*3+0] = SQ3F*vx*ir;
        Y1[idx*3+1] = SQ3F*vy*ir;
        Y1[idx*3+2] = SQ3F*vz*ir;
        const float x2 = x*x, x4 = x2*x2, x5 = x4*x, x6 = x5*x, x7 = x6*x;
        const float fc  = 1.0f - 21.0f*x5 + 35.0f*x6 - 15.0f*x7;
        const float dfc = (-105.0f*x4 + 210.0f*x5 - 105.0f*x6) * RMAXI;
        const float C = 0.63245553203367587f;
        float4 efa, efb4, da, db;
        float* efp = (float*)&efa;
        float* dp  = (float*)&da;
#pragma unroll
        for (int b = 0; b < 8; b++) {
            const float kb = (float)(b + 1) * 0.62831853071795865f;
            float sb, cb;
            sincosf(kb * r, &sb, &cb);
            const float bess  = C * sb * ir;
            const float dbess = C * ir * (kb * cb - sb * ir);
            if (b == 4) { efp = (float*)&efb4; dp = (float*)&db; }
            efp[b & 3] = bess * fc;
            dp[b & 3]  = dbess * fc + bess * dfc;
        }
        ((float4*)ef)[idx*2]    = efa;
        ((float4*)ef)[idx*2+1]  = efb4;
        ((float4*)defdr)[idx*2]   = da;
        ((float4*)defdr)[idx*2+1] = db;
    } else if ((int)blockIdx.x < 665) {
        int* h = (int*)WL;
        if (t < NE) h[t] = 0;
        __syncthreads();
        const int n = (blockIdx.x - 625) * 256 + t;
        if (n < NN) atomicAdd(&h[z[n]], 1);
        __syncthreads();
        if (t < NE && h[t] > 0) atomicAdd(&zcnt[t], h[t]);
    } else if ((int)blockIdx.x < 675) {
        const int zz = blockIdx.x - 665;
        if (t < KK) {
            float a = 0.f, bv = 0.f;
            for (int c = 0; c < KK; c++) {
                const float w = We[zz*KK + c];
                a  += w * Wup1[c*KK + t];
                bv += w * Wsk1[(size_t)(zz*KK + c)*KK + t];
            }
            E1[zz*KK + t] = a;
            T1[zz*KK + t] = bv;
        }
    } else if ((int)blockIdx.x < 679) {
        const int b = blockIdx.x - 675;      // 0..3
        const int h = b & 1;
        t_stage<0>(Wu2v, h, WL);             // Wc = Wmv1 @ Wu2v
        __syncthreads();
        t_compute<0, 0>(Wmv1, Wc, KK, 1.f, b >> 1, h, nullptr, WL);
    } else {
        const int b = blockIdx.x - 679;      // 0..3
        const int h = b & 1;
        t_stage<0>(Wu2s, h, WL);             // Wd = Wms1 @ Wu2s
        __syncthreads();
        t_compute<0, 0>(Wms1, Wd, KK, 1.f, b >> 1, h, nullptr, WL);
    }
}

// ---------------- scans ----------------
__global__ __launch_bounds__(1024) void tz_scan(const int* __restrict__ deg_r, const int* __restrict__ deg_s,
                                               const int* __restrict__ zcnt,
                                               int* __restrict__ row_r, int* __restrict__ row_s,
                                               int* __restrict__ zrow) {
    __shared__ int part[1024];
    const int t = threadIdx.x;
    if (t == 0) {
        int s = 0;
        for (int i = 0; i < NE; i++) { zrow[i] = s; s += zcnt[i]; }
        zrow[NE] = s;
    }
    for (int a = 0; a < 2; a++) {
        const int* deg = a ? deg_s : deg_r;
        int* row = a ? row_s : row_r;
        const int base = t * 10;
        int loc[10];
        int s = 0;
#pragma unroll
        for (int k = 0; k < 10; k++) {
            loc[k] = s;
            if (base + k < NN) s += deg[base + k];
        }
        part[t] = s;
        __syncthreads();
        for (int off = 1; off < 1024; off <<= 1) {
            const int v = (t >= off) ? part[t - off] : 0;
            __syncthreads();
            part[t] += v;
            __syncthreads();
        }
        const int bex = (t > 0) ? part[t - 1] : 0;
#pragma unroll
        for (int k = 0; k < 10; k++)
            if (base + k < NN) row[base + k] = bex + loc[k];
        if (t == 1023) row[NN] = part[1023];
        __syncthreads();
    }
}

// ---------------- merged: CSR fill (0..624) + zfill (625..664) + zinit (665..5664) ----------------
__global__ __launch_bounds__(256) void tz_fill3(const int2* __restrict__ cei, const int* __restrict__ nact,
                       const int* __restrict__ row_r, const int* __restrict__ row_s,
                       int* __restrict__ cur_r, int* __restrict__ cur_s,
                       int2* __restrict__ list_r, int2* __restrict__ list_s,
                       const int* __restrict__ z, int* __restrict__ zcur,
                       const int* __restrict__ zrow, int* __restrict__ zlist,
                       const float* __restrict__ E1, const float* __restrict__ T1,
                       float* __restrict__ su1, float* __restrict__ s1) {
    const int t = threadIdx.x;
    if ((int)blockIdx.x < 625) {
        const int i = blockIdx.x * 256 + t;
        if (i >= *nact) return;
        const int2 p = cei[i];
        const int pr = atomicAdd(&cur_r[p.y], 1);
        list_r[row_r[p.y] + pr] = make_int2(i, p.x);
        const int ps = atomicAdd(&cur_s[p.x], 1);
        list_s[row_s[p.x] + ps] = make_int2(i, p.y);
    } else if ((int)blockIdx.x < 665) {
        __shared__ int cnt[NE];
        __shared__ int base[NE];
        if (t < NE) cnt[t] = 0;
        __syncthreads();
        const int n = (blockIdx.x - 625) * 256 + t;
        int pos = -1, zz = 0;
        if (n < NN) { zz = z[n]; pos = atomicAdd(&cnt[zz], 1); }
        __syncthreads();
        if (t < NE && cnt[t] > 0) base[t] = atomicAdd(&zcur[t], cnt[t]);
        __syncthreads();
        if (n < NN) zlist[zrow[zz] + base[zz] + pos] = n;
    } else {
        const int i = (blockIdx.x - 665) * 256 + t;
        if (i >= NN * KK) return;
        const int base = z[i >> 7] * KK + (i & 127);
        su1[i] = E1[base];
        s1[i]  = T1[base];
    }
}

// ---- single dense op ----
template <int TRANS, int ACCUM>
__global__ __launch_bounds__(256) void tz_one(const float* __restrict__ in, const float* __restrict__ W,
                                              float* __restrict__ out, int rows, float alpha) {
    __shared__ float WL[KK * 64];
    const int h = blockIdx.x & 1;
    t_stage<TRANS>(W, h, WL);
    __syncthreads();
    t_compute<ACCUM, 0>(in, out, rows, alpha, blockIdx.x >> 1, h, nullptr, WL);
}

// ---- two dense ops, one dispatch ----
template <int TA, int AA, int TB, int AB>
__global__ __launch_bounds__(256) void tz_two(
        const float* __restrict__ inA, const float* __restrict__ WA, float* __restrict__ outA,
        int rowsA, float alphaA,
        const float* __restrict__ inB, const float* __restrict__ WB, float* __restrict__ outB,
        int rowsB, float alphaB, int blocksA) {
    __shared__ float WL[KK * 64];
    if ((int)blockIdx.x < blocksA) {
        const int h = blockIdx.x & 1;
        t_stage<TA>(WA, h, WL);
        __syncthreads();
        t_compute<AA, 0>(inA, outA, rowsA, alphaA, blockIdx.x >> 1, h, nullptr, WL);
    } else {
        const int b = blockIdx.x - blocksA;
        const int h = b & 1;
        t_stage<TB>(WB, h, WL);
        __syncthreads();
        t_compute<AB, 0>(inB, outB, rowsB, alphaB, b >> 1, h, nullptr, WL);
    }
}

// ---- three dense ops, one dispatch ----
template <int TA, int AA, int TB, int AB, int TC, int AC>
__global__ __launch_bounds__(256) void tz_three(
        const float* __restrict__ inA, const float* __restrict__ WA, float* __restrict__ outA,
        int rowsA, float alphaA,
        const float* __restrict__ inB, const float* __restrict__ WB, float* __restrict__ outB,
        int rowsB, float alphaB,
        const float* __restrict__ inC, const float* __restrict__ WC, float* __restrict__ outC,
        int rowsC, float alphaC, int blocksA, int blocksAB) {
    __shared__ float WL[KK * 64];
    if ((int)blockIdx.x < blocksA) {
        const int h = blockIdx.x & 1;
        t_stage<TA>(WA, h, WL);
        __syncthreads();
        t_compute<AA, 0>(inA, outA, rowsA, alphaA, blockIdx.x >> 1, h, nullptr, WL);
    } else if ((int)blockIdx.x < blocksAB) {
        const int b = blockIdx.x - blocksA;
        const int h = b & 1;
        t_stage<TB>(WB, h, WL);
        __syncthreads();
        t_compute<AB, 0>(inB, outB, rowsB, alphaB, b >> 1, h, nullptr, WL);
    } else {
        const int b = blockIdx.x - blocksAB;
        const int h = b & 1;
        t_stage<TC>(WC, h, WL);
        __syncthreads();
        t_compute<AC, 0>(inC, outC, rowsC, alphaC, b >> 1, h, nullptr, WL);
    }
}

// ---- dense op + per-z skip buckets, one dispatch ----
template <int TA, int AA, int TS, int AS>
__global__ __launch_bounds__(256) void tz_mix(
        const float* __restrict__ inA, const float* __restrict__ WA, float* __restrict__ outA,
        int rowsA, float alphaA,
        const float* __restrict__ inS, const float* __restrict__ Wall, float* __restrict__ outS,
        const int* __restrict__ zrow, const int* __restrict__ zlist, int blocksA) {
    __shared__ float WL[KK * 64];
    if ((int)blockIdx.x < blocksA) {
        const int h = blockIdx.x & 1;
        t_stage<TA>(WA, h, WL);
        __syncthreads();
        t_compute<AA, 0>(inA, outA, rowsA, alphaA, blockIdx.x >> 1, h, nullptr, WL);
    } else {
        const int sbid = blockIdx.x - blocksA;
        const int zz = sbid % NE;
        const int q = sbid / NE;
        const int h = q & 1;
        const int ch0 = q >> 1;
        const int beg = zrow[zz];
        const int cnt = zrow[zz + 1] - beg;
        if (ch0 * 64 >= cnt) return;
        t_stage<TS>(Wall + (size_t)zz * (KK * KK), h, WL);
        __syncthreads();
        for (int ch = ch0; ch * 64 < cnt; ch += 16)
            t_compute<AS, 1>(inS, outS, cnt, 1.f, ch, h, zlist + beg, WL);
    }
}

// ---- backward bundle: dense g_A2 + skip bwd accum + energy (last 32) ----
__global__ __launch_bounds__(256) void tz_bwdmix(
        const float* __restrict__ g_s2, const float* __restrict__ Wms2, float* __restrict__ gA2,
        const float* __restrict__ Wsk2, float* __restrict__ g_s1,
        const int* __restrict__ zrow, const int* __restrict__ zlist,
        const int* __restrict__ z, const int* __restrict__ batch, const float* __restrict__ ae,
        const float* __restrict__ e1n, const float* __restrict__ e2n, float* __restrict__ out,
        int blocksA, int blocksAB) {
    __shared__ float WL[KK * 64];
    const int t = threadIdx.x;
    if ((int)blockIdx.x < blocksA) {
        const int h = blockIdx.x & 1;
        t_stage<1>(Wms2, h, WL);
        __syncthreads();
        t_compute<0, 0>(g_s2, gA2, NN, INV_AVG, blockIdx.x >> 1, h, nullptr, WL);
    } else if ((int)blockIdx.x < blocksAB) {
        const int sbid = blockIdx.x - blocksA;
        const int zz = sbid % NE;
        const int q = sbid / NE;
        const int h = q & 1;
        const int ch0 = q >> 1;
        const int beg = zrow[zz];
        const int cnt = zrow[zz + 1] - beg;
        if (ch0 * 64 >= cnt) return;
        t_stage<1>(Wsk2 + (size_t)zz * (KK * KK), h, WL);
        __syncthreads();
        for (int ch = ch0; ch * 64 < cnt; ch += 16)
            t_compute<1, 1>(g_s2, g_s1, cnt, 1.f, ch, h, zlist + beg, WL);
    } else {
        float* bins = WL;
        for (int i = t; i < GG * 4; i += 256) bins[i] = 0.f;
        __syncthreads();
        const int idx = (blockIdx.x - blocksAB) * 256 + t;
        const int stride = 32 * 256;
        for (int n = idx; n < NN; n += stride) {
            const int b = batch[n];
            const float v0 = ae[z[n]];
            const float v1 = e1n[n];
            const float v2 = e2n[n];
            atomicAdd(&bins[b*4+0], v0 + v1 + v2);
            atomicAdd(&bins[b*4+1], v0);
            atomicAdd(&bins[b*4+2], v1);
            atomicAdd(&bins[b*4+3], v2);
        }
        __syncthreads();
        for (int i = t; i < GG * 4; i += 256) {
            const float v = bins[i];
            if (v != 0.f) {
                const int b = i >> 2;
                const int k = i & 3;
                float* dst = (k == 0) ? &out[b] : &out[GG + b*3 + (k - 1)];
                atomAddF(dst, v);
            }
        }
    }
}

// ---------------- edge pass 1 (rcv-centric gather) ----------------
__global__ __launch_bounds__(256) void tz_edge1(const float* __restrict__ ef, const float* __restrict__ Y1,
                                                 const float* __restrict__ R1, const float* __restrict__ su1,
                                                 const int* __restrict__ row_r, const int2* __restrict__ list_r,
                                                 float* __restrict__ A0, float* __restrict__ A1) {
    __shared__ float RL[2048];
    for (int i = threadIdx.x; i < 2048; i += 256) RL[i] = R1[i];
    __syncthreads();
    const int lane = threadIdx.x & 63;
    const int n = blockIdx.x * 4 + (threadIdx.x >> 6);
    if (n >= NN) return;
    const int c0 = lane;
    const int c1 = lane + 64;
    float a00 = 0.f, a01 = 0.f;
    float ax0 = 0.f, ax1 = 0.f, ay0 = 0.f, ay1 = 0.f, az0 = 0.f, az1 = 0.f;
    const int beg = row_r[n];
    const int end = row_r[n + 1];
    for (int i = beg; i < end; i++) {
        const int2 p = list_r[i];
        const int e = p.x;
        const int sn = p.y;
        const float4 efa = ((const float4*)ef)[e*2];
        const float4 efb4 = ((const float4*)ef)[e*2+1];
        const float y0 = Y1[e*3+0], y1 = Y1[e*3+1], y2 = Y1[e*3+2];
        float wa0 = 0.f, wa1 = 0.f, wb0 = 0.f, wb1 = 0.f;
        const float* eb = (const float*)&efa;
#pragma unroll
        for (int b = 0; b < 8; b++) {
            if (b == 4) eb = (const float*)&efb4;
            const float v = eb[b & 3];
            wa0 += v * RL[b*256 + c0];
            wb0 += v * RL[b*256 + 128 + c0];
            wa1 += v * RL[b*256 + c1];
            wb1 += v * RL[b*256 + 128 + c1];
        }
        const float sj0 = su1[sn*KK + c0];
        const float sj1 = su1[sn*KK + c1];
        a00 += wa0 * sj0;
        a01 += wa1 * sj1;
        const float mb0 = wb0 * sj0;
        const float mb1 = wb1 * sj1;
        ax0 += mb0*y0; ax1 += mb1*y0;
        ay0 += mb0*y1; ay1 += mb1*y1;
        az0 += mb0*y2; az1 += mb1*y2;
    }
    A0[(size_t)n*KK + c0] = a00;
    A0[(size_t)n*KK + c1] = a01;
    float* A1r = A1 + (size_t)n * 384;
    A1r[c0] = ax0;        A1r[c1] = ax1;
    A1r[128 + c0] = ay0;  A1r[128 + c1] = ay1;
    A1r[256 + c0] = az0;  A1r[256 + c1] = az1;
}

// ---------------- edge pass 2 (rcv-centric gather) ----------------
__global__ __launch_bounds__(256) void tz_edge2(const float* __restrict__ ef, const float* __restrict__ Y1,
                                                 const float* __restrict__ R2, const float* __restrict__ s1u2,
                                                 const float* __restrict__ vup,
                                                 const int* __restrict__ row_r, const int2* __restrict__ list_r,
                                                 float* __restrict__ A2) {
    __shared__ float RL[2048];
    for (int i = threadIdx.x; i < 2048; i += 256) RL[i] = R2[(i >> 8) * 512 + (i & 255)];
    __syncthreads();
    const int lane = threadIdx.x & 63;
    const int n = blockIdx.x * 4 + (threadIdx.x >> 6);
    if (n >= NN) return;
    const int c0 = lane;
    const int c1 = lane + 64;
    float a0 = 0.f, a1 = 0.f;
    const int beg = row_r[n];
    const int end = row_r[n + 1];
    for (int i = beg; i < end; i++) {
        const int2 p = list_r[i];
        const int e = p.x;
        const int sn = p.y;
        const float4 efa = ((const float4*)ef)[e*2];
        const float4 efb4 = ((const float4*)ef)[e*2+1];
        const float y0 = Y1[e*3+0], y1 = Y1[e*3+1], y2 = Y1[e*3+2];
        float w00_0 = 0.f, w00_1 = 0.f, w110_0 = 0.f, w110_1 = 0.f;
        const float* eb = (const float*)&efa;
#pragma unroll
        for (int b = 0; b < 8; b++) {
            if (b == 4) eb = (const float*)&efb4;
            const float v = eb[b & 3];
            w00_0  += v * RL[b*256 + c0];
            w110_0 += v * RL[b*256 + 128 + c0];
            w00_1  += v * RL[b*256 + c1];
            w110_1 += v * RL[b*256 + 128 + c1];
        }
        const float sj0 = s1u2[sn*KK + c0];
        const float sj1 = s1u2[sn*KK + c1];
        const float* vu = vup + (size_t)sn * 384;
        const float tt0 = (vu[c0]*y0 + vu[128 + c0]*y1 + vu[256 + c0]*y2) * INV_SQ3;
        const float tt1 = (vu[c1]*y0 + vu[128 + c1]*y1 + vu[256 + c1]*y2) * INV_SQ3;
        a0 += w00_0 * sj0 + w110_0 * tt0;
        a1 += w00_1 * sj1 + w110_1 * tt1;
    }
    A2[(size_t)n*KK + c0] = a0;
    A2[(size_t)n*KK + c1] = a1;
}

// ---------------- MLP energy head + e1 + backward seed ----------------
__global__ __launch_bounds__(128) void tz_mlp(const float* __restrict__ s2, const float* __restrict__ W_mlp,
                                             const float* __restrict__ w_out, const float* __restrict__ w_r1,
                                             const float* __restrict__ s1,
                                             float* __restrict__ g_s2, float* __restrict__ g_s1,
                                             float* __restrict__ e1n, float* __restrict__ e2n) {
    __shared__ float WmL[KK * 17];
    __shared__ float s2L[KK];
    __shared__ float part[128];
    __shared__ float ghL[16];
    __shared__ float eL[16];
    __shared__ float pw[2];
    const int n = blockIdx.x;
    const int t = threadIdx.x;
    for (int i = t; i < KK * 16; i += 128) WmL[(i >> 4) * 17 + (i & 15)] = W_mlp[i];
    s2L[t] = s2[(size_t)n * KK + t];
    const float wr = w_r1[t];
    float p = s1[(size_t)n * KK + t] * wr;
    p = waveRed(p);
    if ((t & 63) == 0) pw[t >> 6] = p;
    __syncthreads();
    {
        const int j = t & 15;
        const int seg = t >> 4;
        float pr = 0.f;
#pragma unroll
        for (int c = 0; c < 16; c++) pr += s2L[seg*16 + c] * WmL[(seg*16 + c) * 17 + j];
        part[t] = pr;
    }
    __syncthreads();
    if (t < 16) {
        float hh = 0.f;
#pragma unroll
        for (int s = 0; s < 8; s++) hh += part[s*16 + t];
        const float sg = 1.f / (1.f + expf(-hh));
        eL[t]  = hh * sg * w_out[t];
        ghL[t] = w_out[t] * sg * (1.f + hh * (1.f - sg));
    }
    __syncthreads();
    if (t == 0) {
        float e = 0.f;
#pragma unroll
        for (int j = 0; j < 16; j++) e += eL[j];
        e2n[n] = e;
        e1n[n] = pw[0] + pw[1];
    }
    float g = 0.f;
#pragma unroll
    for (int j = 0; j < 16; j++) g += ghL[j] * WmL[t * 17 + j];
    g_s2[(size_t)n * KK + t] = g;
    g_s1[(size_t)n * KK + t] = wr;
}

// ---------------- merged backward layer2: per-edge (0..624) + node sums (625..3124) ----------------
__global__ __launch_bounds__(256) void tz_bwdA(const float* __restrict__ ef8, const float* __restrict__ Y1,
                                                const int2* __restrict__ cei, const int* __restrict__ nact,
                                                const float* __restrict__ R2,
                                                const float* __restrict__ gA2, const float* __restrict__ s1u2,
                                                const float* __restrict__ vup,
                                                const int2* __restrict__ list_s, const int* __restrict__ row_s,
                                                float* __restrict__ gefA, float* __restrict__ gyA,
                                                float* __restrict__ Gsj2, float* __restrict__ Gvj) {
    __shared__ float RL[2048];
    const int t = threadIdx.x;
    if ((int)blockIdx.x < 625) {
        const int i = blockIdx.x * 256 + t;
        if (i >= *nact) return;
        const int2 p = list_s[i];
        const int e = p.x;
        const int rv = p.y;
        const int sn = cei[e].x;
        const float y0 = Y1[e*3+0], y1 = Y1[e*3+1], y2 = Y1[e*3+2];
        const float4 efa = ((const float4*)ef8)[e*2];
        const float4 efb = ((const float4*)ef8)[e*2+1];
        const float efv[8] = {efa.x, efa.y, efa.z, efa.w, efb.x, efb.y, efb.z, efb.w};
        float acc[8] = {0.f,0.f,0.f,0.f,0.f,0.f,0.f,0.f};
        float g0 = 0.f, g1 = 0.f, g2 = 0.f;
        const float4* gaR = (const float4*)(gA2 + (size_t)rv * KK);
        const float4* sjR = (const float4*)(s1u2 + (size_t)sn * KK);
        const float4* vxR = (const float4*)(vup + (size_t)sn * 384);
        const float4* vyR = vxR + 32;
        const float4* vzR = vxR + 64;
        for (int cc = 0; cc < 32; cc++) {
            const float4 ga = gaR[cc];
            const float4 sj = sjR[cc];
            const float4 vx = vxR[cc];
            const float4 vy = vyR[cc];
            const float4 vz = vzR[cc];
#pragma unroll
            for (int k = 0; k < 4; k++) {
                const float gaE = ((const float*)&ga)[k];
                const float sjE = ((const float*)&sj)[k];
                const float vxE = ((const float*)&vx)[k];
                const float vyE = ((const float*)&vy)[k];
                const float vzE = ((const float*)&vz)[k];
                const float tt = (vxE*y0 + vyE*y1 + vzE*y2) * INV_SQ3;
                const float gw00 = gaE * sjE;
                const float gw110 = gaE * tt;
                float w110 = 0.f;
                const int c = cc*4 + k;
#pragma unroll
                for (int b = 0; b < 8; b++) {
                    const float r2a = R2[b*512 + c];
                    const float r2b = R2[b*512 + 128 + c];
                    acc[b] += gw00 * r2a + gw110 * r2b;
                    w110 += efv[b] * r2b;
                }
                const float gt = gaE * w110;
                g0 += gt * vxE;
                g1 += gt * vyE;
                g2 += gt * vzE;
            }
        }
        ((float4*)gefA)[e*2]   = make_float4(acc[0], acc[1], acc[2], acc[3]);
        ((float4*)gefA)[e*2+1] = make_float4(acc[4], acc[5], acc[6], acc[7]);
        gyA[e*3+0] = g0 * INV_SQ3;
        gyA[e*3+1] = g1 * INV_SQ3;
        gyA[e*3+2] = g2 * INV_SQ3;
    } else {
        for (int i = t; i < 2048; i += 256) RL[i] = R2[(i >> 8) * 512 + (i & 255)];
        __syncthreads();
        const int lane = t & 63;
        const int sn = (blockIdx.x - 625) * 4 + (t >> 6);
        if (sn >= NN) return;
        const int c0 = lane;
        const int c1 = lane + 64;
        float gs0 = 0.f, gs1 = 0.f;
        float gv00 = 0.f, gv01 = 0.f, gv10 = 0.f, gv11 = 0.f, gv20 = 0.f, gv21 = 0.f;
        const int beg = row_s[sn];
        const int end = row_s[sn + 1];
        for (int i = beg; i < end; i++) {
            const int2 p = list_s[i];
            const int e = p.x;
            const int rv = p.y;
            const float4 efa = ((const float4*)ef8)[e*2];
            const float4 efb4 = ((const float4*)ef8)[e*2+1];
            const float y0 = Y1[e*3+0], y1 = Y1[e*3+1], y2 = Y1[e*3+2];
            float w00_0 = 0.f, w00_1 = 0.f, w110_0 = 0.f, w110_1 = 0.f;
            const float* eb = (const float*)&efa;
#pragma unroll
            for (int b = 0; b < 8; b++) {
                if (b == 4) eb = (const float*)&efb4;
                const float v = eb[b & 3];
                w00_0  += v * RL[b*256 + c0];
                w110_0 += v * RL[b*256 + 128 + c0];
                w00_1  += v * RL[b*256 + c1];
                w110_1 += v * RL[b*256 + 128 + c1];
            }
            const float ga0 = gA2[(size_t)rv*KK + c0];
            const float ga1 = gA2[(size_t)rv*KK + c1];
            gs0 += ga0 * w00_0;
            gs1 += ga1 * w00_1;
            const float gts0 = ga0 * w110_0 * INV_SQ3;
            const float gts1 = ga1 * w110_1 * INV_SQ3;
            gv00 += gts0*y0; gv01 += gts1*y0;
            gv10 += gts0*y1; gv11 += gts1*y1;
            gv20 += gts0*y2; gv21 += gts1*y2;
        }
        Gsj2[(size_t)sn*KK + c0] = gs0;
        Gsj2[(size_t)sn*KK + c1] = gs1;
        float* Gv = Gvj + (size_t)sn * 384;
        Gv[c0] = gv00;        Gv[c1] = gv01;
        Gv[128 + c0] = gv10;  Gv[128 + c1] = gv11;
        Gv[256 + c0] = gv20;  Gv[256 + c1] = gv21;
    }
}

// ---------------- backward layer1 per-edge + fused force (gA0 = A0a + A0b) ----------------
__global__ __launch_bounds__(256) void tz_bwdB(const float* __restrict__ ef8, const float* __restrict__ Y1,
                                                const int2* __restrict__ cei, const int* __restrict__ nact,
                                                const float* __restrict__ R1,
                                                const float* __restrict__ su1,
                                                const float* __restrict__ gA0a, const float* __restrict__ gA0b,
                                                const float* __restrict__ gA1, const int2* __restrict__ list_r,
                                                const float* __restrict__ gefA, const float* __restrict__ gyA,
                                                const float* __restrict__ defdr, const float* __restrict__ rr,
                                                float* __restrict__ forces) {
    const int i = blockIdx.x * 256 + threadIdx.x;
    if (i >= *nact) return;
    const int2 p = list_r[i];
    const int e = p.x;
    const int sn = p.y;
    const int rv = cei[e].y;
    const float y0 = Y1[e*3+0], y1 = Y1[e*3+1], y2 = Y1[e*3+2];
    const float4 efa = ((const float4*)ef8)[e*2];
    const float4 efb = ((const float4*)ef8)[e*2+1];
    const float efv[8] = {efa.x, efa.y, efa.z, efa.w, efb.x, efb.y, efb.z, efb.w};
    float acc[8] = {0.f,0.f,0.f,0.f,0.f,0.f,0.f,0.f};
    float gg0 = 0.f, gg1 = 0.f, gg2 = 0.f;
    const float4* gmRa = (const float4*)(gA0a + (size_t)rv * KK);
    const float4* gmRb = (const float4*)(gA0b + (size_t)rv * KK);
    const float4* sjR = (const float4*)(su1 + (size_t)sn * KK);
    const float4* gxR = (const float4*)(gA1 + (size_t)rv * 384);
    const float4* gyR = gxR + 32;
    const float4* gzR = gxR + 64;
    for (int cc = 0; cc < 32; cc++) {
        const float4 gma = gmRa[cc];
        const float4 gmb = gmRb[cc];
        const float4 sj = sjR[cc];
        const float4 gx = gxR[cc];
        const float4 gy = gyR[cc];
        const float4 gz = gzR[cc];
#pragma unroll
        for (int k = 0; k < 4; k++) {
            const float gmE = ((const float*)&gma)[k] + ((const float*)&gmb)[k];
            const float sjE = ((const float*)&sj)[k];
            const float g1E = ((const float*)&gx)[k];
            const float g2E = ((const float*)&gy)[k];
            const float g3E = ((const float*)&gz)[k];
            const float q = g1E*y0 + g2E*y1 + g3E*y2;
            const float gwa = gmE * sjE;
            const float gwb = q * sjE;
            float w = 0.f;
            const int c = cc*4 + k;
#pragma unroll
            for (int b = 0; b < 8; b++) {
                const float r1a = R1[b*256 + c];
                const float r1b = R1[b*256 + 128 + c];
                acc[b] += gwa * r1a + gwb * r1b;
                w += efv[b] * r1b;
            }
            const float ws = w * sjE;
            gg0 += g1E * ws;
            gg1 += g2E * ws;
            gg2 += g3E * ws;
        }
    }
    float gr = 0.f;
#pragma unroll
    for (int b = 0; b < 8; b++) gr += (gefA[e*8+b] + acc[b]) * defdr[e*8+b];
    const float g0 = gyA[e*3+0] + gg0;
    const float g1 = gyA[e*3+1] + gg1;
    const float g2 = gyA[e*3+2] + gg2;
    const float ir = 1.f / rr[e];
    const float dot = g0*y0 + g1*y1 + g2*y2;
    const float a = gr * INV_SQ3;
    const float b2 = SQ3F * ir;
    const float c = b2 * dot * (1.f / 3.f);
    const float gv0 = a*y0 + b2*g0 - c*y0;
    const float gv1 = a*y1 + b2*g1 - c*y1;
    const float gv2 = a*y2 + b2*g2 - c*y2;
    atomAddF(&forces[rv*3+0], -gv0);
    atomAddF(&forces[rv*3+1], -gv1);
    atomAddF(&forces[rv*3+2], -gv2);
    atomAddF(&forces[sn*3+0],  gv0);
    atomAddF(&forces[sn*3+1],  gv1);
    atomAddF(&forces[sn*3+2],  gv2);
}

extern "C" void kernel_launch(void* const* d_in, const int* in_sizes, int n_in,
                              void* d_out, int out_size, void* d_ws, size_t ws_size,
                              hipStream_t stream) {
    const float* positions  = (const float*)d_in[0];
    const float* shifts     = (const float*)d_in[1];
    const int*   edge_index = (const int*)d_in[2];
    const int*   node_z     = (const int*)d_in[3];
    const int*   batch      = (const int*)d_in[4];
    const float* atomic_e   = (const float*)d_in[5];
    const float* W_embed    = (const float*)d_in[6];
    const float* R1         = (const float*)d_in[7];
    const float* W_up1      = (const float*)d_in[8];
    const float* W_mix_s1   = (const float*)d_in[9];
    const float* W_mix_v1   = (const float*)d_in[10];
    const float* W_sk_s1    = (const float*)d_in[11];
    const float* w_r1       = (const float*)d_in[12];
    const float* R2         = (const float*)d_in[13];
    const float* W_up2s     = (const float*)d_in[14];
    const float* W_up2v     = (const float*)d_in[15];
    const float* W_mix_s2   = (const float*)d_in[16];
    const float* W_sk_s2    = (const float*)d_in[17];
    const float* W_mlp      = (const float*)d_in[18];
    const float* w_out      = (const float*)d_in[19];

    float* out = (float*)d_out;
    float* ws = (float*)d_ws;
    size_t off = 0;
    float* ef    = ws + off; off += (size_t)EE * 8;
    float* defdr = ws + off; off += (size_t)EE * 8;
    float* Y1    = ws + off; off += (size_t)EE * 3;
    float* rr    = ws + off; off += (size_t)EE;
    float* gefA  = ws + off; off += (size_t)EE * 8;
    float* gyA   = ws + off; off += (size_t)EE * 3;
    float* su1   = ws + off; off += (size_t)NN * KK;
    float* s1    = ws + off; off += (size_t)NN * KK;
    float* s1u2  = ws + off; off += (size_t)NN * KK;
    float* s2    = ws + off; off += (size_t)NN * KK;
    float* g_s2  = ws + off; off += (size_t)NN * KK;
    float* g_s1  = ws + off; off += (size_t)NN * KK;
    float* vup   = ws + off; off += (size_t)NN * KK * 3;
    float* A0    = ws + off; off += (size_t)NN * KK;
    float* A0b   = ws + off; off += (size_t)NN * KK;
    float* A2    = ws + off; off += (size_t)NN * KK;
    float* Gsj2  = ws + off; off += (size_t)NN * KK;
    float* A1    = ws + off; off += (size_t)NN * KK * 3;
    float* Gvj   = ws + off; off += (size_t)NN * KK * 3;
    float* E1    = ws + off; off += 10 * KK;
    float* T1    = ws + off; off += 10 * KK;
    float* Wc    = ws + off; off += KK * KK;
    float* Wd    = ws + off; off += KK * KK;
    float* e1n   = ws + off; off += NN;
    float* e2n   = ws + off; off += NN;
    int* ip = (int*)(ws + off);
    size_t ioff = 0;
    int* deg_r = ip + ioff; ioff += NN;
    int* deg_s = ip + ioff; ioff += NN;
    int* cur_r = ip + ioff; ioff += NN;
    int* cur_s = ip + ioff; ioff += NN;
    int* zcnt  = ip + ioff; ioff += 16;
    int* zcur  = ip + ioff; ioff += 16;
    int* nact  = ip + ioff; ioff += 16;
    int* row_r = ip + ioff; ioff += NN + 2;
    int* row_s = ip + ioff; ioff += NN + 2;
    int* zrow  = ip + ioff; ioff += 16;
    int* zlist = ip + ioff; ioff += NN;
    int2* cei    = (int2*)(ip + ioff); ioff += (size_t)EE * 2;
    int2* list_r = (int2*)(ip + ioff); ioff += (size_t)EE * 2;
    int2* list_s = (int2*)(ip + ioff); ioff += (size_t)EE * 2;

    const int EG = (EE + 255) / 256;                // 625
    const int BNB  = ((NN + 63) / 64) * 2;          // 314
    const int BN3B = ((NN * 3 + 63) / 64) * 2;      // 938
    const int BS   = NE * 32;                       // 320
    const int ZB   = (out_size + 255) / 256;
    const int ZI   = (4 * NN + 48 + 255) / 256;
    tz_zero<<<ZB + ZI, 256, 0, stream>>>(out, out_size, deg_r, 4 * NN + 48, ZB);
    tz_geomtab<<<683, 256, 0, stream>>>(positions, shifts, edge_index, ef, defdr, Y1, rr,
                                        cei, nact, deg_r, deg_s, node_z, zcnt,
                                        W_embed, W_up1, W_sk_s1, E1, T1, W_mix_v1, W_up2v, Wc,
                                        W_mix_s1, W_up2s, Wd);
    tz_scan<<<1, 1024, 0, stream>>>(deg_r, deg_s, zcnt, row_r, row_s, zrow);
    tz_fill3<<<665 + (NN * KK) / 256, 256, 0, stream>>>(cei, nact, row_r, row_s, cur_r, cur_s,
                                                        list_r, list_s, node_z, zcur, zrow, zlist,
                                                        E1, T1, su1, s1);
    tz_edge1<<<(NN + 3) / 4, 256, 0, stream>>>(ef, Y1, R1, su1, row_r, list_r, A0, A1);
    tz_two<0, 1, 0, 0><<<BNB + BN3B, 256, 0, stream>>>(A0, W_mix_s1, s1, NN, INV_AVG,
                                                       A1, Wc, vup, NN * 3, INV_AVG, BNB);
    tz_mix<0, 0, 0, 0><<<BNB + BS, 256, 0, stream>>>(s1, W_up2s, s1u2, NN, 1.f,
                                                     s1, W_sk_s2, s2, zrow, zlist, BNB);
    tz_edge2<<<(NN + 3) / 4, 256, 0, stream>>>(ef, Y1, R2, s1u2, vup, row_r, list_r, A2);
    tz_one<0, 1><<<BNB, 256, 0, stream>>>(A2, W_mix_s2, s2, NN, INV_AVG);
    tz_mlp<<<NN, 128, 0, stream>>>(s2, W_mlp, w_out, w_r1, s1, g_s2, g_s1, e1n, e2n);
    tz_bwdmix<<<BNB + BS + 32, 256, 0, stream>>>(g_s2, W_mix_s2, A2, W_sk_s2, g_s1,
                                                 zrow, zlist, node_z, batch, atomic_e,
                                                 e1n, e2n, out, BNB, BNB + BS);
    tz_bwdA<<<625 + (NN + 3) / 4, 256, 0, stream>>>(ef, Y1, cei, nact, R2, A2, s1u2, vup,
                                                    list_s, row_s, gefA, gyA, Gsj2, Gvj);
    tz_three<1, 0, 1, 0, 1, 0><<<BN3B + BNB + BNB, 256, 0, stream>>>(
        Gvj, Wc, A1, NN * 3, INV_AVG,
        g_s1, W_mix_s1, A0, NN, INV_AVG,
        Gsj2, Wd, A0b, NN, INV_AVG, BN3B, BN3B + BNB);
    tz_bwdB<<<EG, 256, 0, stream>>>(ef, Y1, cei, nact, R1, su1, A0, A0b, A1, list_r,
                                    gefA, gyA, defdr, rr, out + GG + GG * 3);
}